// Round 1
// baseline (6134.241 us; speedup 1.0000x reference)
//
#include <hip/hip_runtime.h>
#include <hip/hip_bf16.h>

constexpr int K_MAX    = 128;   // max supported k (actual k=64 read from device)
constexpr int CAND_MAX = 512;   // candidate cap per row
constexpr int BM = 128, BN = 128, BK = 16;
constexpr int NBITER = 42;      // bisection iterations

// ---------------- kernel 1: encoder GEMM (fp32, approximate pass) ----------------
// pre[b,h] = sum_d (x[b,d]-b_pre[d]) * W_enc[h,d] + b_enc[h]
__global__ __launch_bounds__(256) void enc_gemm_f32(
    const float* __restrict__ X, const float* __restrict__ W,
    const float* __restrict__ b_enc, const float* __restrict__ b_pre,
    float* __restrict__ pre, int D, int H)
{
  __shared__ float As[BK][BM + 4];
  __shared__ float Bs[BK][BN + 4];
  const int tid = threadIdx.x;
  const int m0 = blockIdx.y * BM;
  const int n0 = blockIdx.x * BN;
  const int tx = tid & 15, ty = tid >> 4;
  float acc[8][8];
#pragma unroll
  for (int i = 0; i < 8; ++i)
#pragma unroll
    for (int j = 0; j < 8; ++j) acc[i][j] = 0.f;

  for (int kb = 0; kb < D; kb += BK) {
#pragma unroll
    for (int t = 0; t < 2; ++t) {
      const int f4i = tid + t * 256;
      const int row = f4i >> 2;
      const int kq  = (f4i & 3) << 2;
      float4 xv = *reinterpret_cast<const float4*>(X + (size_t)(m0 + row) * D + kb + kq);
      float4 bp = *reinterpret_cast<const float4*>(b_pre + kb + kq);
      As[kq + 0][row] = xv.x - bp.x; As[kq + 1][row] = xv.y - bp.y;
      As[kq + 2][row] = xv.z - bp.z; As[kq + 3][row] = xv.w - bp.w;
      float4 wv = *reinterpret_cast<const float4*>(W + (size_t)(n0 + row) * D + kb + kq);
      Bs[kq + 0][row] = wv.x; Bs[kq + 1][row] = wv.y;
      Bs[kq + 2][row] = wv.z; Bs[kq + 3][row] = wv.w;
    }
    __syncthreads();
#pragma unroll
    for (int kk = 0; kk < BK; ++kk) {
      float4 a0 = *reinterpret_cast<const float4*>(&As[kk][ty * 8]);
      float4 a1 = *reinterpret_cast<const float4*>(&As[kk][ty * 8 + 4]);
      float4 b0 = *reinterpret_cast<const float4*>(&Bs[kk][tx * 8]);
      float4 b1 = *reinterpret_cast<const float4*>(&Bs[kk][tx * 8 + 4]);
      float av[8] = {a0.x, a0.y, a0.z, a0.w, a1.x, a1.y, a1.z, a1.w};
      float bv[8] = {b0.x, b0.y, b0.z, b0.w, b1.x, b1.y, b1.z, b1.w};
#pragma unroll
      for (int i = 0; i < 8; ++i)
#pragma unroll
        for (int j = 0; j < 8; ++j) acc[i][j] += av[i] * bv[j];
    }
    __syncthreads();
  }
#pragma unroll
  for (int i = 0; i < 8; ++i) {
    const size_t m = (size_t)(m0 + ty * 8 + i);
#pragma unroll
    for (int j = 0; j < 8; j += 4) {
      const int n = n0 + tx * 8 + j;
      float4 o;
      o.x = acc[i][j + 0] + b_enc[n + 0];
      o.y = acc[i][j + 1] + b_enc[n + 1];
      o.z = acc[i][j + 2] + b_enc[n + 2];
      o.w = acc[i][j + 3] + b_enc[n + 3];
      *reinterpret_cast<float4*>(pre + m * H + n) = o;
    }
  }
}

// ---------------- kernel 2: per-row top-k with exact f64 refinement ----------------
// One block per row. Approx pre row is in `hidden`; we pick candidates near the
// k-th value, recompute their dot products in f64 (exact vs a f64 reference),
// rank exactly (index tie-break), rewrite the hidden row sparse, store (idx,val).
__global__ __launch_bounds__(256) void topk_refine(
    const float* __restrict__ X, const float* __restrict__ b_pre,
    const float* __restrict__ W, const float* __restrict__ b_enc,
    float* __restrict__ hidden, int* __restrict__ tk_idx, float* __restrict__ tk_val,
    const int* __restrict__ kptr, int D, int H, float margin)
{
  extern __shared__ char smem_raw[];
  double* cand_val = reinterpret_cast<double*>(smem_raw);
  float*  xr       = reinterpret_cast<float*>(cand_val + CAND_MAX);
  int*    cand_idx = reinterpret_cast<int*>(xr + D);
  int*    misc     = cand_idx + CAND_MAX;   // NBITER count slots + candidate counter

  const int tid = threadIdx.x;
  const int b = blockIdx.x;
  const int k = min(*kptr, K_MAX);
  float* hrow = hidden + (size_t)b * H;

  for (int i = tid; i < NBITER + 2; i += 256) misc[i] = 0;
  for (int d = tid; d < D; d += 256) xr[d] = X[(size_t)b * D + d] - b_pre[d];

  // each thread keeps 64 row elements in registers (static indices only)
  float f[64];
#pragma unroll
  for (int i = 0; i < 16; ++i) {
    const int base = i * 1024 + tid * 4;
    float4 v = {-3e38f, -3e38f, -3e38f, -3e38f};
    if (base + 3 < H) v = *reinterpret_cast<const float4*>(hrow + base);
    f[4 * i + 0] = v.x; f[4 * i + 1] = v.y; f[4 * i + 2] = v.z; f[4 * i + 3] = v.w;
  }
  __syncthreads();

  // bisection: lo converges to k-th largest approx value (count(>=lo) >= k)
  float lo = -1e4f, hi = 1e4f;
  for (int it = 0; it < NBITER; ++it) {
    const float mid = 0.5f * (lo + hi);
    int cnt = 0;
#pragma unroll
    for (int j = 0; j < 64; ++j) cnt += (f[j] >= mid) ? 1 : 0;
    for (int off = 32; off; off >>= 1) cnt += __shfl_xor(cnt, off);
    if ((tid & 63) == 0) atomicAdd(&misc[it], cnt);
    __syncthreads();
    if (misc[it] >= k) lo = mid; else hi = mid;
  }

  const float thresh = lo - margin;  // margin >> approx-GEMM error
#pragma unroll
  for (int j = 0; j < 64; ++j) {
    if (f[j] >= thresh) {
      const int h = (j >> 2) * 1024 + tid * 4 + (j & 3);
      if (h < H) {
        int pos = atomicAdd(&misc[NBITER], 1);
        if (pos < CAND_MAX) cand_idx[pos] = h;
      }
    }
  }
  __syncthreads();
  const int C = min(misc[NBITER], CAND_MAX);

  // exact f64 dot products for candidates (deterministic reduction order)
  const int wid = tid >> 6, lane = tid & 63;
  for (int c = wid; c < C; c += 4) {
    const int h = cand_idx[c];
    const float* wr = W + (size_t)h * D;
    double s = 0.0;
    for (int i = lane; i < D; i += 64)
      s += (double)xr[i] * (double)wr[i];
    for (int off = 32; off; off >>= 1) s += __shfl_xor(s, off);
    if (lane == 0) cand_val[c] = s + (double)b_enc[h];
  }
  __syncthreads();

  // zero the hidden row, then scatter the exact top-k
  const float4 z4 = {0.f, 0.f, 0.f, 0.f};
  for (int i = tid; i < (H >> 2); i += 256)
    reinterpret_cast<float4*>(hrow)[i] = z4;
  __syncthreads();  // drains stores before the scatter below

  for (int c = tid; c < C; c += 256) {
    const double v = cand_val[c];
    const int h = cand_idx[c];
    int r = 0;
    for (int j = 0; j < C; ++j) {
      const double vj = cand_val[j];
      r += ((vj > v) || (vj == v && cand_idx[j] < h)) ? 1 : 0;
    }
    if (r < k) {
      const float rv = (v > 0.0) ? (float)v : 0.f;   // relu
      hrow[h] = rv;
      tk_idx[(size_t)b * K_MAX + r] = h;
      tk_val[(size_t)b * K_MAX + r] = rv;
    }
  }
}

// ---------------- kernel 3: W_dec [D,H] -> W_decT [H,D] ----------------
__global__ __launch_bounds__(256) void transpose_wdec(
    const float* __restrict__ Wsrc, float* __restrict__ WT, int D, int H)
{
  __shared__ float tile[32][33];
  const int c  = threadIdx.x & 31;
  const int r0 = threadIdx.x >> 5;
  const int h0 = blockIdx.x * 32;
  const int d0 = blockIdx.y * 32;
#pragma unroll
  for (int r = r0; r < 32; r += 8) {
    const int d = d0 + r, h = h0 + c;
    if (d < D && h < H) tile[r][c] = Wsrc[(size_t)d * H + h];
  }
  __syncthreads();
#pragma unroll
  for (int r = r0; r < 32; r += 8) {
    const int h = h0 + r, d = d0 + c;
    if (h < H && d < D) WT[(size_t)h * D + d] = tile[c][r];
  }
}

// ---------------- kernel 4: sparse decode + per-row squared error ----------------
__global__ __launch_bounds__(256) void decode_loss(
    const float* __restrict__ X, const float* __restrict__ b_pre,
    const float* __restrict__ b_dec, const float* __restrict__ Wd,
    const int* __restrict__ tk_idx, const float* __restrict__ tk_val,
    const int* __restrict__ kptr,
    float* __restrict__ recon, double* __restrict__ row_ssq,
    int D, int H, int useWT)
{
  __shared__ int   sidx[K_MAX];
  __shared__ float sval[K_MAX];
  __shared__ double sd[4];
  const int tid = threadIdx.x, b = blockIdx.x;
  const int k = min(*kptr, K_MAX);
  if (tid < k) {
    sidx[tid] = tk_idx[(size_t)b * K_MAX + tid];
    sval[tid] = tk_val[(size_t)b * K_MAX + tid];
  }
  __syncthreads();
  double ssq = 0.0;
  for (int d = tid; d < D; d += 256) {
    float a = b_dec[d] + b_pre[d];
    if (useWT) {
#pragma unroll 4
      for (int j = 0; j < k; ++j) a += sval[j] * Wd[(size_t)sidx[j] * D + d];
    } else {
#pragma unroll 4
      for (int j = 0; j < k; ++j) a += sval[j] * Wd[(size_t)d * H + sidx[j]];
    }
    recon[(size_t)b * D + d] = a;
    const double diff = (double)a - (double)X[(size_t)b * D + d];
    ssq += diff * diff;
  }
  for (int off = 32; off; off >>= 1) ssq += __shfl_xor(ssq, off);
  if ((tid & 63) == 0) sd[tid >> 6] = ssq;
  __syncthreads();
  if (tid == 0) row_ssq[b] = sd[0] + sd[1] + sd[2] + sd[3];
}

// ---------------- kernel 5: finalize scalar losses ----------------
__global__ __launch_bounds__(256) void finalize_k(
    const double* __restrict__ row_ssq, const float* __restrict__ tk_val,
    const int* __restrict__ kptr, float* __restrict__ scalars, int Bdim, int D)
{
  __shared__ double sd[4];
  __shared__ int si[4];
  const int tid = threadIdx.x;
  const int k = min(*kptr, K_MAX);
  double s = 0.0;
  for (int i = tid; i < Bdim; i += 256) s += row_ssq[i];
  int cnt = 0;
  for (int i = tid; i < Bdim * k; i += 256) {
    const int b = i / k, j = i - b * k;
    cnt += (tk_val[(size_t)b * K_MAX + j] > 0.f) ? 1 : 0;
  }
  for (int off = 32; off; off >>= 1) { s += __shfl_xor(s, off); cnt += __shfl_xor(cnt, off); }
  if ((tid & 63) == 0) { sd[tid >> 6] = s; si[tid >> 6] = cnt; }
  __syncthreads();
  if (tid == 0) {
    double st = 0; int ct = 0;
    for (int w = 0; w < 4; ++w) { st += sd[w]; ct += si[w]; }
    const double rl = st / ((double)Bdim * (double)D);
    scalars[0] = (float)rl;                     // loss
    scalars[1] = (float)rl;                     // reconstruction_loss
    scalars[2] = 0.f;                           // sparsity_loss
    scalars[3] = (float)((double)ct / Bdim);    // l0
  }
}

extern "C" void kernel_launch(void* const* d_in, const int* in_sizes, int n_in,
                              void* d_out, int out_size, void* d_ws, size_t ws_size,
                              hipStream_t stream)
{
  const float* x     = (const float*)d_in[0];
  const float* W_enc = (const float*)d_in[1];
  const float* b_enc = (const float*)d_in[2];
  const float* W_dec = (const float*)d_in[3];
  const float* b_dec = (const float*)d_in[4];
  const float* b_pre = (const float*)d_in[5];
  const int*   kptr  = (const int*)d_in[6];

  const int D = in_sizes[4];          // 1280
  const int H = in_sizes[2];          // 16384
  const int B = in_sizes[0] / D;      // 8192

  float* recon   = (float*)d_out;
  float* hidden  = recon + (size_t)B * D;       // also holds `pre` temporarily
  float* scalars = hidden + (size_t)B * H;

  char* w = (char*)d_ws;
  int*    tk_idx  = (int*)w;    w += (size_t)B * K_MAX * sizeof(int);
  float*  tk_val  = (float*)w;  w += (size_t)B * K_MAX * sizeof(float);
  double* row_ssq = (double*)w; w += (size_t)B * sizeof(double);
  const size_t base_need = (size_t)(w - (char*)d_ws);
  float* WT = (float*)w;
  const int useWT = (ws_size >= base_need + (size_t)D * H * sizeof(float)) ? 1 : 0;

  dim3 gg(H / BN, B / BM);
  enc_gemm_f32<<<gg, 256, 0, stream>>>(x, W_enc, b_enc, b_pre, hidden, D, H);

  const size_t sh = CAND_MAX * sizeof(double) + (size_t)D * sizeof(float)
                  + CAND_MAX * sizeof(int) + (NBITER + 8) * sizeof(int);
  topk_refine<<<B, 256, sh, stream>>>(x, b_pre, W_enc, b_enc, hidden,
                                      tk_idx, tk_val, kptr, D, H, 1e-3f);

  if (useWT)
    transpose_wdec<<<dim3((H + 31) / 32, (D + 31) / 32), 256, 0, stream>>>(W_dec, WT, D, H);

  decode_loss<<<B, 256, 0, stream>>>(x, b_pre, b_dec, useWT ? WT : W_dec,
                                     tk_idx, tk_val, kptr, recon, row_ssq, D, H, useWT);

  finalize_k<<<1, 256, 0, stream>>>(row_ssq, tk_val, kptr, scalars, B, D);
}

// Round 2
// 2896.395 us; speedup vs baseline: 2.1179x; 2.1179x over previous
//
#include <hip/hip_runtime.h>
#include <hip/hip_bf16.h>

constexpr int K_MAX    = 128;   // max supported k (actual k=64 read from device)
constexpr int CAND_MAX = 512;   // candidate cap per row
constexpr int BM = 128, BN = 128, BK = 16;
constexpr int NBITER = 42;      // bisection iterations

typedef __attribute__((ext_vector_type(8))) short bf16x8;
typedef __attribute__((ext_vector_type(4))) float f32x4;

__device__ inline unsigned short f2bf(float f) {   // round-to-nearest-even
  unsigned u = __float_as_uint(f);
  unsigned r = (u + 0x7fff + ((u >> 16) & 1)) >> 16;
  return (unsigned short)r;
}

// ---------------- prep: xc_bf16 = bf16(x - b_pre), W_bf16 = bf16(W_enc) ----------------
__global__ __launch_bounds__(256) void prep_xb(
    const float* __restrict__ x, const float* __restrict__ b_pre,
    unsigned short* __restrict__ Xb, int D, size_t total4)
{
  for (size_t i = blockIdx.x * 256 + threadIdx.x; i < total4; i += (size_t)gridDim.x * 256) {
    const size_t e = i * 4;
    const int d = (int)(e % D);
    float4 xv = *reinterpret_cast<const float4*>(x + e);
    float4 bp = *reinterpret_cast<const float4*>(b_pre + d);
    ushort4 o;
    o.x = f2bf(xv.x - bp.x); o.y = f2bf(xv.y - bp.y);
    o.z = f2bf(xv.z - bp.z); o.w = f2bf(xv.w - bp.w);
    *reinterpret_cast<ushort4*>(Xb + e) = o;
  }
}

__global__ __launch_bounds__(256) void prep_wb(
    const float* __restrict__ W, unsigned short* __restrict__ Wb, size_t total4)
{
  for (size_t i = blockIdx.x * 256 + threadIdx.x; i < total4; i += (size_t)gridDim.x * 256) {
    const size_t e = i * 4;
    float4 wv = *reinterpret_cast<const float4*>(W + e);
    ushort4 o;
    o.x = f2bf(wv.x); o.y = f2bf(wv.y); o.z = f2bf(wv.z); o.w = f2bf(wv.w);
    *reinterpret_cast<ushort4*>(Wb + e) = o;
  }
}

// ---------------- kernel 1: encoder GEMM, bf16 MFMA (m97 structure) ----------------
// pre[b,h] = sum_d Xb[b,d]*Wb[h,d] + b_enc[h]; both operands K-contiguous (gemm_bt).
__global__ __launch_bounds__(256) void enc_gemm_bf16(
    const unsigned short* __restrict__ Xb, const unsigned short* __restrict__ Wb,
    const float* __restrict__ b_enc, float* __restrict__ pre, int D, int H)
{
  __shared__ unsigned short As[128 * 32];   // [row][k] linear, 64B rows
  __shared__ unsigned short Bs[128 * 32];
  const int tid  = threadIdx.x;
  const int wave = tid >> 6, lane = tid & 63;
  const int m0 = blockIdx.y * 128, n0 = blockIdx.x * 128;
  const int wm = (wave >> 1) * 64, wn = (wave & 1) * 64;   // wave's 64x64 subtile
  const int l16 = lane & 15, lhi = lane >> 4;

  f32x4 acc[4][4];
#pragma unroll
  for (int i = 0; i < 4; ++i)
#pragma unroll
    for (int j = 0; j < 4; ++j) acc[i][j] = (f32x4){0.f, 0.f, 0.f, 0.f};

  for (int kb = 0; kb < D; kb += 32) {
    // stage A/B tiles: 512 x 16B chunks each; wave-uniform LDS base + lane*16
#pragma unroll
    for (int i = 0; i < 2; ++i) {
      const int base = wave * 64 + i * 256;       // chunk index of this wave's lane 0
      const int idx  = base + lane;
      const int row  = idx >> 2, ch = idx & 3;    // 4 x 16B chunks per 64B row
      const unsigned short* gA = Xb + (size_t)(m0 + row) * D + kb + ch * 8;
      __builtin_amdgcn_global_load_lds(
          (const __attribute__((address_space(1))) unsigned int*)gA,
          (__attribute__((address_space(3))) unsigned int*)(As + (size_t)base * 8),
          16, 0, 0);
      const unsigned short* gB = Wb + (size_t)(n0 + row) * D + kb + ch * 8;
      __builtin_amdgcn_global_load_lds(
          (const __attribute__((address_space(1))) unsigned int*)gB,
          (__attribute__((address_space(3))) unsigned int*)(Bs + (size_t)base * 8),
          16, 0, 0);
    }
    __syncthreads();   // compiler emits vmcnt(0) drain before barrier

    bf16x8 af[4], bfr[4];
#pragma unroll
    for (int mi = 0; mi < 4; ++mi)
      af[mi] = *reinterpret_cast<const bf16x8*>(As + (size_t)(wm + mi * 16 + l16) * 32 + lhi * 8);
#pragma unroll
    for (int ni = 0; ni < 4; ++ni)
      bfr[ni] = *reinterpret_cast<const bf16x8*>(Bs + (size_t)(wn + ni * 16 + l16) * 32 + lhi * 8);
#pragma unroll
    for (int mi = 0; mi < 4; ++mi)
#pragma unroll
      for (int ni = 0; ni < 4; ++ni)
        acc[mi][ni] = __builtin_amdgcn_mfma_f32_16x16x32_bf16(af[mi], bfr[ni], acc[mi][ni], 0, 0, 0);
    __syncthreads();
  }

#pragma unroll
  for (int ni = 0; ni < 4; ++ni) {
    const int n = n0 + wn + ni * 16 + l16;
    const float be = b_enc[n];
#pragma unroll
    for (int mi = 0; mi < 4; ++mi) {
      const int mbase = m0 + wm + mi * 16 + lhi * 4;
#pragma unroll
      for (int r = 0; r < 4; ++r)
        pre[(size_t)(mbase + r) * H + n] = acc[mi][ni][r] + be;
    }
  }
}

// ---------------- fallback: fp32 GEMM (used only if ws too small for bf16 bufs) ----------------
__global__ __launch_bounds__(256) void enc_gemm_f32(
    const float* __restrict__ X, const float* __restrict__ W,
    const float* __restrict__ b_enc, const float* __restrict__ b_pre,
    float* __restrict__ pre, int D, int H)
{
  __shared__ float As[BK][BM + 4];
  __shared__ float Bs[BK][BN + 4];
  const int tid = threadIdx.x;
  const int m0 = blockIdx.y * BM;
  const int n0 = blockIdx.x * BN;
  const int tx = tid & 15, ty = tid >> 4;
  float acc[8][8];
#pragma unroll
  for (int i = 0; i < 8; ++i)
#pragma unroll
    for (int j = 0; j < 8; ++j) acc[i][j] = 0.f;

  for (int kb = 0; kb < D; kb += BK) {
#pragma unroll
    for (int t = 0; t < 2; ++t) {
      const int f4i = tid + t * 256;
      const int row = f4i >> 2;
      const int kq  = (f4i & 3) << 2;
      float4 xv = *reinterpret_cast<const float4*>(X + (size_t)(m0 + row) * D + kb + kq);
      float4 bp = *reinterpret_cast<const float4*>(b_pre + kb + kq);
      As[kq + 0][row] = xv.x - bp.x; As[kq + 1][row] = xv.y - bp.y;
      As[kq + 2][row] = xv.z - bp.z; As[kq + 3][row] = xv.w - bp.w;
      float4 wv = *reinterpret_cast<const float4*>(W + (size_t)(n0 + row) * D + kb + kq);
      Bs[kq + 0][row] = wv.x; Bs[kq + 1][row] = wv.y;
      Bs[kq + 2][row] = wv.z; Bs[kq + 3][row] = wv.w;
    }
    __syncthreads();
#pragma unroll
    for (int kk = 0; kk < BK; ++kk) {
      float4 a0 = *reinterpret_cast<const float4*>(&As[kk][ty * 8]);
      float4 a1 = *reinterpret_cast<const float4*>(&As[kk][ty * 8 + 4]);
      float4 b0 = *reinterpret_cast<const float4*>(&Bs[kk][tx * 8]);
      float4 b1 = *reinterpret_cast<const float4*>(&Bs[kk][tx * 8 + 4]);
      float av[8] = {a0.x, a0.y, a0.z, a0.w, a1.x, a1.y, a1.z, a1.w};
      float bv[8] = {b0.x, b0.y, b0.z, b0.w, b1.x, b1.y, b1.z, b1.w};
#pragma unroll
      for (int i = 0; i < 8; ++i)
#pragma unroll
        for (int j = 0; j < 8; ++j) acc[i][j] += av[i] * bv[j];
    }
    __syncthreads();
  }
#pragma unroll
  for (int i = 0; i < 8; ++i) {
    const size_t m = (size_t)(m0 + ty * 8 + i);
#pragma unroll
    for (int j = 0; j < 8; j += 4) {
      const int n = n0 + tx * 8 + j;
      float4 o;
      o.x = acc[i][j + 0] + b_enc[n + 0];
      o.y = acc[i][j + 1] + b_enc[n + 1];
      o.z = acc[i][j + 2] + b_enc[n + 2];
      o.w = acc[i][j + 3] + b_enc[n + 3];
      *reinterpret_cast<float4*>(pre + m * H + n) = o;
    }
  }
}

// ---------------- kernel 2: per-row top-k with exact f64 refinement ----------------
__global__ __launch_bounds__(256) void topk_refine(
    const float* __restrict__ X, const float* __restrict__ b_pre,
    const float* __restrict__ W, const float* __restrict__ b_enc,
    float* __restrict__ hidden, int* __restrict__ tk_idx, float* __restrict__ tk_val,
    const int* __restrict__ kptr, int D, int H, float margin)
{
  extern __shared__ char smem_raw[];
  double* cand_val = reinterpret_cast<double*>(smem_raw);
  float*  xr       = reinterpret_cast<float*>(cand_val + CAND_MAX);
  int*    cand_idx = reinterpret_cast<int*>(xr + D);
  int*    misc     = cand_idx + CAND_MAX;   // NBITER count slots + candidate counter

  const int tid = threadIdx.x;
  const int b = blockIdx.x;
  const int k = min(*kptr, K_MAX);
  float* hrow = hidden + (size_t)b * H;

  for (int i = tid; i < NBITER + 2; i += 256) misc[i] = 0;
  for (int d = tid; d < D; d += 256) xr[d] = X[(size_t)b * D + d] - b_pre[d];

  // each thread keeps 64 row elements in registers (static indices only)
  float f[64];
#pragma unroll
  for (int i = 0; i < 16; ++i) {
    const int base = i * 1024 + tid * 4;
    float4 v = {-3e38f, -3e38f, -3e38f, -3e38f};
    if (base + 3 < H) v = *reinterpret_cast<const float4*>(hrow + base);
    f[4 * i + 0] = v.x; f[4 * i + 1] = v.y; f[4 * i + 2] = v.z; f[4 * i + 3] = v.w;
  }
  __syncthreads();

  // bisection: lo converges to k-th largest approx value (count(>=lo) >= k)
  float lo = -1e4f, hi = 1e4f;
  for (int it = 0; it < NBITER; ++it) {
    const float mid = 0.5f * (lo + hi);
    int cnt = 0;
#pragma unroll
    for (int j = 0; j < 64; ++j) cnt += (f[j] >= mid) ? 1 : 0;
    for (int off = 32; off; off >>= 1) cnt += __shfl_xor(cnt, off);
    if ((tid & 63) == 0) atomicAdd(&misc[it], cnt);
    __syncthreads();
    if (misc[it] >= k) lo = mid; else hi = mid;
  }

  const float thresh = lo - margin;  // margin >> approx-GEMM (bf16) error
#pragma unroll
  for (int j = 0; j < 64; ++j) {
    if (f[j] >= thresh) {
      const int h = (j >> 2) * 1024 + tid * 4 + (j & 3);
      if (h < H) {
        int pos = atomicAdd(&misc[NBITER], 1);
        if (pos < CAND_MAX) cand_idx[pos] = h;
      }
    }
  }
  __syncthreads();
  const int C = min(misc[NBITER], CAND_MAX);

  // exact f64 dot products for candidates (deterministic reduction order)
  const int wid = tid >> 6, lane = tid & 63;
  for (int c = wid; c < C; c += 4) {
    const int h = cand_idx[c];
    const float* wr = W + (size_t)h * D;
    double s = 0.0;
    for (int i = lane; i < D; i += 64)
      s += (double)xr[i] * (double)wr[i];
    for (int off = 32; off; off >>= 1) s += __shfl_xor(s, off);
    if (lane == 0) cand_val[c] = s + (double)b_enc[h];
  }
  __syncthreads();

  // zero the hidden row, then scatter the exact top-k
  const float4 z4 = {0.f, 0.f, 0.f, 0.f};
  for (int i = tid; i < (H >> 2); i += 256)
    reinterpret_cast<float4*>(hrow)[i] = z4;
  __syncthreads();  // drains stores before the scatter below

  for (int c = tid; c < C; c += 256) {
    const double v = cand_val[c];
    const int h = cand_idx[c];
    int r = 0;
    for (int j = 0; j < C; ++j) {
      const double vj = cand_val[j];
      r += ((vj > v) || (vj == v && cand_idx[j] < h)) ? 1 : 0;
    }
    if (r < k) {
      const float rv = (v > 0.0) ? (float)v : 0.f;   // relu
      hrow[h] = rv;
      tk_idx[(size_t)b * K_MAX + r] = h;
      tk_val[(size_t)b * K_MAX + r] = rv;
    }
  }
}

// ---------------- kernel 3: W_dec [D,H] -> W_decT [H,D] ----------------
__global__ __launch_bounds__(256) void transpose_wdec(
    const float* __restrict__ Wsrc, float* __restrict__ WT, int D, int H)
{
  __shared__ float tile[32][33];
  const int c  = threadIdx.x & 31;
  const int r0 = threadIdx.x >> 5;
  const int h0 = blockIdx.x * 32;
  const int d0 = blockIdx.y * 32;
#pragma unroll
  for (int r = r0; r < 32; r += 8) {
    const int d = d0 + r, h = h0 + c;
    if (d < D && h < H) tile[r][c] = Wsrc[(size_t)d * H + h];
  }
  __syncthreads();
#pragma unroll
  for (int r = r0; r < 32; r += 8) {
    const int h = h0 + r, d = d0 + c;
    if (h < H && d < D) WT[(size_t)h * D + d] = tile[c][r];
  }
}

// ---------------- kernel 4: sparse decode + per-row squared error ----------------
__global__ __launch_bounds__(256) void decode_loss(
    const float* __restrict__ X, const float* __restrict__ b_pre,
    const float* __restrict__ b_dec, const float* __restrict__ Wd,
    const int* __restrict__ tk_idx, const float* __restrict__ tk_val,
    const int* __restrict__ kptr,
    float* __restrict__ recon, double* __restrict__ row_ssq,
    int D, int H, int useWT)
{
  __shared__ int   sidx[K_MAX];
  __shared__ float sval[K_MAX];
  __shared__ double sd[4];
  const int tid = threadIdx.x, b = blockIdx.x;
  const int k = min(*kptr, K_MAX);
  if (tid < k) {
    sidx[tid] = tk_idx[(size_t)b * K_MAX + tid];
    sval[tid] = tk_val[(size_t)b * K_MAX + tid];
  }
  __syncthreads();
  double ssq = 0.0;
  for (int d = tid; d < D; d += 256) {
    float a = b_dec[d] + b_pre[d];
    if (useWT) {
#pragma unroll 4
      for (int j = 0; j < k; ++j) a += sval[j] * Wd[(size_t)sidx[j] * D + d];
    } else {
#pragma unroll 4
      for (int j = 0; j < k; ++j) a += sval[j] * Wd[(size_t)d * H + sidx[j]];
    }
    recon[(size_t)b * D + d] = a;
    const double diff = (double)a - (double)X[(size_t)b * D + d];
    ssq += diff * diff;
  }
  for (int off = 32; off; off >>= 1) ssq += __shfl_xor(ssq, off);
  if ((tid & 63) == 0) sd[tid >> 6] = ssq;
  __syncthreads();
  if (tid == 0) row_ssq[b] = sd[0] + sd[1] + sd[2] + sd[3];
}

// ---------------- kernel 5: finalize scalar losses ----------------
__global__ __launch_bounds__(256) void finalize_k(
    const double* __restrict__ row_ssq, const float* __restrict__ tk_val,
    const int* __restrict__ kptr, float* __restrict__ scalars, int Bdim, int D)
{
  __shared__ double sd[4];
  __shared__ int si[4];
  const int tid = threadIdx.x;
  const int k = min(*kptr, K_MAX);
  double s = 0.0;
  for (int i = tid; i < Bdim; i += 256) s += row_ssq[i];
  int cnt = 0;
  for (int i = tid; i < Bdim * k; i += 256) {
    const int b = i / k, j = i - b * k;
    cnt += (tk_val[(size_t)b * K_MAX + j] > 0.f) ? 1 : 0;
  }
  for (int off = 32; off; off >>= 1) { s += __shfl_xor(s, off); cnt += __shfl_xor(cnt, off); }
  if ((tid & 63) == 0) { sd[tid >> 6] = s; si[tid >> 6] = cnt; }
  __syncthreads();
  if (tid == 0) {
    double st = 0; int ct = 0;
    for (int w = 0; w < 4; ++w) { st += sd[w]; ct += si[w]; }
    const double rl = st / ((double)Bdim * (double)D);
    scalars[0] = (float)rl;                     // loss
    scalars[1] = (float)rl;                     // reconstruction_loss
    scalars[2] = 0.f;                           // sparsity_loss
    scalars[3] = (float)((double)ct / Bdim);    // l0
  }
}

extern "C" void kernel_launch(void* const* d_in, const int* in_sizes, int n_in,
                              void* d_out, int out_size, void* d_ws, size_t ws_size,
                              hipStream_t stream)
{
  const float* x     = (const float*)d_in[0];
  const float* W_enc = (const float*)d_in[1];
  const float* b_enc = (const float*)d_in[2];
  const float* W_dec = (const float*)d_in[3];
  const float* b_dec = (const float*)d_in[4];
  const float* b_pre = (const float*)d_in[5];
  const int*   kptr  = (const int*)d_in[6];

  const int D = in_sizes[4];          // 1280
  const int H = in_sizes[2];          // 16384
  const int B = in_sizes[0] / D;      // 8192

  float* recon   = (float*)d_out;
  float* hidden  = recon + (size_t)B * D;       // also holds `pre` temporarily
  float* scalars = hidden + (size_t)B * H;

  char* w = (char*)d_ws;
  int*    tk_idx  = (int*)w;    w += (size_t)B * K_MAX * sizeof(int);
  float*  tk_val  = (float*)w;  w += (size_t)B * K_MAX * sizeof(float);
  double* row_ssq = (double*)w; w += (size_t)B * sizeof(double);

  unsigned short* Xb = (unsigned short*)w;
  const size_t xb_bytes = (size_t)B * D * sizeof(unsigned short);
  unsigned short* Wb = (unsigned short*)(w + xb_bytes);
  const size_t wb_bytes = (size_t)H * D * sizeof(unsigned short);
  const size_t after_bf16 = (size_t)(w - (char*)d_ws) + xb_bytes + wb_bytes;
  const int useBF16 = (ws_size >= after_bf16) ? 1 : 0;

  char* wt_base = useBF16 ? (w + xb_bytes + wb_bytes) : w;
  float* WT = (float*)wt_base;
  const size_t wt_need = (size_t)(wt_base - (char*)d_ws) + (size_t)D * H * sizeof(float);
  const int useWT = (ws_size >= wt_need) ? 1 : 0;

  const bool div_ok = (D % 32 == 0) && (H % 128 == 0) && (B % 128 == 0) && (D % 4 == 0);

  if (useBF16 && div_ok) {
    const size_t tx4 = (size_t)B * D / 4, tw4 = (size_t)H * D / 4;
    prep_xb<<<2048, 256, 0, stream>>>(x, b_pre, Xb, D, tx4);
    prep_wb<<<2048, 256, 0, stream>>>(W_enc, Wb, tw4);
    dim3 gg(H / 128, B / 128);
    enc_gemm_bf16<<<gg, 256, 0, stream>>>(Xb, Wb, b_enc, hidden, D, H);
  } else {
    dim3 gg(H / BN, B / BM);
    enc_gemm_f32<<<gg, 256, 0, stream>>>(x, W_enc, b_enc, b_pre, hidden, D, H);
  }

  // margin covers worst-case bf16-GEMM deviation (sigma ~1.6e-3, 0.06 ≈ 37 sigma)
  const float margin = (useBF16 && div_ok) ? 0.06f : 1e-3f;
  const size_t sh = CAND_MAX * sizeof(double) + (size_t)D * sizeof(float)
                  + CAND_MAX * sizeof(int) + (NBITER + 8) * sizeof(int);
  topk_refine<<<B, 256, sh, stream>>>(x, b_pre, W_enc, b_enc, hidden,
                                      tk_idx, tk_val, kptr, D, H, margin);

  if (useWT)
    transpose_wdec<<<dim3((H + 31) / 32, (D + 31) / 32), 256, 0, stream>>>(W_dec, WT, D, H);

  decode_loss<<<B, 256, 0, stream>>>(x, b_pre, b_dec, useWT ? WT : W_dec,
                                     tk_idx, tk_val, kptr, recon, row_ssq, D, H, useWT);

  finalize_k<<<1, 256, 0, stream>>>(row_ssq, tk_val, kptr, scalars, B, D);
}

// Round 3
// 2442.326 us; speedup vs baseline: 2.5116x; 1.1859x over previous
//
#include <hip/hip_runtime.h>
#include <hip/hip_bf16.h>

constexpr int K_MAX    = 128;   // max supported k (actual k=64 read from device)
constexpr int CAND_MAX = 512;   // candidate cap per row
constexpr int BM = 128, BN = 128, BK = 16;
constexpr int NBITER = 42;      // fallback bisection iterations
constexpr int D_MAX   = 2048;   // fast path requires D <= D_MAX
constexpr int H_FIX   = 16384;  // fast path requires H == H_FIX

typedef __attribute__((ext_vector_type(8))) short bf16x8;
typedef __attribute__((ext_vector_type(8))) unsigned short u16x8;
typedef __attribute__((ext_vector_type(4))) float f32x4;

__device__ inline unsigned short f2bf(float f) {   // round-to-nearest-even
  unsigned u = __float_as_uint(f);
  return (unsigned short)((u + 0x7fff + ((u >> 16) & 1)) >> 16);
}
// monotone 16-bit key: key order == value order (handles negatives)
__device__ inline unsigned short key_of(float f) {
  unsigned short b = f2bf(f);
  return b ^ ((b & 0x8000) ? 0xFFFF : 0x8000);
}
__device__ inline float val_of_key(unsigned short kk) {
  unsigned short b = (kk & 0x8000) ? (unsigned short)(kk ^ 0x8000)
                                   : (unsigned short)(kk ^ 0xFFFF);
  return __uint_as_float(((unsigned)b) << 16);
}
__device__ inline float bf2f(unsigned short b) {
  return __uint_as_float(((unsigned)b) << 16);
}

// ---------------- prep: Xb = bf16(x - b_pre), Wb = bf16(W_enc) ----------------
__global__ __launch_bounds__(256) void prep_xb(
    const float* __restrict__ x, const float* __restrict__ b_pre,
    unsigned short* __restrict__ Xb, int D, size_t total4)
{
  for (size_t i = blockIdx.x * 256 + threadIdx.x; i < total4; i += (size_t)gridDim.x * 256) {
    const size_t e = i * 4;
    const int d = (int)(e % D);
    float4 xv = *reinterpret_cast<const float4*>(x + e);
    float4 bp = *reinterpret_cast<const float4*>(b_pre + d);
    ushort4 o;
    o.x = f2bf(xv.x - bp.x); o.y = f2bf(xv.y - bp.y);
    o.z = f2bf(xv.z - bp.z); o.w = f2bf(xv.w - bp.w);
    *reinterpret_cast<ushort4*>(Xb + e) = o;
  }
}

__global__ __launch_bounds__(256) void prep_wb(
    const float* __restrict__ W, unsigned short* __restrict__ Wb, size_t total4)
{
  for (size_t i = blockIdx.x * 256 + threadIdx.x; i < total4; i += (size_t)gridDim.x * 256) {
    const size_t e = i * 4;
    float4 wv = *reinterpret_cast<const float4*>(W + e);
    ushort4 o;
    o.x = f2bf(wv.x); o.y = f2bf(wv.y); o.z = f2bf(wv.z); o.w = f2bf(wv.w);
    *reinterpret_cast<ushort4*>(Wb + e) = o;
  }
}

// ---------------- kernel 1: encoder GEMM, bf16 MFMA, writes monotone u16 keys ----------------
__global__ __launch_bounds__(256) void enc_gemm_bf16k(
    const unsigned short* __restrict__ Xb, const unsigned short* __restrict__ Wb,
    const float* __restrict__ b_enc, float* __restrict__ pre, int D, int H)
{
  __shared__ unsigned short As[128 * 32];   // [row][k] linear, 64B rows
  __shared__ unsigned short Bs[128 * 32];
  const int tid  = threadIdx.x;
  const int wave = tid >> 6, lane = tid & 63;
  const int m0 = blockIdx.y * 128, n0 = blockIdx.x * 128;
  const int wm = (wave >> 1) * 64, wn = (wave & 1) * 64;
  const int l16 = lane & 15, lhi = lane >> 4;

  f32x4 acc[4][4];
#pragma unroll
  for (int i = 0; i < 4; ++i)
#pragma unroll
    for (int j = 0; j < 4; ++j) acc[i][j] = (f32x4){0.f, 0.f, 0.f, 0.f};

  for (int kb = 0; kb < D; kb += 32) {
#pragma unroll
    for (int i = 0; i < 2; ++i) {
      const int base = wave * 64 + i * 256;
      const int idx  = base + lane;
      const int row  = idx >> 2, ch = idx & 3;
      const unsigned short* gA = Xb + (size_t)(m0 + row) * D + kb + ch * 8;
      __builtin_amdgcn_global_load_lds(
          (const __attribute__((address_space(1))) unsigned int*)gA,
          (__attribute__((address_space(3))) unsigned int*)(As + (size_t)base * 8),
          16, 0, 0);
      const unsigned short* gB = Wb + (size_t)(n0 + row) * D + kb + ch * 8;
      __builtin_amdgcn_global_load_lds(
          (const __attribute__((address_space(1))) unsigned int*)gB,
          (__attribute__((address_space(3))) unsigned int*)(Bs + (size_t)base * 8),
          16, 0, 0);
    }
    __syncthreads();

    bf16x8 af[4], bfr[4];
#pragma unroll
    for (int mi = 0; mi < 4; ++mi)
      af[mi] = *reinterpret_cast<const bf16x8*>(As + (size_t)(wm + mi * 16 + l16) * 32 + lhi * 8);
#pragma unroll
    for (int ni = 0; ni < 4; ++ni)
      bfr[ni] = *reinterpret_cast<const bf16x8*>(Bs + (size_t)(wn + ni * 16 + l16) * 32 + lhi * 8);
#pragma unroll
    for (int mi = 0; mi < 4; ++mi)
#pragma unroll
      for (int ni = 0; ni < 4; ++ni)
        acc[mi][ni] = __builtin_amdgcn_mfma_f32_16x16x32_bf16(af[mi], bfr[ni], acc[mi][ni], 0, 0, 0);
    __syncthreads();
  }

#pragma unroll
  for (int ni = 0; ni < 4; ++ni) {
    const int n = n0 + wn + ni * 16 + l16;
    const float be = b_enc[n];
#pragma unroll
    for (int mi = 0; mi < 4; ++mi) {
      const int mbase = m0 + wm + mi * 16 + lhi * 4;
#pragma unroll
      for (int r = 0; r < 4; ++r) {
        unsigned short* prow = (unsigned short*)(pre + (size_t)(mbase + r) * H);
        prow[n] = key_of(acc[mi][ni][r] + be);
      }
    }
  }
}

// ---------------- kernel 2 (fast): single-pass histogram select + exact f64 refine ----------------
__global__ __launch_bounds__(256, 2) void topk_select(
    const float* __restrict__ X, const float* __restrict__ b_pre,
    const float* __restrict__ W, const float* __restrict__ b_enc,
    float* __restrict__ hidden, int* __restrict__ tk_idx, float* __restrict__ tk_val,
    const int* __restrict__ kptr, int D, float margin)
{
  constexpr int H = H_FIX, NC = H_FIX / (256 * 8);   // 8 chunks of u16x8 per thread
  __shared__ double cand_sv[CAND_MAX];
  __shared__ float  xr[D_MAX];
  __shared__ int    cand_ix[CAND_MAX];
  __shared__ int    hist[4096];
  __shared__ int    chunk[256];
  __shared__ int    misc[8];

  const int tid = threadIdx.x, b = blockIdx.x;
  const int k = min(*kptr, K_MAX);
  float* hrow = hidden + (size_t)b * H;
  const unsigned short* krow = (const unsigned short*)hrow;

  if (tid < 8) misc[tid] = 0;
  for (int i = tid; i < 4096; i += 256) hist[i] = 0;
  for (int d = tid; d < D; d += 256) xr[d] = X[(size_t)b * D + d] - b_pre[d];

  // keys in registers: 8 x u16x8, statically indexed (no spill)
  u16x8 kv[NC];
#pragma unroll
  for (int i = 0; i < NC; ++i)
    kv[i] = *reinterpret_cast<const u16x8*>(krow + ((size_t)i * 256 + tid) * 8);
  __syncthreads();

  // histogram over key>>4 (4096 bins)
#pragma unroll
  for (int i = 0; i < NC; ++i)
#pragma unroll
    for (int j = 0; j < 8; ++j)
      atomicAdd(&hist[((unsigned)(unsigned short)kv[i][j]) >> 4], 1);
  __syncthreads();

  // suffix-scan from the top to locate the bin containing the k-th largest
  int csum = 0;
#pragma unroll
  for (int j = 0; j < 16; ++j) csum += hist[tid * 16 + j];
  chunk[tid] = csum;
  __syncthreads();
  int gt = 0;
  for (int j = tid + 1; j < 256; ++j) gt += chunk[j];
  {
    int run = gt;
#pragma unroll
    for (int j = 15; j >= 0; --j) {
      const int hc = hist[tid * 16 + j];
      if (run < k && k <= run + hc) { misc[0] = tid * 16 + j; misc[1] = run; }
      run += hc;
    }
  }
  __syncthreads();
  const int b1 = misc[0];
  if (tid < 16) chunk[tid] = 0;
  __syncthreads();
  // 16-bin sub-histogram inside bin b1 -> exact k-th key
#pragma unroll
  for (int i = 0; i < NC; ++i)
#pragma unroll
    for (int j = 0; j < 8; ++j) {
      const unsigned kk = (unsigned)(unsigned short)kv[i][j];
      if ((int)(kk >> 4) == b1) atomicAdd(&chunk[kk & 15], 1);
    }
  __syncthreads();
  if (tid == 0) {
    int run = misc[1];
    int K16 = b1 << 4;
    for (int j = 15; j >= 0; --j) {
      const int c = chunk[j];
      if (run < k && k <= run + c) K16 = (b1 << 4) | j;
      run += c;
    }
    const float vthr = val_of_key((unsigned short)K16) - margin;
    int kt = (int)key_of(vthr);
    if (kt > K16) kt = K16;   // always include ties at the k-th key
    misc[2] = kt;
  }
  __syncthreads();
  const unsigned kthr = (unsigned)misc[2];

  // collect candidate indices
#pragma unroll
  for (int i = 0; i < NC; ++i)
#pragma unroll
    for (int j = 0; j < 8; ++j) {
      if ((unsigned)(unsigned short)kv[i][j] >= kthr) {
        const int pos = atomicAdd(&misc[3], 1);
        if (pos < CAND_MAX) cand_ix[pos] = (i * 256 + tid) * 8 + j;
      }
    }
  __syncthreads();
  const int C = min(misc[3], CAND_MAX);

  // zero hidden row (keys already consumed into registers)
  const float4 z4 = {0.f, 0.f, 0.f, 0.f};
  for (int i = tid; i < (H >> 2); i += 256)
    reinterpret_cast<float4*>(hrow)[i] = z4;

  // exact f64 dot products for candidates (deterministic reduction order)
  const int wid = tid >> 6, lane = tid & 63;
  for (int c = wid; c < C; c += 4) {
    const int h = cand_ix[c];
    const float* wr = W + (size_t)h * D;
    double s = 0.0;
    for (int i = lane; i < D; i += 64) s += (double)xr[i] * (double)wr[i];
    for (int off = 32; off; off >>= 1) s += __shfl_xor(s, off);
    if (lane == 0) cand_sv[c] = s + (double)b_enc[h];
  }
  __syncthreads();   // drains zero-stores (vmcnt0 before barrier) + publishes cand_sv

  // exact rank (index tie-break), scatter
  for (int c = tid; c < C; c += 256) {
    const double v = cand_sv[c];
    const int h = cand_ix[c];
    int r = 0;
    for (int j = 0; j < C; ++j) {
      const double vj = cand_sv[j];
      r += ((vj > v) || (vj == v && cand_ix[j] < h)) ? 1 : 0;
    }
    if (r < k) {
      const float rv = (v > 0.0) ? (float)v : 0.f;
      hrow[h] = rv;
      tk_idx[(size_t)b * K_MAX + r] = h;
      tk_val[(size_t)b * K_MAX + r] = rv;
    }
  }
}

// ---------------- fallback: fp32 GEMM ----------------
__global__ __launch_bounds__(256) void enc_gemm_f32(
    const float* __restrict__ X, const float* __restrict__ W,
    const float* __restrict__ b_enc, const float* __restrict__ b_pre,
    float* __restrict__ pre, int D, int H)
{
  __shared__ float As[BK][BM + 4];
  __shared__ float Bs[BK][BN + 4];
  const int tid = threadIdx.x;
  const int m0 = blockIdx.y * BM;
  const int n0 = blockIdx.x * BN;
  const int tx = tid & 15, ty = tid >> 4;
  float acc[8][8];
#pragma unroll
  for (int i = 0; i < 8; ++i)
#pragma unroll
    for (int j = 0; j < 8; ++j) acc[i][j] = 0.f;

  for (int kb = 0; kb < D; kb += BK) {
#pragma unroll
    for (int t = 0; t < 2; ++t) {
      const int f4i = tid + t * 256;
      const int row = f4i >> 2;
      const int kq  = (f4i & 3) << 2;
      float4 xv = *reinterpret_cast<const float4*>(X + (size_t)(m0 + row) * D + kb + kq);
      float4 bp = *reinterpret_cast<const float4*>(b_pre + kb + kq);
      As[kq + 0][row] = xv.x - bp.x; As[kq + 1][row] = xv.y - bp.y;
      As[kq + 2][row] = xv.z - bp.z; As[kq + 3][row] = xv.w - bp.w;
      float4 wv = *reinterpret_cast<const float4*>(W + (size_t)(n0 + row) * D + kb + kq);
      Bs[kq + 0][row] = wv.x; Bs[kq + 1][row] = wv.y;
      Bs[kq + 2][row] = wv.z; Bs[kq + 3][row] = wv.w;
    }
    __syncthreads();
#pragma unroll
    for (int kk = 0; kk < BK; ++kk) {
      float4 a0 = *reinterpret_cast<const float4*>(&As[kk][ty * 8]);
      float4 a1 = *reinterpret_cast<const float4*>(&As[kk][ty * 8 + 4]);
      float4 b0 = *reinterpret_cast<const float4*>(&Bs[kk][tx * 8]);
      float4 b1 = *reinterpret_cast<const float4*>(&Bs[kk][tx * 8 + 4]);
      float av[8] = {a0.x, a0.y, a0.z, a0.w, a1.x, a1.y, a1.z, a1.w};
      float bv[8] = {b0.x, b0.y, b0.z, b0.w, b1.x, b1.y, b1.z, b1.w};
#pragma unroll
      for (int i = 0; i < 8; ++i)
#pragma unroll
        for (int j = 0; j < 8; ++j) acc[i][j] += av[i] * bv[j];
    }
    __syncthreads();
  }
#pragma unroll
  for (int i = 0; i < 8; ++i) {
    const size_t m = (size_t)(m0 + ty * 8 + i);
#pragma unroll
    for (int j = 0; j < 8; j += 4) {
      const int n = n0 + tx * 8 + j;
      float4 o;
      o.x = acc[i][j + 0] + b_enc[n + 0];
      o.y = acc[i][j + 1] + b_enc[n + 1];
      o.z = acc[i][j + 2] + b_enc[n + 2];
      o.w = acc[i][j + 3] + b_enc[n + 3];
      *reinterpret_cast<float4*>(pre + m * H + n) = o;
    }
  }
}

// ---------------- fallback: bisection top-k (reads f32 pre) ----------------
__global__ __launch_bounds__(256) void topk_refine(
    const float* __restrict__ X, const float* __restrict__ b_pre,
    const float* __restrict__ W, const float* __restrict__ b_enc,
    float* __restrict__ hidden, int* __restrict__ tk_idx, float* __restrict__ tk_val,
    const int* __restrict__ kptr, int D, int H, float margin)
{
  extern __shared__ char smem_raw[];
  double* cand_val = reinterpret_cast<double*>(smem_raw);
  float*  xr       = reinterpret_cast<float*>(cand_val + CAND_MAX);
  int*    cand_idx = reinterpret_cast<int*>(xr + D);
  int*    misc     = cand_idx + CAND_MAX;

  const int tid = threadIdx.x;
  const int b = blockIdx.x;
  const int k = min(*kptr, K_MAX);
  float* hrow = hidden + (size_t)b * H;

  for (int i = tid; i < NBITER + 2; i += 256) misc[i] = 0;
  for (int d = tid; d < D; d += 256) xr[d] = X[(size_t)b * D + d] - b_pre[d];

  float f[64];
#pragma unroll
  for (int i = 0; i < 16; ++i) {
    const int base = i * 1024 + tid * 4;
    float4 v = {-3e38f, -3e38f, -3e38f, -3e38f};
    if (base + 3 < H) v = *reinterpret_cast<const float4*>(hrow + base);
    f[4 * i + 0] = v.x; f[4 * i + 1] = v.y; f[4 * i + 2] = v.z; f[4 * i + 3] = v.w;
  }
  __syncthreads();

  float lo = -1e4f, hi = 1e4f;
  for (int it = 0; it < NBITER; ++it) {
    const float mid = 0.5f * (lo + hi);
    int cnt = 0;
#pragma unroll
    for (int j = 0; j < 64; ++j) cnt += (f[j] >= mid) ? 1 : 0;
    for (int off = 32; off; off >>= 1) cnt += __shfl_xor(cnt, off);
    if ((tid & 63) == 0) atomicAdd(&misc[it], cnt);
    __syncthreads();
    if (misc[it] >= k) lo = mid; else hi = mid;
  }

  const float thresh = lo - margin;
#pragma unroll
  for (int j = 0; j < 64; ++j) {
    if (f[j] >= thresh) {
      const int h = (j >> 2) * 1024 + tid * 4 + (j & 3);
      if (h < H) {
        int pos = atomicAdd(&misc[NBITER], 1);
        if (pos < CAND_MAX) cand_idx[pos] = h;
      }
    }
  }
  __syncthreads();
  const int C = min(misc[NBITER], CAND_MAX);

  const int wid = tid >> 6, lane = tid & 63;
  for (int c = wid; c < C; c += 4) {
    const int h = cand_idx[c];
    const float* wr = W + (size_t)h * D;
    double s = 0.0;
    for (int i = lane; i < D; i += 64) s += (double)xr[i] * (double)wr[i];
    for (int off = 32; off; off >>= 1) s += __shfl_xor(s, off);
    if (lane == 0) cand_val[c] = s + (double)b_enc[h];
  }
  __syncthreads();

  const float4 z4 = {0.f, 0.f, 0.f, 0.f};
  for (int i = tid; i < (H >> 2); i += 256)
    reinterpret_cast<float4*>(hrow)[i] = z4;
  __syncthreads();

  for (int c = tid; c < C; c += 256) {
    const double v = cand_val[c];
    const int h = cand_idx[c];
    int r = 0;
    for (int j = 0; j < C; ++j) {
      const double vj = cand_val[j];
      r += ((vj > v) || (vj == v && cand_idx[j] < h)) ? 1 : 0;
    }
    if (r < k) {
      const float rv = (v > 0.0) ? (float)v : 0.f;
      hrow[h] = rv;
      tk_idx[(size_t)b * K_MAX + r] = h;
      tk_val[(size_t)b * K_MAX + r] = rv;
    }
  }
}

// ---------------- kernel 3: W_dec [D,H] -> bf16 W_decT [H,D] ----------------
__global__ __launch_bounds__(256) void transpose_wdec_bf16(
    const float* __restrict__ Wsrc, unsigned short* __restrict__ WT, int D, int H)
{
  __shared__ float tile[32][33];
  const int c  = threadIdx.x & 31;
  const int r0 = threadIdx.x >> 5;
  const int h0 = blockIdx.x * 32;
  const int d0 = blockIdx.y * 32;
#pragma unroll
  for (int r = r0; r < 32; r += 8) {
    const int d = d0 + r, h = h0 + c;
    if (d < D && h < H) tile[r][c] = Wsrc[(size_t)d * H + h];
  }
  __syncthreads();
#pragma unroll
  for (int r = r0; r < 32; r += 8) {
    const int h = h0 + r, d = d0 + c;
    if (h < H && d < D) WT[(size_t)h * D + d] = f2bf(tile[c][r]);
  }
}

// ---------------- kernel 4: sparse decode + per-row squared error ----------------
__global__ __launch_bounds__(256) void decode_loss(
    const float* __restrict__ X, const float* __restrict__ b_pre,
    const float* __restrict__ b_dec, const float* __restrict__ Wfull,
    const unsigned short* __restrict__ WTb,
    const int* __restrict__ tk_idx, const float* __restrict__ tk_val,
    const int* __restrict__ kptr,
    float* __restrict__ recon, double* __restrict__ row_ssq,
    int D, int H, int useWT)
{
  __shared__ int   sidx[K_MAX];
  __shared__ float sval[K_MAX];
  __shared__ double sd[4];
  const int tid = threadIdx.x, b = blockIdx.x;
  const int k = min(*kptr, K_MAX);
  if (tid < k) {
    sidx[tid] = tk_idx[(size_t)b * K_MAX + tid];
    sval[tid] = tk_val[(size_t)b * K_MAX + tid];
  }
  __syncthreads();
  double ssq = 0.0;
  for (int d = tid; d < D; d += 256) {
    float a = b_dec[d] + b_pre[d];
    if (useWT) {
#pragma unroll 4
      for (int j = 0; j < k; ++j) a += sval[j] * bf2f(WTb[(size_t)sidx[j] * D + d]);
    } else {
#pragma unroll 4
      for (int j = 0; j < k; ++j) a += sval[j] * Wfull[(size_t)d * H + sidx[j]];
    }
    recon[(size_t)b * D + d] = a;
    const double diff = (double)a - (double)X[(size_t)b * D + d];
    ssq += diff * diff;
  }
  for (int off = 32; off; off >>= 1) ssq += __shfl_xor(ssq, off);
  if ((tid & 63) == 0) sd[tid >> 6] = ssq;
  __syncthreads();
  if (tid == 0) row_ssq[b] = sd[0] + sd[1] + sd[2] + sd[3];
}

// ---------------- kernel 5: finalize scalar losses ----------------
__global__ __launch_bounds__(256) void finalize_k(
    const double* __restrict__ row_ssq, const float* __restrict__ tk_val,
    const int* __restrict__ kptr, float* __restrict__ scalars, int Bdim, int D)
{
  __shared__ double sd[4];
  __shared__ int si[4];
  const int tid = threadIdx.x;
  const int k = min(*kptr, K_MAX);
  double s = 0.0;
  for (int i = tid; i < Bdim; i += 256) s += row_ssq[i];
  int cnt = 0;
  for (int i = tid; i < Bdim * k; i += 256) {
    const int b = i / k, j = i - b * k;
    cnt += (tk_val[(size_t)b * K_MAX + j] > 0.f) ? 1 : 0;
  }
  for (int off = 32; off; off >>= 1) { s += __shfl_xor(s, off); cnt += __shfl_xor(cnt, off); }
  if ((tid & 63) == 0) { sd[tid >> 6] = s; si[tid >> 6] = cnt; }
  __syncthreads();
  if (tid == 0) {
    double st = 0; int ct = 0;
    for (int w = 0; w < 4; ++w) { st += sd[w]; ct += si[w]; }
    const double rl = st / ((double)Bdim * (double)D);
    scalars[0] = (float)rl;
    scalars[1] = (float)rl;
    scalars[2] = 0.f;
    scalars[3] = (float)((double)ct / Bdim);
  }
}

extern "C" void kernel_launch(void* const* d_in, const int* in_sizes, int n_in,
                              void* d_out, int out_size, void* d_ws, size_t ws_size,
                              hipStream_t stream)
{
  const float* x     = (const float*)d_in[0];
  const float* W_enc = (const float*)d_in[1];
  const float* b_enc = (const float*)d_in[2];
  const float* W_dec = (const float*)d_in[3];
  const float* b_dec = (const float*)d_in[4];
  const float* b_pre = (const float*)d_in[5];
  const int*   kptr  = (const int*)d_in[6];

  const int D = in_sizes[4];          // 1280
  const int H = in_sizes[2];          // 16384
  const int B = in_sizes[0] / D;      // 8192

  float* recon   = (float*)d_out;
  float* hidden  = recon + (size_t)B * D;       // temporarily holds pre keys / f32 pre
  float* scalars = hidden + (size_t)B * H;

  char* w = (char*)d_ws;
  int*    tk_idx  = (int*)w;    w += (size_t)B * K_MAX * sizeof(int);
  float*  tk_val  = (float*)w;  w += (size_t)B * K_MAX * sizeof(float);
  double* row_ssq = (double*)w; w += (size_t)B * sizeof(double);

  unsigned short* Xb = (unsigned short*)w;
  const size_t xb_bytes = (size_t)B * D * sizeof(unsigned short);
  unsigned short* Wb = (unsigned short*)(w + xb_bytes);
  const size_t wb_bytes = (size_t)H * D * sizeof(unsigned short);
  const size_t after_bf16 = (size_t)(w - (char*)d_ws) + xb_bytes + wb_bytes;
  const int useBF16 = (ws_size >= after_bf16) ? 1 : 0;

  char* wt_base = useBF16 ? (w + xb_bytes + wb_bytes) : w;
  unsigned short* WTb = (unsigned short*)wt_base;
  const size_t wt_need = (size_t)(wt_base - (char*)d_ws) + (size_t)D * H * sizeof(unsigned short);
  const int useWT = (ws_size >= wt_need) ? 1 : 0;

  const bool fast_ok = (D % 32 == 0) && (D % 4 == 0) && (D <= D_MAX) &&
                       (H == H_FIX) && (B % 128 == 0);

  if (useBF16 && fast_ok) {
    const size_t tx4 = (size_t)B * D / 4, tw4 = (size_t)H * D / 4;
    prep_xb<<<2048, 256, 0, stream>>>(x, b_pre, Xb, D, tx4);
    prep_wb<<<2048, 256, 0, stream>>>(W_enc, Wb, tw4);
    dim3 gg(H / 128, B / 128);
    enc_gemm_bf16k<<<gg, 256, 0, stream>>>(Xb, Wb, b_enc, hidden, D, H);
    // margin covers bf16-input GEMM error (sigma ~2.3e-3; 0.10 = 43 sigma)
    topk_select<<<B, 256, 0, stream>>>(x, b_pre, W_enc, b_enc, hidden,
                                       tk_idx, tk_val, kptr, D, 0.10f);
  } else {
    dim3 gg(H / BN, B / BM);
    enc_gemm_f32<<<gg, 256, 0, stream>>>(x, W_enc, b_enc, b_pre, hidden, D, H);
    const size_t sh = CAND_MAX * sizeof(double) + (size_t)D * sizeof(float)
                    + CAND_MAX * sizeof(int) + (NBITER + 8) * sizeof(int);
    topk_refine<<<B, 256, sh, stream>>>(x, b_pre, W_enc, b_enc, hidden,
                                        tk_idx, tk_val, kptr, D, H, 1e-3f);
  }

  if (useWT)
    transpose_wdec_bf16<<<dim3((H + 31) / 32, (D + 31) / 32), 256, 0, stream>>>(W_dec, WTb, D, H);

  decode_loss<<<B, 256, 0, stream>>>(x, b_pre, b_dec, W_dec, WTb,
                                     tk_idx, tk_val, kptr, recon, row_ssq, D, H, useWT);

  finalize_k<<<1, 256, 0, stream>>>(row_ssq, tk_val, kptr, scalars, B, D);
}

// Round 5
// 2029.037 us; speedup vs baseline: 3.0232x; 1.2037x over previous
//
#include <hip/hip_runtime.h>
#include <hip/hip_bf16.h>

constexpr int K_MAX    = 128;   // max supported k (actual k=64 read from device)
constexpr int CAND_MAX = 512;   // candidate cap per row
constexpr int BM = 128, BN = 128, BK = 16;
constexpr int NBITER = 42;      // fallback bisection iterations
constexpr int D_MAX   = 2048;   // fast path requires D <= D_MAX
constexpr int H_FIX   = 16384;  // fast path requires H == H_FIX

typedef __attribute__((ext_vector_type(8))) short bf16x8;
typedef __attribute__((ext_vector_type(8))) unsigned short u16x8;
typedef __attribute__((ext_vector_type(4))) float f32x4;

__device__ inline unsigned short f2bf(float f) {   // round-to-nearest-even
  unsigned u = __float_as_uint(f);
  return (unsigned short)((u + 0x7fff + ((u >> 16) & 1)) >> 16);
}
// monotone 16-bit key: key order == value order (handles negatives)
__device__ inline unsigned short key_of(float f) {
  unsigned short b = f2bf(f);
  return b ^ ((b & 0x8000) ? 0xFFFF : 0x8000);
}
__device__ inline float val_of_key(unsigned short kk) {
  unsigned short b = (kk & 0x8000) ? (unsigned short)(kk ^ 0x8000)
                                   : (unsigned short)(kk ^ 0xFFFF);
  return __uint_as_float(((unsigned)b) << 16);
}
__device__ inline float bf2f(unsigned short b) {
  return __uint_as_float(((unsigned)b) << 16);
}

// ---------------- prep: Xb = bf16(x - b_pre), Wb = bf16(W_enc) ----------------
__global__ __launch_bounds__(256) void prep_xb(
    const float* __restrict__ x, const float* __restrict__ b_pre,
    unsigned short* __restrict__ Xb, int D, size_t total4)
{
  for (size_t i = blockIdx.x * 256 + threadIdx.x; i < total4; i += (size_t)gridDim.x * 256) {
    const size_t e = i * 4;
    const int d = (int)(e % D);
    float4 xv = *reinterpret_cast<const float4*>(x + e);
    float4 bp = *reinterpret_cast<const float4*>(b_pre + d);
    ushort4 o;
    o.x = f2bf(xv.x - bp.x); o.y = f2bf(xv.y - bp.y);
    o.z = f2bf(xv.z - bp.z); o.w = f2bf(xv.w - bp.w);
    *reinterpret_cast<ushort4*>(Xb + e) = o;
  }
}

__global__ __launch_bounds__(256) void prep_wb(
    const float* __restrict__ W, unsigned short* __restrict__ Wb, size_t total4)
{
  for (size_t i = blockIdx.x * 256 + threadIdx.x; i < total4; i += (size_t)gridDim.x * 256) {
    const size_t e = i * 4;
    float4 wv = *reinterpret_cast<const float4*>(W + e);
    ushort4 o;
    o.x = f2bf(wv.x); o.y = f2bf(wv.y); o.z = f2bf(wv.z); o.w = f2bf(wv.w);
    *reinterpret_cast<ushort4*>(Wb + e) = o;
  }
}

// ---------------- kernel 1: encoder GEMM, bf16 MFMA, writes monotone u16 keys ----------------
__global__ __launch_bounds__(256) void enc_gemm_bf16k(
    const unsigned short* __restrict__ Xb, const unsigned short* __restrict__ Wb,
    const float* __restrict__ b_enc, float* __restrict__ pre, int D, int H)
{
  __shared__ unsigned short As[128 * 32];   // [row][k] linear, 64B rows
  __shared__ unsigned short Bs[128 * 32];
  const int tid  = threadIdx.x;
  const int wave = tid >> 6, lane = tid & 63;
  const int m0 = blockIdx.y * 128, n0 = blockIdx.x * 128;
  const int wm = (wave >> 1) * 64, wn = (wave & 1) * 64;
  const int l16 = lane & 15, lhi = lane >> 4;

  f32x4 acc[4][4];
#pragma unroll
  for (int i = 0; i < 4; ++i)
#pragma unroll
    for (int j = 0; j < 4; ++j) acc[i][j] = (f32x4){0.f, 0.f, 0.f, 0.f};

  for (int kb = 0; kb < D; kb += 32) {
#pragma unroll
    for (int i = 0; i < 2; ++i) {
      const int base = wave * 64 + i * 256;
      const int idx  = base + lane;
      const int row  = idx >> 2, ch = idx & 3;
      const unsigned short* gA = Xb + (size_t)(m0 + row) * D + kb + ch * 8;
      __builtin_amdgcn_global_load_lds(
          (const __attribute__((address_space(1))) unsigned int*)gA,
          (__attribute__((address_space(3))) unsigned int*)(As + (size_t)base * 8),
          16, 0, 0);
      const unsigned short* gB = Wb + (size_t)(n0 + row) * D + kb + ch * 8;
      __builtin_amdgcn_global_load_lds(
          (const __attribute__((address_space(1))) unsigned int*)gB,
          (__attribute__((address_space(3))) unsigned int*)(Bs + (size_t)base * 8),
          16, 0, 0);
    }
    __syncthreads();

    bf16x8 af[4], bfr[4];
#pragma unroll
    for (int mi = 0; mi < 4; ++mi)
      af[mi] = *reinterpret_cast<const bf16x8*>(As + (size_t)(wm + mi * 16 + l16) * 32 + lhi * 8);
#pragma unroll
    for (int ni = 0; ni < 4; ++ni)
      bfr[ni] = *reinterpret_cast<const bf16x8*>(Bs + (size_t)(wn + ni * 16 + l16) * 32 + lhi * 8);
#pragma unroll
    for (int mi = 0; mi < 4; ++mi)
#pragma unroll
      for (int ni = 0; ni < 4; ++ni)
        acc[mi][ni] = __builtin_amdgcn_mfma_f32_16x16x32_bf16(af[mi], bfr[ni], acc[mi][ni], 0, 0, 0);
    __syncthreads();
  }

#pragma unroll
  for (int ni = 0; ni < 4; ++ni) {
    const int n = n0 + wn + ni * 16 + l16;
    const float be = b_enc[n];
#pragma unroll
    for (int mi = 0; mi < 4; ++mi) {
      const int mbase = m0 + wm + mi * 16 + lhi * 4;
#pragma unroll
      for (int r = 0; r < 4; ++r) {
        unsigned short* prow = (unsigned short*)(pre + (size_t)(mbase + r) * H);
        prow[n] = key_of(acc[mi][ni][r] + be);
      }
    }
  }
}

// ---------------- split kernel A: per-row threshold + candidate collect ----------------
__global__ __launch_bounds__(256) void topk_thresh(
    const float* __restrict__ hidden, int* __restrict__ cand_ix,
    int* __restrict__ cand_cnt, const int* __restrict__ kptr, float margin)
{
  constexpr int H = H_FIX, NC = H_FIX / (256 * 8);
  __shared__ int hist[4096];
  __shared__ int chunk[256];
  __shared__ int misc[8];

  const int tid = threadIdx.x, b = blockIdx.x;
  const int k = min(*kptr, K_MAX);
  const unsigned short* krow = (const unsigned short*)(hidden + (size_t)b * H);

  if (tid < 8) misc[tid] = 0;
  for (int i = tid; i < 4096; i += 256) hist[i] = 0;

  u16x8 kv[NC];   // 64 keys/thread in 16 VGPRs, statically indexed
#pragma unroll
  for (int i = 0; i < NC; ++i)
    kv[i] = *reinterpret_cast<const u16x8*>(krow + ((size_t)i * 256 + tid) * 8);
  __syncthreads();

#pragma unroll
  for (int i = 0; i < NC; ++i)
#pragma unroll
    for (int j = 0; j < 8; ++j)
      atomicAdd(&hist[((unsigned)(unsigned short)kv[i][j]) >> 4], 1);
  __syncthreads();

  int csum = 0;
#pragma unroll
  for (int j = 0; j < 16; ++j) csum += hist[tid * 16 + j];
  chunk[tid] = csum;
  __syncthreads();
  int gt = 0;
  for (int j = tid + 1; j < 256; ++j) gt += chunk[j];
  {
    int run = gt;
#pragma unroll
    for (int j = 15; j >= 0; --j) {
      const int hc = hist[tid * 16 + j];
      if (run < k && k <= run + hc) { misc[0] = tid * 16 + j; misc[1] = run; }
      run += hc;
    }
  }
  __syncthreads();
  const int b1 = misc[0];
  if (tid < 16) chunk[tid] = 0;
  __syncthreads();
#pragma unroll
  for (int i = 0; i < NC; ++i)
#pragma unroll
    for (int j = 0; j < 8; ++j) {
      const unsigned kk = (unsigned)(unsigned short)kv[i][j];
      if ((int)(kk >> 4) == b1) atomicAdd(&chunk[kk & 15], 1);
    }
  __syncthreads();
  if (tid == 0) {
    int run = misc[1];
    int K16 = b1 << 4;
    for (int j = 15; j >= 0; --j) {
      const int c = chunk[j];
      if (run < k && k <= run + c) K16 = (b1 << 4) | j;
      run += c;
    }
    const float vthr = val_of_key((unsigned short)K16) - margin;
    int kt = (int)key_of(vthr);
    if (kt > K16) kt = K16;
    misc[2] = kt;
  }
  __syncthreads();
  const unsigned kthr = (unsigned)misc[2];

#pragma unroll
  for (int i = 0; i < NC; ++i)
#pragma unroll
    for (int j = 0; j < 8; ++j) {
      if ((unsigned)(unsigned short)kv[i][j] >= kthr) {
        const int pos = atomicAdd(&misc[3], 1);
        if (pos < CAND_MAX) cand_ix[(size_t)b * CAND_MAX + pos] = (i * 256 + tid) * 8 + j;
      }
    }
  __syncthreads();
  if (tid == 0) cand_cnt[b] = min(misc[3], CAND_MAX);
}

// ---------------- split kernel B: exact f64 dot products for candidates ----------------
__global__ __launch_bounds__(256) void refine_f64(
    const float* __restrict__ X, const float* __restrict__ b_pre,
    const float* __restrict__ W, const float* __restrict__ b_enc,
    const int* __restrict__ cand_ix, const int* __restrict__ cand_cnt,
    double* __restrict__ cand_sv, int D)
{
  __shared__ float xr[D_MAX];
  const int tid = threadIdx.x, b = blockIdx.x;
  const int C = cand_cnt[b];
  for (int d = tid; d < D; d += 256) xr[d] = X[(size_t)b * D + d] - b_pre[d];
  __syncthreads();
  const int wid = tid >> 6, lane = tid & 63;
  for (int c = wid; c < C; c += 4) {
    const int h = cand_ix[(size_t)b * CAND_MAX + c];
    const float* wr = W + (size_t)h * D;
    double s = 0.0;
    for (int i = lane; i < D; i += 64) s += (double)xr[i] * (double)wr[i];
    for (int off = 32; off; off >>= 1) s += __shfl_xor(s, off);
    if (lane == 0) cand_sv[(size_t)b * CAND_MAX + c] = s + (double)b_enc[h];
  }
}

// ---------------- split kernel C: zero row, exact rank, scatter ----------------
__global__ __launch_bounds__(256) void rank_scatter(
    const int* __restrict__ cand_ix, const double* __restrict__ cand_sv,
    const int* __restrict__ cand_cnt, const int* __restrict__ kptr,
    float* __restrict__ hidden, int* __restrict__ tk_idx, float* __restrict__ tk_val)
{
  constexpr int H = H_FIX;
  __shared__ double sv[CAND_MAX];
  __shared__ int    ix[CAND_MAX];
  const int tid = threadIdx.x, b = blockIdx.x;
  const int k = min(*kptr, K_MAX);
  const int C = cand_cnt[b];
  float* hrow = hidden + (size_t)b * H;

  for (int c = tid; c < C; c += 256) {
    sv[c] = cand_sv[(size_t)b * CAND_MAX + c];
    ix[c] = cand_ix[(size_t)b * CAND_MAX + c];
  }
  const float4 z4 = {0.f, 0.f, 0.f, 0.f};
  for (int i = tid; i < (H >> 2); i += 256)
    reinterpret_cast<float4*>(hrow)[i] = z4;
  __syncthreads();

  for (int c = tid; c < C; c += 256) {
    const double v = sv[c];
    const int h = ix[c];
    int r = 0;
    for (int j = 0; j < C; ++j) {
      const double vj = sv[j];
      r += ((vj > v) || (vj == v && ix[j] < h)) ? 1 : 0;
    }
    if (r < k) {
      const float rv = (v > 0.0) ? (float)v : 0.f;
      hrow[h] = rv;
      tk_idx[(size_t)b * K_MAX + r] = h;
      tk_val[(size_t)b * K_MAX + r] = rv;
    }
  }
}

// ---------------- fused fallback: single-pass select (used when ws is short) ----------------
__global__ __launch_bounds__(256, 2) void topk_select(
    const float* __restrict__ X, const float* __restrict__ b_pre,
    const float* __restrict__ W, const float* __restrict__ b_enc,
    float* __restrict__ hidden, int* __restrict__ tk_idx, float* __restrict__ tk_val,
    const int* __restrict__ kptr, int D, float margin)
{
  constexpr int H = H_FIX, NC = H_FIX / (256 * 8);
  __shared__ double cand_sv[CAND_MAX];
  __shared__ float  xr[D_MAX];
  __shared__ int    cand_ix[CAND_MAX];
  __shared__ int    hist[4096];
  __shared__ int    chunk[256];
  __shared__ int    misc[8];

  const int tid = threadIdx.x, b = blockIdx.x;
  const int k = min(*kptr, K_MAX);
  float* hrow = hidden + (size_t)b * H;
  const unsigned short* krow = (const unsigned short*)hrow;

  if (tid < 8) misc[tid] = 0;
  for (int i = tid; i < 4096; i += 256) hist[i] = 0;
  for (int d = tid; d < D; d += 256) xr[d] = X[(size_t)b * D + d] - b_pre[d];

  u16x8 kv[NC];
#pragma unroll
  for (int i = 0; i < NC; ++i)
    kv[i] = *reinterpret_cast<const u16x8*>(krow + ((size_t)i * 256 + tid) * 8);
  __syncthreads();

#pragma unroll
  for (int i = 0; i < NC; ++i)
#pragma unroll
    for (int j = 0; j < 8; ++j)
      atomicAdd(&hist[((unsigned)(unsigned short)kv[i][j]) >> 4], 1);
  __syncthreads();

  int csum = 0;
#pragma unroll
  for (int j = 0; j < 16; ++j) csum += hist[tid * 16 + j];
  chunk[tid] = csum;
  __syncthreads();
  int gt = 0;
  for (int j = tid + 1; j < 256; ++j) gt += chunk[j];
  {
    int run = gt;
#pragma unroll
    for (int j = 15; j >= 0; --j) {
      const int hc = hist[tid * 16 + j];
      if (run < k && k <= run + hc) { misc[0] = tid * 16 + j; misc[1] = run; }
      run += hc;
    }
  }
  __syncthreads();
  const int b1 = misc[0];
  if (tid < 16) chunk[tid] = 0;
  __syncthreads();
#pragma unroll
  for (int i = 0; i < NC; ++i)
#pragma unroll
    for (int j = 0; j < 8; ++j) {
      const unsigned kk = (unsigned)(unsigned short)kv[i][j];
      if ((int)(kk >> 4) == b1) atomicAdd(&chunk[kk & 15], 1);
    }
  __syncthreads();
  if (tid == 0) {
    int run = misc[1];
    int K16 = b1 << 4;
    for (int j = 15; j >= 0; --j) {
      const int c = chunk[j];
      if (run < k && k <= run + c) K16 = (b1 << 4) | j;
      run += c;
    }
    const float vthr = val_of_key((unsigned short)K16) - margin;
    int kt = (int)key_of(vthr);
    if (kt > K16) kt = K16;
    misc[2] = kt;
  }
  __syncthreads();
  const unsigned kthr = (unsigned)misc[2];

#pragma unroll
  for (int i = 0; i < NC; ++i)
#pragma unroll
    for (int j = 0; j < 8; ++j) {
      if ((unsigned)(unsigned short)kv[i][j] >= kthr) {
        const int pos = atomicAdd(&misc[3], 1);
        if (pos < CAND_MAX) cand_ix[pos] = (i * 256 + tid) * 8 + j;
      }
    }
  __syncthreads();
  const int C = min(misc[3], CAND_MAX);

  const float4 z4 = {0.f, 0.f, 0.f, 0.f};
  for (int i = tid; i < (H >> 2); i += 256)
    reinterpret_cast<float4*>(hrow)[i] = z4;

  const int wid = tid >> 6, lane = tid & 63;
  for (int c = wid; c < C; c += 4) {
    const int h = cand_ix[c];
    const float* wr = W + (size_t)h * D;
    double s = 0.0;
    for (int i = lane; i < D; i += 64) s += (double)xr[i] * (double)wr[i];
    for (int off = 32; off; off >>= 1) s += __shfl_xor(s, off);
    if (lane == 0) cand_sv[c] = s + (double)b_enc[h];
  }
  __syncthreads();

  for (int c = tid; c < C; c += 256) {
    const double v = cand_sv[c];
    const int h = cand_ix[c];
    int r = 0;
    for (int j = 0; j < C; ++j) {
      const double vj = cand_sv[j];
      r += ((vj > v) || (vj == v && cand_ix[j] < h)) ? 1 : 0;
    }
    if (r < k) {
      const float rv = (v > 0.0) ? (float)v : 0.f;
      hrow[h] = rv;
      tk_idx[(size_t)b * K_MAX + r] = h;
      tk_val[(size_t)b * K_MAX + r] = rv;
    }
  }
}

// ---------------- fallback: fp32 GEMM ----------------
__global__ __launch_bounds__(256) void enc_gemm_f32(
    const float* __restrict__ X, const float* __restrict__ W,
    const float* __restrict__ b_enc, const float* __restrict__ b_pre,
    float* __restrict__ pre, int D, int H)
{
  __shared__ float As[BK][BM + 4];
  __shared__ float Bs[BK][BN + 4];
  const int tid = threadIdx.x;
  const int m0 = blockIdx.y * BM;
  const int n0 = blockIdx.x * BN;
  const int tx = tid & 15, ty = tid >> 4;
  float acc[8][8];
#pragma unroll
  for (int i = 0; i < 8; ++i)
#pragma unroll
    for (int j = 0; j < 8; ++j) acc[i][j] = 0.f;

  for (int kb = 0; kb < D; kb += BK) {
#pragma unroll
    for (int t = 0; t < 2; ++t) {
      const int f4i = tid + t * 256;
      const int row = f4i >> 2;
      const int kq  = (f4i & 3) << 2;
      float4 xv = *reinterpret_cast<const float4*>(X + (size_t)(m0 + row) * D + kb + kq);
      float4 bp = *reinterpret_cast<const float4*>(b_pre + kb + kq);
      As[kq + 0][row] = xv.x - bp.x; As[kq + 1][row] = xv.y - bp.y;
      As[kq + 2][row] = xv.z - bp.z; As[kq + 3][row] = xv.w - bp.w;
      float4 wv = *reinterpret_cast<const float4*>(W + (size_t)(n0 + row) * D + kb + kq);
      Bs[kq + 0][row] = wv.x; Bs[kq + 1][row] = wv.y;
      Bs[kq + 2][row] = wv.z; Bs[kq + 3][row] = wv.w;
    }
    __syncthreads();
#pragma unroll
    for (int kk = 0; kk < BK; ++kk) {
      float4 a0 = *reinterpret_cast<const float4*>(&As[kk][ty * 8]);
      float4 a1 = *reinterpret_cast<const float4*>(&As[kk][ty * 8 + 4]);
      float4 b0 = *reinterpret_cast<const float4*>(&Bs[kk][tx * 8]);
      float4 b1 = *reinterpret_cast<const float4*>(&Bs[kk][tx * 8 + 4]);
      float av[8] = {a0.x, a0.y, a0.z, a0.w, a1.x, a1.y, a1.z, a1.w};
      float bv[8] = {b0.x, b0.y, b0.z, b0.w, b1.x, b1.y, b1.z, b1.w};
#pragma unroll
      for (int i = 0; i < 8; ++i)
#pragma unroll
        for (int j = 0; j < 8; ++j) acc[i][j] += av[i] * bv[j];
    }
    __syncthreads();
  }
#pragma unroll
  for (int i = 0; i < 8; ++i) {
    const size_t m = (size_t)(m0 + ty * 8 + i);
#pragma unroll
    for (int j = 0; j < 8; j += 4) {
      const int n = n0 + tx * 8 + j;
      float4 o;
      o.x = acc[i][j + 0] + b_enc[n + 0];
      o.y = acc[i][j + 1] + b_enc[n + 1];
      o.z = acc[i][j + 2] + b_enc[n + 2];
      o.w = acc[i][j + 3] + b_enc[n + 3];
      *reinterpret_cast<float4*>(pre + m * H + n) = o;
    }
  }
}

// ---------------- fallback: bisection top-k (reads f32 pre) ----------------
__global__ __launch_bounds__(256) void topk_refine(
    const float* __restrict__ X, const float* __restrict__ b_pre,
    const float* __restrict__ W, const float* __restrict__ b_enc,
    float* __restrict__ hidden, int* __restrict__ tk_idx, float* __restrict__ tk_val,
    const int* __restrict__ kptr, int D, int H, float margin)
{
  extern __shared__ char smem_raw[];
  double* cand_val = reinterpret_cast<double*>(smem_raw);
  float*  xr       = reinterpret_cast<float*>(cand_val + CAND_MAX);
  int*    cand_idx = reinterpret_cast<int*>(xr + D);
  int*    misc     = cand_idx + CAND_MAX;

  const int tid = threadIdx.x;
  const int b = blockIdx.x;
  const int k = min(*kptr, K_MAX);
  float* hrow = hidden + (size_t)b * H;

  for (int i = tid; i < NBITER + 2; i += 256) misc[i] = 0;
  for (int d = tid; d < D; d += 256) xr[d] = X[(size_t)b * D + d] - b_pre[d];

  float f[64];
#pragma unroll
  for (int i = 0; i < 16; ++i) {
    const int base = i * 1024 + tid * 4;
    float4 v = {-3e38f, -3e38f, -3e38f, -3e38f};
    if (base + 3 < H) v = *reinterpret_cast<const float4*>(hrow + base);
    f[4 * i + 0] = v.x; f[4 * i + 1] = v.y; f[4 * i + 2] = v.z; f[4 * i + 3] = v.w;
  }
  __syncthreads();

  float lo = -1e4f, hi = 1e4f;
  for (int it = 0; it < NBITER; ++it) {
    const float mid = 0.5f * (lo + hi);
    int cnt = 0;
#pragma unroll
    for (int j = 0; j < 64; ++j) cnt += (f[j] >= mid) ? 1 : 0;
    for (int off = 32; off; off >>= 1) cnt += __shfl_xor(cnt, off);
    if ((tid & 63) == 0) atomicAdd(&misc[it], cnt);
    __syncthreads();
    if (misc[it] >= k) lo = mid; else hi = mid;
  }

  const float thresh = lo - margin;
#pragma unroll
  for (int j = 0; j < 64; ++j) {
    if (f[j] >= thresh) {
      const int h = (j >> 2) * 1024 + tid * 4 + (j & 3);
      if (h < H) {
        int pos = atomicAdd(&misc[NBITER], 1);
        if (pos < CAND_MAX) cand_idx[pos] = h;
      }
    }
  }
  __syncthreads();
  const int C = min(misc[NBITER], CAND_MAX);

  const int wid = tid >> 6, lane = tid & 63;
  for (int c = wid; c < C; c += 4) {
    const int h = cand_idx[c];
    const float* wr = W + (size_t)h * D;
    double s = 0.0;
    for (int i = lane; i < D; i += 64) s += (double)xr[i] * (double)wr[i];
    for (int off = 32; off; off >>= 1) s += __shfl_xor(s, off);
    if (lane == 0) cand_val[c] = s + (double)b_enc[h];
  }
  __syncthreads();

  const float4 z4 = {0.f, 0.f, 0.f, 0.f};
  for (int i = tid; i < (H >> 2); i += 256)
    reinterpret_cast<float4*>(hrow)[i] = z4;
  __syncthreads();

  for (int c = tid; c < C; c += 256) {
    const double v = cand_val[c];
    const int h = cand_idx[c];
    int r = 0;
    for (int j = 0; j < C; ++j) {
      const double vj = cand_val[j];
      r += ((vj > v) || (vj == v && cand_idx[j] < h)) ? 1 : 0;
    }
    if (r < k) {
      const float rv = (v > 0.0) ? (float)v : 0.f;
      hrow[h] = rv;
      tk_idx[(size_t)b * K_MAX + r] = h;
      tk_val[(size_t)b * K_MAX + r] = rv;
    }
  }
}

// ---------------- kernel 3: W_dec [D,H] -> bf16 W_decT [H,D] ----------------
__global__ __launch_bounds__(256) void transpose_wdec_bf16(
    const float* __restrict__ Wsrc, unsigned short* __restrict__ WT, int D, int H)
{
  __shared__ float tile[32][33];
  const int c  = threadIdx.x & 31;
  const int r0 = threadIdx.x >> 5;
  const int h0 = blockIdx.x * 32;
  const int d0 = blockIdx.y * 32;
#pragma unroll
  for (int r = r0; r < 32; r += 8) {
    const int d = d0 + r, h = h0 + c;
    if (d < D && h < H) tile[r][c] = Wsrc[(size_t)d * H + h];
  }
  __syncthreads();
#pragma unroll
  for (int r = r0; r < 32; r += 8) {
    const int h = h0 + r, d = d0 + c;
    if (h < H && d < D) WT[(size_t)h * D + d] = f2bf(tile[c][r]);
  }
}

// ---------------- kernel 4: sparse decode + per-row squared error ----------------
__global__ __launch_bounds__(256) void decode_loss(
    const float* __restrict__ X, const float* __restrict__ b_pre,
    const float* __restrict__ b_dec, const float* __restrict__ Wfull,
    const unsigned short* __restrict__ WTb,
    const int* __restrict__ tk_idx, const float* __restrict__ tk_val,
    const int* __restrict__ kptr,
    float* __restrict__ recon, double* __restrict__ row_ssq,
    int D, int H, int useWT)
{
  __shared__ int   sidx[K_MAX];
  __shared__ float sval[K_MAX];
  __shared__ double sd[4];
  const int tid = threadIdx.x, b = blockIdx.x;
  const int k = min(*kptr, K_MAX);
  if (tid < k) {
    sidx[tid] = tk_idx[(size_t)b * K_MAX + tid];
    sval[tid] = tk_val[(size_t)b * K_MAX + tid];
  }
  __syncthreads();
  double ssq = 0.0;
  for (int d = tid; d < D; d += 256) {
    float a = b_dec[d] + b_pre[d];
    if (useWT) {
#pragma unroll 4
      for (int j = 0; j < k; ++j) a += sval[j] * bf2f(WTb[(size_t)sidx[j] * D + d]);
    } else {
#pragma unroll 4
      for (int j = 0; j < k; ++j) a += sval[j] * Wfull[(size_t)d * H + sidx[j]];
    }
    recon[(size_t)b * D + d] = a;
    const double diff = (double)a - (double)X[(size_t)b * D + d];
    ssq += diff * diff;
  }
  for (int off = 32; off; off >>= 1) ssq += __shfl_xor(ssq, off);
  if ((tid & 63) == 0) sd[tid >> 6] = ssq;
  __syncthreads();
  if (tid == 0) row_ssq[b] = sd[0] + sd[1] + sd[2] + sd[3];
}

// ---------------- kernel 5: finalize scalar losses ----------------
__global__ __launch_bounds__(256) void finalize_k(
    const double* __restrict__ row_ssq, const float* __restrict__ tk_val,
    const int* __restrict__ kptr, float* __restrict__ scalars, int Bdim, int D)
{
  __shared__ double sd[4];
  __shared__ int si[4];
  const int tid = threadIdx.x;
  const int k = min(*kptr, K_MAX);
  double s = 0.0;
  for (int i = tid; i < Bdim; i += 256) s += row_ssq[i];
  int cnt = 0;
  for (int i = tid; i < Bdim * k; i += 256) {
    const int b = i / k, j = i - b * k;
    cnt += (tk_val[(size_t)b * K_MAX + j] > 0.f) ? 1 : 0;
  }
  for (int off = 32; off; off >>= 1) { s += __shfl_xor(s, off); cnt += __shfl_xor(cnt, off); }
  if ((tid & 63) == 0) { sd[tid >> 6] = s; si[tid >> 6] = cnt; }
  __syncthreads();
  if (tid == 0) {
    double st = 0; int ct = 0;
    for (int w = 0; w < 4; ++w) { st += sd[w]; ct += si[w]; }
    const double rl = st / ((double)Bdim * (double)D);
    scalars[0] = (float)rl;
    scalars[1] = (float)rl;
    scalars[2] = 0.f;
    scalars[3] = (float)((double)ct / Bdim);
  }
}

extern "C" void kernel_launch(void* const* d_in, const int* in_sizes, int n_in,
                              void* d_out, int out_size, void* d_ws, size_t ws_size,
                              hipStream_t stream)
{
  const float* x     = (const float*)d_in[0];
  const float* W_enc = (const float*)d_in[1];
  const float* b_enc = (const float*)d_in[2];
  const float* W_dec = (const float*)d_in[3];
  const float* b_dec = (const float*)d_in[4];
  const float* b_pre = (const float*)d_in[5];
  const int*   kptr  = (const int*)d_in[6];

  const int D = in_sizes[4];          // 1280
  const int H = in_sizes[2];          // 16384
  const int B = in_sizes[0] / D;      // 8192

  float* recon   = (float*)d_out;
  float* hidden  = recon + (size_t)B * D;       // temporarily holds pre keys / f32 pre
  float* scalars = hidden + (size_t)B * H;

  // ---- workspace layout (single running cursor) ----
  size_t off = 0;
  int* tk_idx = (int*)((char*)d_ws + off);        off += (size_t)B * K_MAX * sizeof(int);
  float* tk_val = (float*)((char*)d_ws + off);    off += (size_t)B * K_MAX * sizeof(float);
  off = (off + 7) & ~(size_t)7;
  double* row_ssq = (double*)((char*)d_ws + off); off += (size_t)B * sizeof(double);

  unsigned short* Xb = (unsigned short*)((char*)d_ws + off);
  off += (size_t)B * D * sizeof(unsigned short);
  unsigned short* Wb = (unsigned short*)((char*)d_ws + off);
  off += (size_t)H * D * sizeof(unsigned short);
  const int useBF16 = (off <= ws_size) ? 1 : 0;

  if (!useBF16) off = (size_t)B * K_MAX * sizeof(int) + (size_t)B * K_MAX * sizeof(float);
  if (!useBF16) { off = (off + 7) & ~(size_t)7; off += (size_t)B * sizeof(double); }

  unsigned short* WTb = (unsigned short*)((char*)d_ws + off);
  off += (size_t)D * H * sizeof(unsigned short);
  const int useWT = (off <= ws_size) ? 1 : 0;

  int* cand_ix = (int*)((char*)d_ws + off);       off += (size_t)B * CAND_MAX * sizeof(int);
  int* cand_cnt = (int*)((char*)d_ws + off);      off += (size_t)B * sizeof(int);
  off = (off + 7) & ~(size_t)7;
  double* cand_sv = (double*)((char*)d_ws + off); off += (size_t)B * CAND_MAX * sizeof(double);
  const int useSPLIT = (useBF16 && useWT && off <= ws_size) ? 1 : 0;

  const bool fast_ok = (D % 32 == 0) && (D % 4 == 0) && (D <= D_MAX) &&
                       (H == H_FIX) && (B % 128 == 0);

  if (useBF16 && fast_ok) {
    const size_t tx4 = (size_t)B * D / 4, tw4 = (size_t)H * D / 4;
    prep_xb<<<2048, 256, 0, stream>>>(x, b_pre, Xb, D, tx4);
    prep_wb<<<2048, 256, 0, stream>>>(W_enc, Wb, tw4);
    dim3 gg(H / 128, B / 128);
    enc_gemm_bf16k<<<gg, 256, 0, stream>>>(Xb, Wb, b_enc, hidden, D, H);
    // margin = 25 sigma of bf16-GEMM error (sigma ~1.6e-3)
    const float margin = 0.04f;
    if (useSPLIT) {
      topk_thresh<<<B, 256, 0, stream>>>(hidden, cand_ix, cand_cnt, kptr, margin);
      refine_f64<<<B, 256, 0, stream>>>(x, b_pre, W_enc, b_enc, cand_ix, cand_cnt, cand_sv, D);
      rank_scatter<<<B, 256, 0, stream>>>(cand_ix, cand_sv, cand_cnt, kptr,
                                          hidden, tk_idx, tk_val);
    } else {
      topk_select<<<B, 256, 0, stream>>>(x, b_pre, W_enc, b_enc, hidden,
                                         tk_idx, tk_val, kptr, D, margin);
    }
  } else {
    dim3 gg(H / BN, B / BM);
    enc_gemm_f32<<<gg, 256, 0, stream>>>(x, W_enc, b_enc, b_pre, hidden, D, H);
    const size_t sh = CAND_MAX * sizeof(double) + (size_t)D * sizeof(float)
                    + CAND_MAX * sizeof(int) + (NBITER + 8) * sizeof(int);
    topk_refine<<<B, 256, sh, stream>>>(x, b_pre, W_enc, b_enc, hidden,
                                        tk_idx, tk_val, kptr, D, H, 1e-3f);
  }

  if (useWT)
    transpose_wdec_bf16<<<dim3((H + 31) / 32, (D + 31) / 32), 256, 0, stream>>>(W_dec, WTb, D, H);

  decode_loss<<<B, 256, 0, stream>>>(x, b_pre, b_dec, W_dec, WTb,
                                     tk_idx, tk_val, kptr, recon, row_ssq, D, H, useWT);

  finalize_k<<<1, 256, 0, stream>>>(row_ssq, tk_val, kptr, scalars, B, D);
}

// Round 6
// 1777.822 us; speedup vs baseline: 3.4504x; 1.1413x over previous
//
#include <hip/hip_runtime.h>
#include <hip/hip_bf16.h>

constexpr int K_MAX    = 128;   // max supported k (actual k=64 read from device)
constexpr int S_MAX    = 128;   // sure-member cap per row
constexpr int A_MAX    = 256;   // ambiguous cap per row
constexpr int P_MAX    = 384;   // loose candidate pool cap (LDS)
constexpr int CAND_MAX = 512;   // fused-fallback candidate cap
constexpr int BM = 128, BN = 128, BK = 16;
constexpr int NBITER = 42;      // fallback bisection iterations
constexpr int D_MAX   = 2048;   // fast path requires D <= D_MAX
constexpr int H_FIX   = 16384;  // fast path requires H == H_FIX

typedef __attribute__((ext_vector_type(8))) short bf16x8;
typedef __attribute__((ext_vector_type(8))) unsigned short u16x8;
typedef __attribute__((ext_vector_type(4))) float f32x4;

__device__ inline unsigned short f2bf(float f) {   // round-to-nearest-even
  unsigned u = __float_as_uint(f);
  return (unsigned short)((u + 0x7fff + ((u >> 16) & 1)) >> 16);
}
// monotone 16-bit key: key order == value order (handles negatives)
__device__ inline unsigned short key_of(float f) {
  unsigned short b = f2bf(f);
  return b ^ ((b & 0x8000) ? 0xFFFF : 0x8000);
}
__device__ inline float val_of_key(unsigned short kk) {
  unsigned short b = (kk & 0x8000) ? (unsigned short)(kk ^ 0x8000)
                                   : (unsigned short)(kk ^ 0xFFFF);
  return __uint_as_float(((unsigned)b) << 16);
}
__device__ inline float bf2f(unsigned short b) {
  return __uint_as_float(((unsigned)b) << 16);
}

// ---------------- prep: Xb = bf16(x - b_pre), Wb = bf16(W_enc) ----------------
__global__ __launch_bounds__(256) void prep_xb(
    const float* __restrict__ x, const float* __restrict__ b_pre,
    unsigned short* __restrict__ Xb, int D, size_t total4)
{
  for (size_t i = blockIdx.x * 256 + threadIdx.x; i < total4; i += (size_t)gridDim.x * 256) {
    const size_t e = i * 4;
    const int d = (int)(e % D);
    float4 xv = *reinterpret_cast<const float4*>(x + e);
    float4 bp = *reinterpret_cast<const float4*>(b_pre + d);
    ushort4 o;
    o.x = f2bf(xv.x - bp.x); o.y = f2bf(xv.y - bp.y);
    o.z = f2bf(xv.z - bp.z); o.w = f2bf(xv.w - bp.w);
    *reinterpret_cast<ushort4*>(Xb + e) = o;
  }
}

__global__ __launch_bounds__(256) void prep_wb(
    const float* __restrict__ W, unsigned short* __restrict__ Wb, size_t total4)
{
  for (size_t i = blockIdx.x * 256 + threadIdx.x; i < total4; i += (size_t)gridDim.x * 256) {
    const size_t e = i * 4;
    float4 wv = *reinterpret_cast<const float4*>(W + e);
    ushort4 o;
    o.x = f2bf(wv.x); o.y = f2bf(wv.y); o.z = f2bf(wv.z); o.w = f2bf(wv.w);
    *reinterpret_cast<ushort4*>(Wb + e) = o;
  }
}

// ---------------- kernel 1: encoder GEMM, bf16 MFMA ----------------
// writeKeys=0: write f32 pre.  writeKeys=1: write monotone u16 keys (fused fallback).
__global__ __launch_bounds__(256) void enc_gemm_bf16(
    const unsigned short* __restrict__ Xb, const unsigned short* __restrict__ Wb,
    const float* __restrict__ b_enc, float* __restrict__ pre, int D, int H, int writeKeys)
{
  __shared__ unsigned short As[128 * 32];   // [row][k] linear, 64B rows
  __shared__ unsigned short Bs[128 * 32];
  const int tid  = threadIdx.x;
  const int wave = tid >> 6, lane = tid & 63;
  const int m0 = blockIdx.y * 128, n0 = blockIdx.x * 128;
  const int wm = (wave >> 1) * 64, wn = (wave & 1) * 64;
  const int l16 = lane & 15, lhi = lane >> 4;

  f32x4 acc[4][4];
#pragma unroll
  for (int i = 0; i < 4; ++i)
#pragma unroll
    for (int j = 0; j < 4; ++j) acc[i][j] = (f32x4){0.f, 0.f, 0.f, 0.f};

  for (int kb = 0; kb < D; kb += 32) {
#pragma unroll
    for (int i = 0; i < 2; ++i) {
      const int base = wave * 64 + i * 256;
      const int idx  = base + lane;
      const int row  = idx >> 2, ch = idx & 3;
      const unsigned short* gA = Xb + (size_t)(m0 + row) * D + kb + ch * 8;
      __builtin_amdgcn_global_load_lds(
          (const __attribute__((address_space(1))) unsigned int*)gA,
          (__attribute__((address_space(3))) unsigned int*)(As + (size_t)base * 8),
          16, 0, 0);
      const unsigned short* gB = Wb + (size_t)(n0 + row) * D + kb + ch * 8;
      __builtin_amdgcn_global_load_lds(
          (const __attribute__((address_space(1))) unsigned int*)gB,
          (__attribute__((address_space(3))) unsigned int*)(Bs + (size_t)base * 8),
          16, 0, 0);
    }
    __syncthreads();

    bf16x8 af[4], bfr[4];
#pragma unroll
    for (int mi = 0; mi < 4; ++mi)
      af[mi] = *reinterpret_cast<const bf16x8*>(As + (size_t)(wm + mi * 16 + l16) * 32 + lhi * 8);
#pragma unroll
    for (int ni = 0; ni < 4; ++ni)
      bfr[ni] = *reinterpret_cast<const bf16x8*>(Bs + (size_t)(wn + ni * 16 + l16) * 32 + lhi * 8);
#pragma unroll
    for (int mi = 0; mi < 4; ++mi)
#pragma unroll
      for (int ni = 0; ni < 4; ++ni)
        acc[mi][ni] = __builtin_amdgcn_mfma_f32_16x16x32_bf16(af[mi], bfr[ni], acc[mi][ni], 0, 0, 0);
    __syncthreads();
  }

  if (writeKeys) {
#pragma unroll
    for (int ni = 0; ni < 4; ++ni) {
      const int n = n0 + wn + ni * 16 + l16;
      const float be = b_enc[n];
#pragma unroll
      for (int mi = 0; mi < 4; ++mi) {
        const int mbase = m0 + wm + mi * 16 + lhi * 4;
#pragma unroll
        for (int r = 0; r < 4; ++r) {
          unsigned short* prow = (unsigned short*)(pre + (size_t)(mbase + r) * H);
          prow[n] = key_of(acc[mi][ni][r] + be);
        }
      }
    }
  } else {
#pragma unroll
    for (int ni = 0; ni < 4; ++ni) {
      const int n = n0 + wn + ni * 16 + l16;
      const float be = b_enc[n];
#pragma unroll
      for (int mi = 0; mi < 4; ++mi) {
        const int mbase = m0 + wm + mi * 16 + lhi * 4;
#pragma unroll
        for (int r = 0; r < 4; ++r)
          pre[(size_t)(mbase + r) * H + n] = acc[mi][ni][r] + be;
      }
    }
  }
}

// ---------------- kernel 2: classify rows into sure members + ambiguous band ----------------
// pass1: 4096-bin key histogram (stream f32 pre).  pass2 (L2-hot): loose pool into
// LDS + 16-sub-bin recount of the k-th bin.  Then exact k-th key -> f32 thresholds;
// classify pool: sure (approx > v_k + delta, value kept) / ambiguous (within band).
__global__ __launch_bounds__(256) void topk_classify(
    const float* __restrict__ pre,
    int* __restrict__ sure_ix, float* __restrict__ sure_val, int* __restrict__ sure_cnt,
    int* __restrict__ amb_ix, int* __restrict__ amb_cnt,
    const int* __restrict__ kptr, float delta)
{
  constexpr int H = H_FIX;
  __shared__ int   hist[4096];
  __shared__ int   chunk[256];
  __shared__ int   misc[8];
  __shared__ float fth[2];
  __shared__ float pot_v[P_MAX];
  __shared__ int   pot_i[P_MAX];

  const int tid = threadIdx.x, b = blockIdx.x;
  const int k = min(*kptr, K_MAX);
  const float* prow = pre + (size_t)b * H;

  if (tid < 8) misc[tid] = 0;
  for (int i = tid; i < 4096; i += 256) hist[i] = 0;
  __syncthreads();

  // ---- pass 1: histogram of bf16 keys (bins = key>>4) ----
  for (int i = tid; i < H / 4; i += 256) {
    float4 v = reinterpret_cast<const float4*>(prow)[i];
    atomicAdd(&hist[key_of(v.x) >> 4], 1);
    atomicAdd(&hist[key_of(v.y) >> 4], 1);
    atomicAdd(&hist[key_of(v.z) >> 4], 1);
    atomicAdd(&hist[key_of(v.w) >> 4], 1);
  }
  __syncthreads();

  // ---- find bin b1 containing the k-th largest key ----
  int csum = 0;
#pragma unroll
  for (int j = 0; j < 16; ++j) csum += hist[tid * 16 + j];
  chunk[tid] = csum;
  __syncthreads();
  int gt = 0;
  for (int j = tid + 1; j < 256; ++j) gt += chunk[j];
  {
    int run = gt;
#pragma unroll
    for (int j = 15; j >= 0; --j) {
      const int hc = hist[tid * 16 + j];
      if (run < k && k <= run + hc) { misc[0] = tid * 16 + j; misc[1] = run; }
      run += hc;
    }
  }
  __syncthreads();
  const int b1 = misc[0];
  if (tid < 16) chunk[tid] = 0;
  __syncthreads();

  // loose lower bound: guaranteed <= final ambiguous threshold
  const float binlo = val_of_key((unsigned short)(b1 << 4));
  const float binhi = val_of_key((unsigned short)min((b1 << 4) + 16, 65535));
  const float v_loose = binlo - delta - (binhi - binlo) * 0.125f;

  // ---- pass 2 (L2-hot): collect loose pool + sub-bin counts of bin b1 ----
  for (int i = tid; i < H / 4; i += 256) {
    float4 v = reinterpret_cast<const float4*>(prow)[i];
    const float f[4] = {v.x, v.y, v.z, v.w};
#pragma unroll
    for (int c = 0; c < 4; ++c) {
      if (f[c] >= v_loose) {
        const int p = atomicAdd(&misc[6], 1);
        if (p < P_MAX) { pot_v[p] = f[c]; pot_i[p] = 4 * i + c; }
      }
      const unsigned short kk = key_of(f[c]);
      if ((int)(kk >> 4) == b1) atomicAdd(&chunk[kk & 15], 1);
    }
  }
  __syncthreads();

  // ---- exact k-th key -> f32 thresholds ----
  if (tid == 0) {
    int run = misc[1];
    int K16 = b1 << 4;
    for (int j = 15; j >= 0; --j) {
      const int c = chunk[j];
      if (run < k && k <= run + c) K16 = (b1 << 4) | j;
      run += c;
    }
    const float v_lo = val_of_key((unsigned short)K16);
    const float v_hi = val_of_key((unsigned short)min(K16 + 1, 65535));
    const float ulp = v_hi - v_lo;
    fth[0] = v_hi + delta;          // sure: f >  fth[0]  (>= v_k^approx + delta)
    fth[1] = v_lo - ulp - delta;    // amb : f >= fth[1]  (<= v_k^approx - delta)
  }
  __syncthreads();
  const float vs = fth[0], va = fth[1];

  // ---- classify pool ----
  const int P = min(misc[6], P_MAX);
  for (int i = tid; i < P; i += 256) {
    const float f = pot_v[i];
    const int h = pot_i[i];
    if (f > vs) {
      const int p = atomicAdd(&misc[4], 1);
      if (p < S_MAX) { sure_ix[(size_t)b * S_MAX + p] = h; sure_val[(size_t)b * S_MAX + p] = f; }
    } else if (f >= va) {
      const int p = atomicAdd(&misc[5], 1);
      if (p < A_MAX) amb_ix[(size_t)b * A_MAX + p] = h;
    }
  }
  __syncthreads();
  if (tid == 0) {
    sure_cnt[b] = min(misc[4], S_MAX);
    amb_cnt[b]  = min(misc[5], A_MAX);
  }
}

// ---------------- kernel 3: exact f64 dot products for ambiguous only ----------------
__global__ __launch_bounds__(256) void refine_f64(
    const float* __restrict__ X, const float* __restrict__ b_pre,
    const float* __restrict__ W, const float* __restrict__ b_enc,
    const int* __restrict__ amb_ix, const int* __restrict__ amb_cnt,
    double* __restrict__ amb_sv, int D)
{
  __shared__ float xr[D_MAX];
  const int tid = threadIdx.x, b = blockIdx.x;
  const int C = min(amb_cnt[b], A_MAX);
  for (int d = tid; d < D; d += 256) xr[d] = X[(size_t)b * D + d] - b_pre[d];
  __syncthreads();
  const int wid = tid >> 6, lane = tid & 63;
  for (int c = wid; c < C; c += 4) {
    const int h = amb_ix[(size_t)b * A_MAX + c];
    const float* wr = W + (size_t)h * D;
    double s0 = 0.0, s1 = 0.0;
    int i = lane;
    for (; i + 64 < D; i += 128) {
      s0 += (double)xr[i] * (double)wr[i];
      s1 += (double)xr[i + 64] * (double)wr[i + 64];
    }
    if (i < D) s0 += (double)xr[i] * (double)wr[i];
    double s = s0 + s1;
    for (int off = 32; off; off >>= 1) s += __shfl_xor(s, off);
    if (lane == 0) amb_sv[(size_t)b * A_MAX + c] = s + (double)b_enc[h];
  }
}

// ---------------- kernel 4: zero row, write sure, rank ambiguous, scatter ----------------
__global__ __launch_bounds__(256) void rank_scatter2(
    const int* __restrict__ sure_ix, const float* __restrict__ sure_val,
    const int* __restrict__ sure_cnt,
    const int* __restrict__ amb_ix, const double* __restrict__ amb_sv,
    const int* __restrict__ amb_cnt, const int* __restrict__ kptr,
    float* __restrict__ hidden, int* __restrict__ tk_idx, float* __restrict__ tk_val)
{
  constexpr int H = H_FIX;
  __shared__ double asv[A_MAX];
  __shared__ int    aix[A_MAX];
  const int tid = threadIdx.x, b = blockIdx.x;
  const int k = min(*kptr, K_MAX);
  const int S = min(min(sure_cnt[b], S_MAX), k);
  const int A = min(amb_cnt[b], A_MAX);
  float* hrow = hidden + (size_t)b * H;

  for (int c = tid; c < A; c += 256) {
    asv[c] = amb_sv[(size_t)b * A_MAX + c];
    aix[c] = amb_ix[(size_t)b * A_MAX + c];
  }
  const float4 z4 = {0.f, 0.f, 0.f, 0.f};
  for (int i = tid; i < (H >> 2); i += 256)
    reinterpret_cast<float4*>(hrow)[i] = z4;
  __syncthreads();

  // sure members: value = f32 GEMM approx (err << 1.28 threshold)
  for (int i = tid; i < S; i += 256) {
    const int h = sure_ix[(size_t)b * S_MAX + i];
    const float v = sure_val[(size_t)b * S_MAX + i];
    const float rv = (v > 0.f) ? v : 0.f;
    hrow[h] = rv;
    tk_idx[(size_t)b * K_MAX + i] = h;
    tk_val[(size_t)b * K_MAX + i] = rv;
  }
  // ambiguous: top (k-S) by exact f64 value, index tie-break
  const int m = k - S;
  for (int c = tid; c < A; c += 256) {
    const double v = asv[c];
    const int h = aix[c];
    int r = 0;
    for (int j = 0; j < A; ++j) {
      const double vj = asv[j];
      r += ((vj > v) || (vj == v && aix[j] < h)) ? 1 : 0;
    }
    if (r < m) {
      const float rv = (v > 0.0) ? (float)v : 0.f;
      hrow[h] = rv;
      tk_idx[(size_t)b * K_MAX + S + r] = h;
      tk_val[(size_t)b * K_MAX + S + r] = rv;
    }
  }
}

// ---------------- fused fallback: single-pass select on u16 keys ----------------
__global__ __launch_bounds__(256, 2) void topk_select(
    const float* __restrict__ X, const float* __restrict__ b_pre,
    const float* __restrict__ W, const float* __restrict__ b_enc,
    float* __restrict__ hidden, int* __restrict__ tk_idx, float* __restrict__ tk_val,
    const int* __restrict__ kptr, int D, float margin)
{
  constexpr int H = H_FIX, NC = H_FIX / (256 * 8);
  __shared__ double cand_sv[CAND_MAX];
  __shared__ float  xr[D_MAX];
  __shared__ int    cand_ix[CAND_MAX];
  __shared__ int    hist[4096];
  __shared__ int    chunk[256];
  __shared__ int    misc[8];

  const int tid = threadIdx.x, b = blockIdx.x;
  const int k = min(*kptr, K_MAX);
  float* hrow = hidden + (size_t)b * H;
  const unsigned short* krow = (const unsigned short*)hrow;

  if (tid < 8) misc[tid] = 0;
  for (int i = tid; i < 4096; i += 256) hist[i] = 0;
  for (int d = tid; d < D; d += 256) xr[d] = X[(size_t)b * D + d] - b_pre[d];

  u16x8 kv[NC];
#pragma unroll
  for (int i = 0; i < NC; ++i)
    kv[i] = *reinterpret_cast<const u16x8*>(krow + ((size_t)i * 256 + tid) * 8);
  __syncthreads();

#pragma unroll
  for (int i = 0; i < NC; ++i)
#pragma unroll
    for (int j = 0; j < 8; ++j)
      atomicAdd(&hist[((unsigned)(unsigned short)kv[i][j]) >> 4], 1);
  __syncthreads();

  int csum = 0;
#pragma unroll
  for (int j = 0; j < 16; ++j) csum += hist[tid * 16 + j];
  chunk[tid] = csum;
  __syncthreads();
  int gt = 0;
  for (int j = tid + 1; j < 256; ++j) gt += chunk[j];
  {
    int run = gt;
#pragma unroll
    for (int j = 15; j >= 0; --j) {
      const int hc = hist[tid * 16 + j];
      if (run < k && k <= run + hc) { misc[0] = tid * 16 + j; misc[1] = run; }
      run += hc;
    }
  }
  __syncthreads();
  const int b1 = misc[0];
  if (tid < 16) chunk[tid] = 0;
  __syncthreads();
#pragma unroll
  for (int i = 0; i < NC; ++i)
#pragma unroll
    for (int j = 0; j < 8; ++j) {
      const unsigned kk = (unsigned)(unsigned short)kv[i][j];
      if ((int)(kk >> 4) == b1) atomicAdd(&chunk[kk & 15], 1);
    }
  __syncthreads();
  if (tid == 0) {
    int run = misc[1];
    int K16 = b1 << 4;
    for (int j = 15; j >= 0; --j) {
      const int c = chunk[j];
      if (run < k && k <= run + c) K16 = (b1 << 4) | j;
      run += c;
    }
    const float vthr = val_of_key((unsigned short)K16) - margin;
    int kt = (int)key_of(vthr);
    if (kt > K16) kt = K16;
    misc[2] = kt;
  }
  __syncthreads();
  const unsigned kthr = (unsigned)misc[2];

#pragma unroll
  for (int i = 0; i < NC; ++i)
#pragma unroll
    for (int j = 0; j < 8; ++j) {
      if ((unsigned)(unsigned short)kv[i][j] >= kthr) {
        const int pos = atomicAdd(&misc[3], 1);
        if (pos < CAND_MAX) cand_ix[pos] = (i * 256 + tid) * 8 + j;
      }
    }
  __syncthreads();
  const int C = min(misc[3], CAND_MAX);

  const float4 z4 = {0.f, 0.f, 0.f, 0.f};
  for (int i = tid; i < (H >> 2); i += 256)
    reinterpret_cast<float4*>(hrow)[i] = z4;

  const int wid = tid >> 6, lane = tid & 63;
  for (int c = wid; c < C; c += 4) {
    const int h = cand_ix[c];
    const float* wr = W + (size_t)h * D;
    double s = 0.0;
    for (int i = lane; i < D; i += 64) s += (double)xr[i] * (double)wr[i];
    for (int off = 32; off; off >>= 1) s += __shfl_xor(s, off);
    if (lane == 0) cand_sv[c] = s + (double)b_enc[h];
  }
  __syncthreads();

  for (int c = tid; c < C; c += 256) {
    const double v = cand_sv[c];
    const int h = cand_ix[c];
    int r = 0;
    for (int j = 0; j < C; ++j) {
      const double vj = cand_sv[j];
      r += ((vj > v) || (vj == v && cand_ix[j] < h)) ? 1 : 0;
    }
    if (r < k) {
      const float rv = (v > 0.0) ? (float)v : 0.f;
      hrow[h] = rv;
      tk_idx[(size_t)b * K_MAX + r] = h;
      tk_val[(size_t)b * K_MAX + r] = rv;
    }
  }
}

// ---------------- fallback: fp32 GEMM ----------------
__global__ __launch_bounds__(256) void enc_gemm_f32(
    const float* __restrict__ X, const float* __restrict__ W,
    const float* __restrict__ b_enc, const float* __restrict__ b_pre,
    float* __restrict__ pre, int D, int H)
{
  __shared__ float As[BK][BM + 4];
  __shared__ float Bs[BK][BN + 4];
  const int tid = threadIdx.x;
  const int m0 = blockIdx.y * BM;
  const int n0 = blockIdx.x * BN;
  const int tx = tid & 15, ty = tid >> 4;
  float acc[8][8];
#pragma unroll
  for (int i = 0; i < 8; ++i)
#pragma unroll
    for (int j = 0; j < 8; ++j) acc[i][j] = 0.f;

  for (int kb = 0; kb < D; kb += BK) {
#pragma unroll
    for (int t = 0; t < 2; ++t) {
      const int f4i = tid + t * 256;
      const int row = f4i >> 2;
      const int kq  = (f4i & 3) << 2;
      float4 xv = *reinterpret_cast<const float4*>(X + (size_t)(m0 + row) * D + kb + kq);
      float4 bp = *reinterpret_cast<const float4*>(b_pre + kb + kq);
      As[kq + 0][row] = xv.x - bp.x; As[kq + 1][row] = xv.y - bp.y;
      As[kq + 2][row] = xv.z - bp.z; As[kq + 3][row] = xv.w - bp.w;
      float4 wv = *reinterpret_cast<const float4*>(W + (size_t)(n0 + row) * D + kb + kq);
      Bs[kq + 0][row] = wv.x; Bs[kq + 1][row] = wv.y;
      Bs[kq + 2][row] = wv.z; Bs[kq + 3][row] = wv.w;
    }
    __syncthreads();
#pragma unroll
    for (int kk = 0; kk < BK; ++kk) {
      float4 a0 = *reinterpret_cast<const float4*>(&As[kk][ty * 8]);
      float4 a1 = *reinterpret_cast<const float4*>(&As[kk][ty * 8 + 4]);
      float4 b0 = *reinterpret_cast<const float4*>(&Bs[kk][tx * 8]);
      float4 b1 = *reinterpret_cast<const float4*>(&Bs[kk][tx * 8 + 4]);
      float av[8] = {a0.x, a0.y, a0.z, a0.w, a1.x, a1.y, a1.z, a1.w};
      float bv[8] = {b0.x, b0.y, b0.z, b0.w, b1.x, b1.y, b1.z, b1.w};
#pragma unroll
      for (int i = 0; i < 8; ++i)
#pragma unroll
        for (int j = 0; j < 8; ++j) acc[i][j] += av[i] * bv[j];
    }
    __syncthreads();
  }
#pragma unroll
  for (int i = 0; i < 8; ++i) {
    const size_t m = (size_t)(m0 + ty * 8 + i);
#pragma unroll
    for (int j = 0; j < 8; j += 4) {
      const int n = n0 + tx * 8 + j;
      float4 o;
      o.x = acc[i][j + 0] + b_enc[n + 0];
      o.y = acc[i][j + 1] + b_enc[n + 1];
      o.z = acc[i][j + 2] + b_enc[n + 2];
      o.w = acc[i][j + 3] + b_enc[n + 3];
      *reinterpret_cast<float4*>(pre + m * H + n) = o;
    }
  }
}

// ---------------- fallback: bisection top-k (reads f32 pre) ----------------
__global__ __launch_bounds__(256) void topk_refine(
    const float* __restrict__ X, const float* __restrict__ b_pre,
    const float* __restrict__ W, const float* __restrict__ b_enc,
    float* __restrict__ hidden, int* __restrict__ tk_idx, float* __restrict__ tk_val,
    const int* __restrict__ kptr, int D, int H, float margin)
{
  extern __shared__ char smem_raw[];
  double* cand_val = reinterpret_cast<double*>(smem_raw);
  float*  xr       = reinterpret_cast<float*>(cand_val + CAND_MAX);
  int*    cand_idx = reinterpret_cast<int*>(xr + D);
  int*    misc     = cand_idx + CAND_MAX;

  const int tid = threadIdx.x;
  const int b = blockIdx.x;
  const int k = min(*kptr, K_MAX);
  float* hrow = hidden + (size_t)b * H;

  for (int i = tid; i < NBITER + 2; i += 256) misc[i] = 0;
  for (int d = tid; d < D; d += 256) xr[d] = X[(size_t)b * D + d] - b_pre[d];

  float f[64];
#pragma unroll
  for (int i = 0; i < 16; ++i) {
    const int base = i * 1024 + tid * 4;
    float4 v = {-3e38f, -3e38f, -3e38f, -3e38f};
    if (base + 3 < H) v = *reinterpret_cast<const float4*>(hrow + base);
    f[4 * i + 0] = v.x; f[4 * i + 1] = v.y; f[4 * i + 2] = v.z; f[4 * i + 3] = v.w;
  }
  __syncthreads();

  float lo = -1e4f, hi = 1e4f;
  for (int it = 0; it < NBITER; ++it) {
    const float mid = 0.5f * (lo + hi);
    int cnt = 0;
#pragma unroll
    for (int j = 0; j < 64; ++j) cnt += (f[j] >= mid) ? 1 : 0;
    for (int off = 32; off; off >>= 1) cnt += __shfl_xor(cnt, off);
    if ((tid & 63) == 0) atomicAdd(&misc[it], cnt);
    __syncthreads();
    if (misc[it] >= k) lo = mid; else hi = mid;
  }

  const float thresh = lo - margin;
#pragma unroll
  for (int j = 0; j < 64; ++j) {
    if (f[j] >= thresh) {
      const int h = (j >> 2) * 1024 + tid * 4 + (j & 3);
      if (h < H) {
        int pos = atomicAdd(&misc[NBITER], 1);
        if (pos < CAND_MAX) cand_idx[pos] = h;
      }
    }
  }
  __syncthreads();
  const int C = min(misc[NBITER], CAND_MAX);

  const int wid = tid >> 6, lane = tid & 63;
  for (int c = wid; c < C; c += 4) {
    const int h = cand_idx[c];
    const float* wr = W + (size_t)h * D;
    double s = 0.0;
    for (int i = lane; i < D; i += 64) s += (double)xr[i] * (double)wr[i];
    for (int off = 32; off; off >>= 1) s += __shfl_xor(s, off);
    if (lane == 0) cand_val[c] = s + (double)b_enc[h];
  }
  __syncthreads();

  const float4 z4 = {0.f, 0.f, 0.f, 0.f};
  for (int i = tid; i < (H >> 2); i += 256)
    reinterpret_cast<float4*>(hrow)[i] = z4;
  __syncthreads();

  for (int c = tid; c < C; c += 256) {
    const double v = cand_val[c];
    const int h = cand_idx[c];
    int r = 0;
    for (int j = 0; j < C; ++j) {
      const double vj = cand_val[j];
      r += ((vj > v) || (vj == v && cand_idx[j] < h)) ? 1 : 0;
    }
    if (r < k) {
      const float rv = (v > 0.0) ? (float)v : 0.f;
      hrow[h] = rv;
      tk_idx[(size_t)b * K_MAX + r] = h;
      tk_val[(size_t)b * K_MAX + r] = rv;
    }
  }
}

// ---------------- kernel 5: W_dec [D,H] -> bf16 W_decT [H,D] ----------------
__global__ __launch_bounds__(256) void transpose_wdec_bf16(
    const float* __restrict__ Wsrc, unsigned short* __restrict__ WT, int D, int H)
{
  __shared__ float tile[32][33];
  const int c  = threadIdx.x & 31;
  const int r0 = threadIdx.x >> 5;
  const int h0 = blockIdx.x * 32;
  const int d0 = blockIdx.y * 32;
#pragma unroll
  for (int r = r0; r < 32; r += 8) {
    const int d = d0 + r, h = h0 + c;
    if (d < D && h < H) tile[r][c] = Wsrc[(size_t)d * H + h];
  }
  __syncthreads();
#pragma unroll
  for (int r = r0; r < 32; r += 8) {
    const int h = h0 + r, d = d0 + c;
    if (h < H && d < D) WT[(size_t)h * D + d] = f2bf(tile[c][r]);
  }
}

// ---------------- kernel 6: sparse decode + per-row squared error ----------------
__global__ __launch_bounds__(256) void decode_loss(
    const float* __restrict__ X, const float* __restrict__ b_pre,
    const float* __restrict__ b_dec, const float* __restrict__ Wfull,
    const unsigned short* __restrict__ WTb,
    const int* __restrict__ tk_idx, const float* __restrict__ tk_val,
    const int* __restrict__ kptr,
    float* __restrict__ recon, double* __restrict__ row_ssq,
    int D, int H, int useWT)
{
  __shared__ int   sidx[K_MAX];
  __shared__ float sval[K_MAX];
  __shared__ double sd[4];
  const int tid = threadIdx.x, b = blockIdx.x;
  const int k = min(*kptr, K_MAX);
  if (tid < k) {
    sidx[tid] = tk_idx[(size_t)b * K_MAX + tid];
    sval[tid] = tk_val[(size_t)b * K_MAX + tid];
  }
  __syncthreads();
  double ssq = 0.0;
  for (int d = tid; d < D; d += 256) {
    float a = b_dec[d] + b_pre[d];
    if (useWT) {
#pragma unroll 4
      for (int j = 0; j < k; ++j) a += sval[j] * bf2f(WTb[(size_t)sidx[j] * D + d]);
    } else {
#pragma unroll 4
      for (int j = 0; j < k; ++j) a += sval[j] * Wfull[(size_t)d * H + sidx[j]];
    }
    recon[(size_t)b * D + d] = a;
    const double diff = (double)a - (double)X[(size_t)b * D + d];
    ssq += diff * diff;
  }
  for (int off = 32; off; off >>= 1) ssq += __shfl_xor(ssq, off);
  if ((tid & 63) == 0) sd[tid >> 6] = ssq;
  __syncthreads();
  if (tid == 0) row_ssq[b] = sd[0] + sd[1] + sd[2] + sd[3];
}

// ---------------- kernel 7: finalize scalar losses ----------------
__global__ __launch_bounds__(256) void finalize_k(
    const double* __restrict__ row_ssq, const float* __restrict__ tk_val,
    const int* __restrict__ kptr, float* __restrict__ scalars, int Bdim, int D)
{
  __shared__ double sd[4];
  __shared__ int si[4];
  const int tid = threadIdx.x;
  const int k = min(*kptr, K_MAX);
  double s = 0.0;
  for (int i = tid; i < Bdim; i += 256) s += row_ssq[i];
  int cnt = 0;
  for (int i = tid; i < Bdim * k; i += 256) {
    const int b = i / k, j = i - b * k;
    cnt += (tk_val[(size_t)b * K_MAX + j] > 0.f) ? 1 : 0;
  }
  for (int off = 32; off; off >>= 1) { s += __shfl_xor(s, off); cnt += __shfl_xor(cnt, off); }
  if ((tid & 63) == 0) { sd[tid >> 6] = s; si[tid >> 6] = cnt; }
  __syncthreads();
  if (tid == 0) {
    double st = 0; int ct = 0;
    for (int w = 0; w < 4; ++w) { st += sd[w]; ct += si[w]; }
    const double rl = st / ((double)Bdim * (double)D);
    scalars[0] = (float)rl;
    scalars[1] = (float)rl;
    scalars[2] = 0.f;
    scalars[3] = (float)((double)ct / Bdim);
  }
}

extern "C" void kernel_launch(void* const* d_in, const int* in_sizes, int n_in,
                              void* d_out, int out_size, void* d_ws, size_t ws_size,
                              hipStream_t stream)
{
  const float* x     = (const float*)d_in[0];
  const float* W_enc = (const float*)d_in[1];
  const float* b_enc = (const float*)d_in[2];
  const float* W_dec = (const float*)d_in[3];
  const float* b_dec = (const float*)d_in[4];
  const float* b_pre = (const float*)d_in[5];
  const int*   kptr  = (const int*)d_in[6];

  const int D = in_sizes[4];          // 1280
  const int H = in_sizes[2];          // 16384
  const int B = in_sizes[0] / D;      // 8192

  float* recon   = (float*)d_out;
  float* hidden  = recon + (size_t)B * D;       // temporarily holds pre (f32 or keys)
  float* scalars = hidden + (size_t)B * H;

  // ---- workspace layout (single running cursor) ----
  size_t off = 0;
  int* tk_idx = (int*)((char*)d_ws + off);        off += (size_t)B * K_MAX * sizeof(int);
  float* tk_val = (float*)((char*)d_ws + off);    off += (size_t)B * K_MAX * sizeof(float);
  off = (off + 7) & ~(size_t)7;
  double* row_ssq = (double*)((char*)d_ws + off); off += (size_t)B * sizeof(double);

  unsigned short* Xb = (unsigned short*)((char*)d_ws + off);
  off += (size_t)B * D * sizeof(unsigned short);
  unsigned short* Wb = (unsigned short*)((char*)d_ws + off);
  off += (size_t)H * D * sizeof(unsigned short);
  const int useBF16 = (off <= ws_size) ? 1 : 0;

  unsigned short* WTb = (unsigned short*)((char*)d_ws + off);
  off += (size_t)D * H * sizeof(unsigned short);
  const int useWT = (off <= ws_size) ? 1 : 0;

  int* sure_ix = (int*)((char*)d_ws + off);       off += (size_t)B * S_MAX * sizeof(int);
  float* sure_val = (float*)((char*)d_ws + off);  off += (size_t)B * S_MAX * sizeof(float);
  int* sure_cnt = (int*)((char*)d_ws + off);      off += (size_t)B * sizeof(int);
  int* amb_ix = (int*)((char*)d_ws + off);        off += (size_t)B * A_MAX * sizeof(int);
  int* amb_cnt = (int*)((char*)d_ws + off);       off += (size_t)B * sizeof(int);
  off = (off + 7) & ~(size_t)7;
  double* amb_sv = (double*)((char*)d_ws + off);  off += (size_t)B * A_MAX * sizeof(double);
  const int useSPLIT = (useBF16 && off <= ws_size) ? 1 : 0;

  const bool fast_ok = (D % 32 == 0) && (D % 4 == 0) && (D <= D_MAX) &&
                       (H == H_FIX) && (B % 128 == 0);

  if (useBF16 && fast_ok) {
    const size_t tx4 = (size_t)B * D / 4, tw4 = (size_t)H * D / 4;
    prep_xb<<<2048, 256, 0, stream>>>(x, b_pre, Xb, D, tx4);
    prep_wb<<<2048, 256, 0, stream>>>(W_enc, Wb, tw4);
    dim3 gg(H / 128, B / 128);
    if (useSPLIT) {
      enc_gemm_bf16<<<gg, 256, 0, stream>>>(Xb, Wb, b_enc, hidden, D, H, 0);  // f32 pre
      // delta >= 2*eps: eps (max |f32approx - f64|) <= ~0.012 -> delta 0.035
      topk_classify<<<B, 256, 0, stream>>>(hidden, sure_ix, sure_val, sure_cnt,
                                           amb_ix, amb_cnt, kptr, 0.035f);
      refine_f64<<<B, 256, 0, stream>>>(x, b_pre, W_enc, b_enc, amb_ix, amb_cnt, amb_sv, D);
      rank_scatter2<<<B, 256, 0, stream>>>(sure_ix, sure_val, sure_cnt,
                                           amb_ix, amb_sv, amb_cnt, kptr,
                                           hidden, tk_idx, tk_val);
    } else {
      enc_gemm_bf16<<<gg, 256, 0, stream>>>(Xb, Wb, b_enc, hidden, D, H, 1);  // u16 keys
      topk_select<<<B, 256, 0, stream>>>(x, b_pre, W_enc, b_enc, hidden,
                                         tk_idx, tk_val, kptr, D, 0.04f);
    }
  } else {
    dim3 gg(H / BN, B / BM);
    enc_gemm_f32<<<gg, 256, 0, stream>>>(x, W_enc, b_enc, b_pre, hidden, D, H);
    const size_t sh = CAND_MAX * sizeof(double) + (size_t)D * sizeof(float)
                    + CAND_MAX * sizeof(int) + (NBITER + 8) * sizeof(int);
    topk_refine<<<B, 256, sh, stream>>>(x, b_pre, W_enc, b_enc, hidden,
                                        tk_idx, tk_val, kptr, D, H, 1e-3f);
  }

  if (useWT)
    transpose_wdec_bf16<<<dim3((H + 31) / 32, (D + 31) / 32), 256, 0, stream>>>(W_dec, WTb, D, H);

  decode_loss<<<B, 256, 0, stream>>>(x, b_pre, b_dec, W_dec, WTb,
                                     tk_idx, tk_val, kptr, recon, row_ssq, D, H, useWT);

  finalize_k<<<1, 256, 0, stream>>>(row_ssq, tk_val, kptr, scalars, B, D);
}

// Round 7
// 1330.065 us; speedup vs baseline: 4.6120x; 1.3366x over previous
//
#include <hip/hip_runtime.h>
#include <hip/hip_bf16.h>

constexpr int K_MAX    = 128;   // max supported k (actual k=64 read from device)
constexpr int S_MAX    = 128;   // sure-member cap per row
constexpr int A_MAX    = 256;   // ambiguous cap per row
constexpr int P_MAX    = 384;   // loose candidate pool cap (LDS)
constexpr int CAND_MAX = 512;   // fused-fallback candidate cap
constexpr int BM = 128, BN = 128, BKF = 16;
constexpr int NBITER = 42;      // fallback bisection iterations
constexpr int D_MAX   = 2048;   // fast path requires D <= D_MAX
constexpr int H_FIX   = 16384;  // fast path requires H == H_FIX

typedef __attribute__((ext_vector_type(8))) short bf16x8;
typedef __attribute__((ext_vector_type(8))) unsigned short u16x8;
typedef __attribute__((ext_vector_type(4))) float f32x4;

__device__ inline unsigned short f2bf(float f) {   // round-to-nearest-even
  unsigned u = __float_as_uint(f);
  return (unsigned short)((u + 0x7fff + ((u >> 16) & 1)) >> 16);
}
// monotone 16-bit key: key order == value order (handles negatives)
__device__ inline unsigned short key_of(float f) {
  unsigned short b = f2bf(f);
  return b ^ ((b & 0x8000) ? 0xFFFF : 0x8000);
}
__device__ inline float val_of_key(unsigned short kk) {
  unsigned short b = (kk & 0x8000) ? (unsigned short)(kk ^ 0x8000)
                                   : (unsigned short)(kk ^ 0xFFFF);
  return __uint_as_float(((unsigned)b) << 16);
}
__device__ inline float bf2f(unsigned short b) {
  return __uint_as_float(((unsigned)b) << 16);
}

// ---------------- prep: Xb = bf16(x - b_pre), Wb = bf16(W_enc) ----------------
__global__ __launch_bounds__(256) void prep_xb(
    const float* __restrict__ x, const float* __restrict__ b_pre,
    unsigned short* __restrict__ Xb, int D, size_t total4)
{
  for (size_t i = blockIdx.x * 256 + threadIdx.x; i < total4; i += (size_t)gridDim.x * 256) {
    const size_t e = i * 4;
    const int d = (int)(e % D);
    float4 xv = *reinterpret_cast<const float4*>(x + e);
    float4 bp = *reinterpret_cast<const float4*>(b_pre + d);
    ushort4 o;
    o.x = f2bf(xv.x - bp.x); o.y = f2bf(xv.y - bp.y);
    o.z = f2bf(xv.z - bp.z); o.w = f2bf(xv.w - bp.w);
    *reinterpret_cast<ushort4*>(Xb + e) = o;
  }
}

__global__ __launch_bounds__(256) void prep_wb(
    const float* __restrict__ W, unsigned short* __restrict__ Wb, size_t total4)
{
  for (size_t i = blockIdx.x * 256 + threadIdx.x; i < total4; i += (size_t)gridDim.x * 256) {
    const size_t e = i * 4;
    float4 wv = *reinterpret_cast<const float4*>(W + e);
    ushort4 o;
    o.x = f2bf(wv.x); o.y = f2bf(wv.y); o.z = f2bf(wv.z); o.w = f2bf(wv.w);
    *reinterpret_cast<ushort4*>(Wb + e) = o;
  }
}

// ---------------- kernel 1: encoder GEMM, bf16 MFMA ----------------
// BK=64, double-buffered LDS, stage-first, ONE barrier per K-tile (T3-minimum).
// writeKeys=0: f32 pre.  writeKeys=1: monotone u16 keys (fused fallback).
__global__ __launch_bounds__(256) void enc_gemm_bf16(
    const unsigned short* __restrict__ Xb, const unsigned short* __restrict__ Wb,
    const float* __restrict__ b_enc, float* __restrict__ pre, int D, int H, int writeKeys)
{
  __shared__ unsigned short As[2][128 * 64];   // [row][k] linear, 128B rows
  __shared__ unsigned short Bs[2][128 * 64];
  const int tid  = threadIdx.x;
  const int wave = tid >> 6, lane = tid & 63;
  const int m0 = blockIdx.y * 128, n0 = blockIdx.x * 128;
  const int wm = (wave >> 1) * 64, wn = (wave & 1) * 64;
  const int l16 = lane & 15, lhi = lane >> 4;

  f32x4 acc[4][4];
#pragma unroll
  for (int i = 0; i < 4; ++i)
#pragma unroll
    for (int j = 0; j < 4; ++j) acc[i][j] = (f32x4){0.f, 0.f, 0.f, 0.f};

  const int NT = D / 64;

  // prologue: stage tile 0 into buffer 0
#pragma unroll
  for (int i = 0; i < 4; ++i) {
    const int base = wave * 64 + i * 256;     // wave-uniform chunk base
    const int idx  = base + lane;
    const int row  = idx >> 3, ch = idx & 7;  // 8 x 16B chunks per 128B row
    __builtin_amdgcn_global_load_lds(
        (const __attribute__((address_space(1))) unsigned int*)(Xb + (size_t)(m0 + row) * D + ch * 8),
        (__attribute__((address_space(3))) unsigned int*)(As[0] + (size_t)base * 8), 16, 0, 0);
    __builtin_amdgcn_global_load_lds(
        (const __attribute__((address_space(1))) unsigned int*)(Wb + (size_t)(n0 + row) * D + ch * 8),
        (__attribute__((address_space(3))) unsigned int*)(Bs[0] + (size_t)base * 8), 16, 0, 0);
  }
  __syncthreads();   // compiler emits vmcnt(0) drain before s_barrier

  int cur = 0;
  for (int t = 0; t < NT; ++t) {
    // issue next tile's staging BEFORE compute (overlaps with MFMA below)
    if (t + 1 < NT) {
      const int kb = (t + 1) * 64;
      const int nxt = cur ^ 1;
#pragma unroll
      for (int i = 0; i < 4; ++i) {
        const int base = wave * 64 + i * 256;
        const int idx  = base + lane;
        const int row  = idx >> 3, ch = idx & 7;
        __builtin_amdgcn_global_load_lds(
            (const __attribute__((address_space(1))) unsigned int*)(Xb + (size_t)(m0 + row) * D + kb + ch * 8),
            (__attribute__((address_space(3))) unsigned int*)(As[nxt] + (size_t)base * 8), 16, 0, 0);
        __builtin_amdgcn_global_load_lds(
            (const __attribute__((address_space(1))) unsigned int*)(Wb + (size_t)(n0 + row) * D + kb + ch * 8),
            (__attribute__((address_space(3))) unsigned int*)(Bs[nxt] + (size_t)base * 8), 16, 0, 0);
      }
    }
    // compute current tile (K=64 = two K=32 slices)
#pragma unroll
    for (int kk = 0; kk < 2; ++kk) {
      bf16x8 af[4], bfr[4];
#pragma unroll
      for (int mi = 0; mi < 4; ++mi)
        af[mi] = *reinterpret_cast<const bf16x8*>(
            As[cur] + (size_t)(wm + mi * 16 + l16) * 64 + kk * 32 + lhi * 8);
#pragma unroll
      for (int ni = 0; ni < 4; ++ni)
        bfr[ni] = *reinterpret_cast<const bf16x8*>(
            Bs[cur] + (size_t)(wn + ni * 16 + l16) * 64 + kk * 32 + lhi * 8);
#pragma unroll
      for (int mi = 0; mi < 4; ++mi)
#pragma unroll
        for (int ni = 0; ni < 4; ++ni)
          acc[mi][ni] = __builtin_amdgcn_mfma_f32_16x16x32_bf16(af[mi], bfr[ni], acc[mi][ni], 0, 0, 0);
    }
    __syncthreads();   // drains next-tile stores + protects buffer reuse
    cur ^= 1;
  }

  if (writeKeys) {
#pragma unroll
    for (int ni = 0; ni < 4; ++ni) {
      const int n = n0 + wn + ni * 16 + l16;
      const float be = b_enc[n];
#pragma unroll
      for (int mi = 0; mi < 4; ++mi) {
        const int mbase = m0 + wm + mi * 16 + lhi * 4;
#pragma unroll
        for (int r = 0; r < 4; ++r) {
          unsigned short* prow = (unsigned short*)(pre + (size_t)(mbase + r) * H);
          prow[n] = key_of(acc[mi][ni][r] + be);
        }
      }
    }
  } else {
#pragma unroll
    for (int ni = 0; ni < 4; ++ni) {
      const int n = n0 + wn + ni * 16 + l16;
      const float be = b_enc[n];
#pragma unroll
      for (int mi = 0; mi < 4; ++mi) {
        const int mbase = m0 + wm + mi * 16 + lhi * 4;
#pragma unroll
        for (int r = 0; r < 4; ++r)
          pre[(size_t)(mbase + r) * H + n] = acc[mi][ni][r] + be;
      }
    }
  }
}

// ---------------- kernel 2: classify rows into sure members + ambiguous band ----------------
// pass1: 4096-bin key histogram.  pass2 (L2-hot): loose pool into LDS only.
// Sub-bin counts of the k-th bin come FROM THE POOL (covers all of bin b1).
__global__ __launch_bounds__(256) void topk_classify(
    const float* __restrict__ pre,
    int* __restrict__ sure_ix, float* __restrict__ sure_val, int* __restrict__ sure_cnt,
    int* __restrict__ amb_ix, int* __restrict__ amb_cnt,
    const int* __restrict__ kptr, float delta)
{
  constexpr int H = H_FIX;
  __shared__ int   hist[4096];
  __shared__ int   chunk[256];
  __shared__ int   misc[8];
  __shared__ float fth[2];
  __shared__ float pot_v[P_MAX];
  __shared__ int   pot_i[P_MAX];

  const int tid = threadIdx.x, b = blockIdx.x;
  const int k = min(*kptr, K_MAX);
  const float* prow = pre + (size_t)b * H;

  if (tid < 8) misc[tid] = 0;
  for (int i = tid; i < 4096; i += 256) hist[i] = 0;
  __syncthreads();

  // ---- pass 1: histogram of bf16 keys (bins = key>>4) ----
  for (int i = tid; i < H / 4; i += 256) {
    float4 v = reinterpret_cast<const float4*>(prow)[i];
    atomicAdd(&hist[key_of(v.x) >> 4], 1);
    atomicAdd(&hist[key_of(v.y) >> 4], 1);
    atomicAdd(&hist[key_of(v.z) >> 4], 1);
    atomicAdd(&hist[key_of(v.w) >> 4], 1);
  }
  __syncthreads();

  // ---- find bin b1 containing the k-th largest key ----
  int csum = 0;
#pragma unroll
  for (int j = 0; j < 16; ++j) csum += hist[tid * 16 + j];
  chunk[tid] = csum;
  __syncthreads();
  int gt = 0;
  for (int j = tid + 1; j < 256; ++j) gt += chunk[j];
  {
    int run = gt;
#pragma unroll
    for (int j = 15; j >= 0; --j) {
      const int hc = hist[tid * 16 + j];
      if (run < k && k <= run + hc) { misc[0] = tid * 16 + j; misc[1] = run; }
      run += hc;
    }
  }
  __syncthreads();
  const int b1 = misc[0];
  if (tid < 16) chunk[tid] = 0;
  __syncthreads();

  // loose lower bound: guaranteed <= final ambiguous threshold, and < bin b1 bottom
  const float binlo = val_of_key((unsigned short)(b1 << 4));
  const float binhi = val_of_key((unsigned short)min((b1 << 4) + 16, 65535));
  const float v_loose = binlo - delta - (binhi - binlo) * 0.25f;

  // ---- pass 2 (L2-hot): collect loose pool only ----
  for (int i = tid; i < H / 4; i += 256) {
    float4 v = reinterpret_cast<const float4*>(prow)[i];
    const float f[4] = {v.x, v.y, v.z, v.w};
#pragma unroll
    for (int c = 0; c < 4; ++c) {
      if (f[c] >= v_loose) {
        const int p = atomicAdd(&misc[6], 1);
        if (p < P_MAX) { pot_v[p] = f[c]; pot_i[p] = 4 * i + c; }
      }
    }
  }
  __syncthreads();
  const int P = min(misc[6], P_MAX);

  // ---- sub-bin counts of bin b1 from the pool ----
  for (int i = tid; i < P; i += 256) {
    const unsigned short kk = key_of(pot_v[i]);
    if ((int)(kk >> 4) == b1) atomicAdd(&chunk[kk & 15], 1);
  }
  __syncthreads();

  // ---- exact k-th key -> f32 thresholds ----
  if (tid == 0) {
    int run = misc[1];
    int K16 = b1 << 4;
    for (int j = 15; j >= 0; --j) {
      const int c = chunk[j];
      if (run < k && k <= run + c) K16 = (b1 << 4) | j;
      run += c;
    }
    const float v_lo = val_of_key((unsigned short)K16);
    const float v_hi = val_of_key((unsigned short)min(K16 + 1, 65535));
    const float ulp = v_hi - v_lo;
    fth[0] = v_hi + delta;          // sure: f >  fth[0]
    fth[1] = v_lo - ulp - delta;    // amb : f >= fth[1]
  }
  __syncthreads();
  const float vs = fth[0], va = fth[1];

  // ---- classify pool ----
  for (int i = tid; i < P; i += 256) {
    const float f = pot_v[i];
    const int h = pot_i[i];
    if (f > vs) {
      const int p = atomicAdd(&misc[4], 1);
      if (p < S_MAX) { sure_ix[(size_t)b * S_MAX + p] = h; sure_val[(size_t)b * S_MAX + p] = f; }
    } else if (f >= va) {
      const int p = atomicAdd(&misc[5], 1);
      if (p < A_MAX) amb_ix[(size_t)b * A_MAX + p] = h;
    }
  }
  __syncthreads();
  if (tid == 0) {
    sure_cnt[b] = min(misc[4], S_MAX);
    amb_cnt[b]  = min(misc[5], A_MAX);
  }
}

// ---------------- kernel 3: exact f64 dot products for ambiguous only ----------------
__global__ __launch_bounds__(256) void refine_f64(
    const float* __restrict__ X, const float* __restrict__ b_pre,
    const float* __restrict__ W, const float* __restrict__ b_enc,
    const int* __restrict__ amb_ix, const int* __restrict__ amb_cnt,
    double* __restrict__ amb_sv, int D)
{
  __shared__ float xr[D_MAX];
  const int tid = threadIdx.x, b = blockIdx.x;
  const int C = min(amb_cnt[b], A_MAX);
  for (int d = tid; d < D; d += 256) xr[d] = X[(size_t)b * D + d] - b_pre[d];
  __syncthreads();
  const int wid = tid >> 6, lane = tid & 63;
  for (int c = wid; c < C; c += 4) {
    const int h = amb_ix[(size_t)b * A_MAX + c];
    const float* wr = W + (size_t)h * D;
    double s0 = 0.0, s1 = 0.0;
    int i = lane;
    for (; i + 64 < D; i += 128) {
      s0 += (double)xr[i] * (double)wr[i];
      s1 += (double)xr[i + 64] * (double)wr[i + 64];
    }
    if (i < D) s0 += (double)xr[i] * (double)wr[i];
    double s = s0 + s1;
    for (int off = 32; off; off >>= 1) s += __shfl_xor(s, off);
    if (lane == 0) amb_sv[(size_t)b * A_MAX + c] = s + (double)b_enc[h];
  }
}

// ---------------- kernel 4: zero row, write sure, rank ambiguous, scatter ----------------
__global__ __launch_bounds__(256) void rank_scatter2(
    const int* __restrict__ sure_ix, const float* __restrict__ sure_val,
    const int* __restrict__ sure_cnt,
    const int* __restrict__ amb_ix, const double* __restrict__ amb_sv,
    const int* __restrict__ amb_cnt, const int* __restrict__ kptr,
    float* __restrict__ hidden, int* __restrict__ tk_idx, float* __restrict__ tk_val)
{
  constexpr int H = H_FIX;
  __shared__ double asv[A_MAX];
  __shared__ int    aix[A_MAX];
  const int tid = threadIdx.x, b = blockIdx.x;
  const int k = min(*kptr, K_MAX);
  const int S = min(min(sure_cnt[b], S_MAX), k);
  const int A = min(amb_cnt[b], A_MAX);
  float* hrow = hidden + (size_t)b * H;

  for (int c = tid; c < A; c += 256) {
    asv[c] = amb_sv[(size_t)b * A_MAX + c];
    aix[c] = amb_ix[(size_t)b * A_MAX + c];
  }
  const float4 z4 = {0.f, 0.f, 0.f, 0.f};
  for (int i = tid; i < (H >> 2); i += 256)
    reinterpret_cast<float4*>(hrow)[i] = z4;
  __syncthreads();

  // sure members: value = f32 GEMM approx (err << 1.28 threshold)
  for (int i = tid; i < S; i += 256) {
    const int h = sure_ix[(size_t)b * S_MAX + i];
    const float v = sure_val[(size_t)b * S_MAX + i];
    const float rv = (v > 0.f) ? v : 0.f;
    hrow[h] = rv;
    tk_idx[(size_t)b * K_MAX + i] = h;
    tk_val[(size_t)b * K_MAX + i] = rv;
  }
  // ambiguous: top (k-S) by exact f64 value, index tie-break
  const int m = k - S;
  for (int c = tid; c < A; c += 256) {
    const double v = asv[c];
    const int h = aix[c];
    int r = 0;
    for (int j = 0; j < A; ++j) {
      const double vj = asv[j];
      r += ((vj > v) || (vj == v && aix[j] < h)) ? 1 : 0;
    }
    if (r < m) {
      const float rv = (v > 0.0) ? (float)v : 0.f;
      hrow[h] = rv;
      tk_idx[(size_t)b * K_MAX + S + r] = h;
      tk_val[(size_t)b * K_MAX + S + r] = rv;
    }
  }
}

// ---------------- fused fallback: single-pass select on u16 keys ----------------
__global__ __launch_bounds__(256, 2) void topk_select(
    const float* __restrict__ X, const float* __restrict__ b_pre,
    const float* __restrict__ W, const float* __restrict__ b_enc,
    float* __restrict__ hidden, int* __restrict__ tk_idx, float* __restrict__ tk_val,
    const int* __restrict__ kptr, int D, float margin)
{
  constexpr int H = H_FIX, NC = H_FIX / (256 * 8);
  __shared__ double cand_sv[CAND_MAX];
  __shared__ float  xr[D_MAX];
  __shared__ int    cand_ix[CAND_MAX];
  __shared__ int    hist[4096];
  __shared__ int    chunk[256];
  __shared__ int    misc[8];

  const int tid = threadIdx.x, b = blockIdx.x;
  const int k = min(*kptr, K_MAX);
  float* hrow = hidden + (size_t)b * H;
  const unsigned short* krow = (const unsigned short*)hrow;

  if (tid < 8) misc[tid] = 0;
  for (int i = tid; i < 4096; i += 256) hist[i] = 0;
  for (int d = tid; d < D; d += 256) xr[d] = X[(size_t)b * D + d] - b_pre[d];

  u16x8 kv[NC];
#pragma unroll
  for (int i = 0; i < NC; ++i)
    kv[i] = *reinterpret_cast<const u16x8*>(krow + ((size_t)i * 256 + tid) * 8);
  __syncthreads();

#pragma unroll
  for (int i = 0; i < NC; ++i)
#pragma unroll
    for (int j = 0; j < 8; ++j)
      atomicAdd(&hist[((unsigned)(unsigned short)kv[i][j]) >> 4], 1);
  __syncthreads();

  int csum = 0;
#pragma unroll
  for (int j = 0; j < 16; ++j) csum += hist[tid * 16 + j];
  chunk[tid] = csum;
  __syncthreads();
  int gt = 0;
  for (int j = tid + 1; j < 256; ++j) gt += chunk[j];
  {
    int run = gt;
#pragma unroll
    for (int j = 15; j >= 0; --j) {
      const int hc = hist[tid * 16 + j];
      if (run < k && k <= run + hc) { misc[0] = tid * 16 + j; misc[1] = run; }
      run += hc;
    }
  }
  __syncthreads();
  const int b1 = misc[0];
  if (tid < 16) chunk[tid] = 0;
  __syncthreads();
#pragma unroll
  for (int i = 0; i < NC; ++i)
#pragma unroll
    for (int j = 0; j < 8; ++j) {
      const unsigned kk = (unsigned)(unsigned short)kv[i][j];
      if ((int)(kk >> 4) == b1) atomicAdd(&chunk[kk & 15], 1);
    }
  __syncthreads();
  if (tid == 0) {
    int run = misc[1];
    int K16 = b1 << 4;
    for (int j = 15; j >= 0; --j) {
      const int c = chunk[j];
      if (run < k && k <= run + c) K16 = (b1 << 4) | j;
      run += c;
    }
    const float vthr = val_of_key((unsigned short)K16) - margin;
    int kt = (int)key_of(vthr);
    if (kt > K16) kt = K16;
    misc[2] = kt;
  }
  __syncthreads();
  const unsigned kthr = (unsigned)misc[2];

#pragma unroll
  for (int i = 0; i < NC; ++i)
#pragma unroll
    for (int j = 0; j < 8; ++j) {
      if ((unsigned)(unsigned short)kv[i][j] >= kthr) {
        const int pos = atomicAdd(&misc[3], 1);
        if (pos < CAND_MAX) cand_ix[pos] = (i * 256 + tid) * 8 + j;
      }
    }
  __syncthreads();
  const int C = min(misc[3], CAND_MAX);

  const float4 z4 = {0.f, 0.f, 0.f, 0.f};
  for (int i = tid; i < (H >> 2); i += 256)
    reinterpret_cast<float4*>(hrow)[i] = z4;

  const int wid = tid >> 6, lane = tid & 63;
  for (int c = wid; c < C; c += 4) {
    const int h = cand_ix[c];
    const float* wr = W + (size_t)h * D;
    double s = 0.0;
    for (int i = lane; i < D; i += 64) s += (double)xr[i] * (double)wr[i];
    for (int off = 32; off; off >>= 1) s += __shfl_xor(s, off);
    if (lane == 0) cand_sv[c] = s + (double)b_enc[h];
  }
  __syncthreads();

  for (int c = tid; c < C; c += 256) {
    const double v = cand_sv[c];
    const int h = cand_ix[c];
    int r = 0;
    for (int j = 0; j < C; ++j) {
      const double vj = cand_sv[j];
      r += ((vj > v) || (vj == v && cand_ix[j] < h)) ? 1 : 0;
    }
    if (r < k) {
      const float rv = (v > 0.0) ? (float)v : 0.f;
      hrow[h] = rv;
      tk_idx[(size_t)b * K_MAX + r] = h;
      tk_val[(size_t)b * K_MAX + r] = rv;
    }
  }
}

// ---------------- fallback: fp32 GEMM ----------------
__global__ __launch_bounds__(256) void enc_gemm_f32(
    const float* __restrict__ X, const float* __restrict__ W,
    const float* __restrict__ b_enc, const float* __restrict__ b_pre,
    float* __restrict__ pre, int D, int H)
{
  __shared__ float As[BKF][BM + 4];
  __shared__ float Bs[BKF][BN + 4];
  const int tid = threadIdx.x;
  const int m0 = blockIdx.y * BM;
  const int n0 = blockIdx.x * BN;
  const int tx = tid & 15, ty = tid >> 4;
  float acc[8][8];
#pragma unroll
  for (int i = 0; i < 8; ++i)
#pragma unroll
    for (int j = 0; j < 8; ++j) acc[i][j] = 0.f;

  for (int kb = 0; kb < D; kb += BKF) {
#pragma unroll
    for (int t = 0; t < 2; ++t) {
      const int f4i = tid + t * 256;
      const int row = f4i >> 2;
      const int kq  = (f4i & 3) << 2;
      float4 xv = *reinterpret_cast<const float4*>(X + (size_t)(m0 + row) * D + kb + kq);
      float4 bp = *reinterpret_cast<const float4*>(b_pre + kb + kq);
      As[kq + 0][row] = xv.x - bp.x; As[kq + 1][row] = xv.y - bp.y;
      As[kq + 2][row] = xv.z - bp.z; As[kq + 3][row] = xv.w - bp.w;
      float4 wv = *reinterpret_cast<const float4*>(W + (size_t)(n0 + row) * D + kb + kq);
      Bs[kq + 0][row] = wv.x; Bs[kq + 1][row] = wv.y;
      Bs[kq + 2][row] = wv.z; Bs[kq + 3][row] = wv.w;
    }
    __syncthreads();
#pragma unroll
    for (int kk = 0; kk < BKF; ++kk) {
      float4 a0 = *reinterpret_cast<const float4*>(&As[kk][ty * 8]);
      float4 a1 = *reinterpret_cast<const float4*>(&As[kk][ty * 8 + 4]);
      float4 b0 = *reinterpret_cast<const float4*>(&Bs[kk][tx * 8]);
      float4 b1 = *reinterpret_cast<const float4*>(&Bs[kk][tx * 8 + 4]);
      float av[8] = {a0.x, a0.y, a0.z, a0.w, a1.x, a1.y, a1.z, a1.w};
      float bv[8] = {b0.x, b0.y, b0.z, b0.w, b1.x, b1.y, b1.z, b1.w};
#pragma unroll
      for (int i = 0; i < 8; ++i)
#pragma unroll
        for (int j = 0; j < 8; ++j) acc[i][j] += av[i] * bv[j];
    }
    __syncthreads();
  }
#pragma unroll
  for (int i = 0; i < 8; ++i) {
    const size_t m = (size_t)(m0 + ty * 8 + i);
#pragma unroll
    for (int j = 0; j < 8; j += 4) {
      const int n = n0 + tx * 8 + j;
      float4 o;
      o.x = acc[i][j + 0] + b_enc[n + 0];
      o.y = acc[i][j + 1] + b_enc[n + 1];
      o.z = acc[i][j + 2] + b_enc[n + 2];
      o.w = acc[i][j + 3] + b_enc[n + 3];
      *reinterpret_cast<float4*>(pre + m * H + n) = o;
    }
  }
}

// ---------------- fallback: bisection top-k (reads f32 pre) ----------------
__global__ __launch_bounds__(256) void topk_refine(
    const float* __restrict__ X, const float* __restrict__ b_pre,
    const float* __restrict__ W, const float* __restrict__ b_enc,
    float* __restrict__ hidden, int* __restrict__ tk_idx, float* __restrict__ tk_val,
    const int* __restrict__ kptr, int D, int H, float margin)
{
  extern __shared__ char smem_raw[];
  double* cand_val = reinterpret_cast<double*>(smem_raw);
  float*  xr       = reinterpret_cast<float*>(cand_val + CAND_MAX);
  int*    cand_idx = reinterpret_cast<int*>(xr + D);
  int*    misc     = cand_idx + CAND_MAX;

  const int tid = threadIdx.x;
  const int b = blockIdx.x;
  const int k = min(*kptr, K_MAX);
  float* hrow = hidden + (size_t)b * H;

  for (int i = tid; i < NBITER + 2; i += 256) misc[i] = 0;
  for (int d = tid; d < D; d += 256) xr[d] = X[(size_t)b * D + d] - b_pre[d];

  float f[64];
#pragma unroll
  for (int i = 0; i < 16; ++i) {
    const int base = i * 1024 + tid * 4;
    float4 v = {-3e38f, -3e38f, -3e38f, -3e38f};
    if (base + 3 < H) v = *reinterpret_cast<const float4*>(hrow + base);
    f[4 * i + 0] = v.x; f[4 * i + 1] = v.y; f[4 * i + 2] = v.z; f[4 * i + 3] = v.w;
  }
  __syncthreads();

  float lo = -1e4f, hi = 1e4f;
  for (int it = 0; it < NBITER; ++it) {
    const float mid = 0.5f * (lo + hi);
    int cnt = 0;
#pragma unroll
    for (int j = 0; j < 64; ++j) cnt += (f[j] >= mid) ? 1 : 0;
    for (int off = 32; off; off >>= 1) cnt += __shfl_xor(cnt, off);
    if ((tid & 63) == 0) atomicAdd(&misc[it], cnt);
    __syncthreads();
    if (misc[it] >= k) lo = mid; else hi = mid;
  }

  const float thresh = lo - margin;
#pragma unroll
  for (int j = 0; j < 64; ++j) {
    if (f[j] >= thresh) {
      const int h = (j >> 2) * 1024 + tid * 4 + (j & 3);
      if (h < H) {
        int pos = atomicAdd(&misc[NBITER], 1);
        if (pos < CAND_MAX) cand_idx[pos] = h;
      }
    }
  }
  __syncthreads();
  const int C = min(misc[NBITER], CAND_MAX);

  const int wid = tid >> 6, lane = tid & 63;
  for (int c = wid; c < C; c += 4) {
    const int h = cand_idx[c];
    const float* wr = W + (size_t)h * D;
    double s = 0.0;
    for (int i = lane; i < D; i += 64) s += (double)xr[i] * (double)wr[i];
    for (int off = 32; off; off >>= 1) s += __shfl_xor(s, off);
    if (lane == 0) cand_val[c] = s + (double)b_enc[h];
  }
  __syncthreads();

  const float4 z4 = {0.f, 0.f, 0.f, 0.f};
  for (int i = tid; i < (H >> 2); i += 256)
    reinterpret_cast<float4*>(hrow)[i] = z4;
  __syncthreads();

  for (int c = tid; c < C; c += 256) {
    const double v = cand_val[c];
    const int h = cand_idx[c];
    int r = 0;
    for (int j = 0; j < C; ++j) {
      const double vj = cand_val[j];
      r += ((vj > v) || (vj == v && cand_idx[j] < h)) ? 1 : 0;
    }
    if (r < k) {
      const float rv = (v > 0.0) ? (float)v : 0.f;
      hrow[h] = rv;
      tk_idx[(size_t)b * K_MAX + r] = h;
      tk_val[(size_t)b * K_MAX + r] = rv;
    }
  }
}

// ---------------- kernel 5: W_dec [D,H] -> bf16 W_decT [H,D] ----------------
__global__ __launch_bounds__(256) void transpose_wdec_bf16(
    const float* __restrict__ Wsrc, unsigned short* __restrict__ WT, int D, int H)
{
  __shared__ float tile[32][33];
  const int c  = threadIdx.x & 31;
  const int r0 = threadIdx.x >> 5;
  const int h0 = blockIdx.x * 32;
  const int d0 = blockIdx.y * 32;
#pragma unroll
  for (int r = r0; r < 32; r += 8) {
    const int d = d0 + r, h = h0 + c;
    if (d < D && h < H) tile[r][c] = Wsrc[(size_t)d * H + h];
  }
  __syncthreads();
#pragma unroll
  for (int r = r0; r < 32; r += 8) {
    const int h = h0 + r, d = d0 + c;
    if (h < H && d < D) WT[(size_t)h * D + d] = f2bf(tile[c][r]);
  }
}

// ---------------- kernel 6: sparse decode + per-row squared error (vectorized) ----------------
__global__ __launch_bounds__(256) void decode_loss(
    const float* __restrict__ X, const float* __restrict__ b_pre,
    const float* __restrict__ b_dec, const float* __restrict__ Wfull,
    const unsigned short* __restrict__ WTb,
    const int* __restrict__ tk_idx, const float* __restrict__ tk_val,
    const int* __restrict__ kptr,
    float* __restrict__ recon, double* __restrict__ row_ssq,
    int D, int H, int useWT)
{
  __shared__ int   sidx[K_MAX];
  __shared__ float sval[K_MAX];
  __shared__ double sd[4];
  const int tid = threadIdx.x, b = blockIdx.x;
  const int k = min(*kptr, K_MAX);
  if (tid < k) {
    sidx[tid] = tk_idx[(size_t)b * K_MAX + tid];
    sval[tid] = tk_val[(size_t)b * K_MAX + tid];
  }
  __syncthreads();
  double ssq = 0.0;
  const int D4 = D >> 2;
  for (int dc = tid; dc < D4; dc += 256) {
    const int d = dc * 4;
    float4 bd = *reinterpret_cast<const float4*>(b_dec + d);
    float4 bp = *reinterpret_cast<const float4*>(b_pre + d);
    float4 a = {bd.x + bp.x, bd.y + bp.y, bd.z + bp.z, bd.w + bp.w};
    if (useWT) {
#pragma unroll 4
      for (int j = 0; j < k; ++j) {
        const ushort4 w = *reinterpret_cast<const ushort4*>(WTb + (size_t)sidx[j] * D + d);
        const float s = sval[j];
        a.x += s * bf2f(w.x); a.y += s * bf2f(w.y);
        a.z += s * bf2f(w.z); a.w += s * bf2f(w.w);
      }
    } else {
#pragma unroll 4
      for (int j = 0; j < k; ++j) {
        const float s = sval[j];
        const int h = sidx[j];
        a.x += s * Wfull[(size_t)(d + 0) * H + h];
        a.y += s * Wfull[(size_t)(d + 1) * H + h];
        a.z += s * Wfull[(size_t)(d + 2) * H + h];
        a.w += s * Wfull[(size_t)(d + 3) * H + h];
      }
    }
    *reinterpret_cast<float4*>(recon + (size_t)b * D + d) = a;
    float4 xv = *reinterpret_cast<const float4*>(X + (size_t)b * D + d);
    const double d0 = (double)a.x - (double)xv.x;
    const double d1 = (double)a.y - (double)xv.y;
    const double d2 = (double)a.z - (double)xv.z;
    const double d3 = (double)a.w - (double)xv.w;
    ssq += d0 * d0 + d1 * d1 + d2 * d2 + d3 * d3;
  }
  for (int off = 32; off; off >>= 1) ssq += __shfl_xor(ssq, off);
  if ((tid & 63) == 0) sd[tid >> 6] = ssq;
  __syncthreads();
  if (tid == 0) row_ssq[b] = sd[0] + sd[1] + sd[2] + sd[3];
}

// ---------------- kernel 7a: per-chunk partial losses (64 blocks) ----------------
__global__ __launch_bounds__(256) void finalize_part(
    const double* __restrict__ row_ssq, const float* __restrict__ tk_val,
    const int* __restrict__ kptr, double* __restrict__ part_s, int* __restrict__ part_c,
    int Bdim, int rows_per_blk)
{
  __shared__ double sd[4];
  __shared__ int si[4];
  const int tid = threadIdx.x;
  const int k = min(*kptr, K_MAX);
  const int b0 = blockIdx.x * rows_per_blk;
  const int b1 = min(b0 + rows_per_blk, Bdim);
  double s = 0.0;
  for (int i = b0 + tid; i < b1; i += 256) s += row_ssq[i];
  int cnt = 0;
  const int total = (b1 - b0) * k;
  for (int i = tid; i < total; i += 256) {
    const int bb = b0 + i / k, j = i - (i / k) * k;
    cnt += (tk_val[(size_t)bb * K_MAX + j] > 0.f) ? 1 : 0;
  }
  for (int off = 32; off; off >>= 1) { s += __shfl_xor(s, off); cnt += __shfl_xor(cnt, off); }
  if ((tid & 63) == 0) { sd[tid >> 6] = s; si[tid >> 6] = cnt; }
  __syncthreads();
  if (tid == 0) {
    part_s[blockIdx.x] = sd[0] + sd[1] + sd[2] + sd[3];
    part_c[blockIdx.x] = si[0] + si[1] + si[2] + si[3];
  }
}

// ---------------- kernel 7b: final scalar losses ----------------
__global__ __launch_bounds__(64) void finalize_k2(
    const double* __restrict__ part_s, const int* __restrict__ part_c,
    float* __restrict__ scalars, int nparts, int Bdim, int D)
{
  const int tid = threadIdx.x;
  double s = (tid < nparts) ? part_s[tid] : 0.0;
  int cnt = (tid < nparts) ? part_c[tid] : 0;
  for (int off = 32; off; off >>= 1) { s += __shfl_xor(s, off); cnt += __shfl_xor(cnt, off); }
  if (tid == 0) {
    const double rl = s / ((double)Bdim * (double)D);
    scalars[0] = (float)rl;                     // loss
    scalars[1] = (float)rl;                     // reconstruction_loss
    scalars[2] = 0.f;                           // sparsity_loss
    scalars[3] = (float)((double)cnt / Bdim);   // l0
  }
}

extern "C" void kernel_launch(void* const* d_in, const int* in_sizes, int n_in,
                              void* d_out, int out_size, void* d_ws, size_t ws_size,
                              hipStream_t stream)
{
  const float* x     = (const float*)d_in[0];
  const float* W_enc = (const float*)d_in[1];
  const float* b_enc = (const float*)d_in[2];
  const float* W_dec = (const float*)d_in[3];
  const float* b_dec = (const float*)d_in[4];
  const float* b_pre = (const float*)d_in[5];
  const int*   kptr  = (const int*)d_in[6];

  const int D = in_sizes[4];          // 1280
  const int H = in_sizes[2];          // 16384
  const int B = in_sizes[0] / D;      // 8192

  float* recon   = (float*)d_out;
  float* hidden  = recon + (size_t)B * D;       // temporarily holds pre (f32 or keys)
  float* scalars = hidden + (size_t)B * H;

  // ---- workspace layout (single running cursor) ----
  size_t off = 0;
  int* tk_idx = (int*)((char*)d_ws + off);        off += (size_t)B * K_MAX * sizeof(int);
  float* tk_val = (float*)((char*)d_ws + off);    off += (size_t)B * K_MAX * sizeof(float);
  off = (off + 7) & ~(size_t)7;
  double* row_ssq = (double*)((char*)d_ws + off); off += (size_t)B * sizeof(double);
  double* part_s = (double*)((char*)d_ws + off);  off += 64 * sizeof(double);
  int* part_c = (int*)((char*)d_ws + off);        off += 64 * sizeof(int);
  off = (off + 7) & ~(size_t)7;

  unsigned short* Xb = (unsigned short*)((char*)d_ws + off);
  off += (size_t)B * D * sizeof(unsigned short);
  unsigned short* Wb = (unsigned short*)((char*)d_ws + off);
  off += (size_t)H * D * sizeof(unsigned short);
  const int useBF16 = (off <= ws_size) ? 1 : 0;

  unsigned short* WTb = (unsigned short*)((char*)d_ws + off);
  off += (size_t)D * H * sizeof(unsigned short);
  const int useWT = (off <= ws_size) ? 1 : 0;

  int* sure_ix = (int*)((char*)d_ws + off);       off += (size_t)B * S_MAX * sizeof(int);
  float* sure_val = (float*)((char*)d_ws + off);  off += (size_t)B * S_MAX * sizeof(float);
  int* sure_cnt = (int*)((char*)d_ws + off);      off += (size_t)B * sizeof(int);
  int* amb_ix = (int*)((char*)d_ws + off);        off += (size_t)B * A_MAX * sizeof(int);
  int* amb_cnt = (int*)((char*)d_ws + off);       off += (size_t)B * sizeof(int);
  off = (off + 7) & ~(size_t)7;
  double* amb_sv = (double*)((char*)d_ws + off);  off += (size_t)B * A_MAX * sizeof(double);
  const int useSPLIT = (useBF16 && off <= ws_size) ? 1 : 0;

  const bool fast_ok = (D % 64 == 0) && (D <= D_MAX) &&
                       (H == H_FIX) && (B % 128 == 0);

  if (useBF16 && fast_ok) {
    const size_t tx4 = (size_t)B * D / 4, tw4 = (size_t)H * D / 4;
    prep_xb<<<2048, 256, 0, stream>>>(x, b_pre, Xb, D, tx4);
    prep_wb<<<2048, 256, 0, stream>>>(W_enc, Wb, tw4);
    dim3 gg(H / 128, B / 128);
    if (useSPLIT) {
      enc_gemm_bf16<<<gg, 256, 0, stream>>>(Xb, Wb, b_enc, hidden, D, H, 0);  // f32 pre
      // delta >= 2*eps: eps (max |f32approx - f64|) <= ~0.015 -> delta 0.04
      topk_classify<<<B, 256, 0, stream>>>(hidden, sure_ix, sure_val, sure_cnt,
                                           amb_ix, amb_cnt, kptr, 0.04f);
      refine_f64<<<B, 256, 0, stream>>>(x, b_pre, W_enc, b_enc, amb_ix, amb_cnt, amb_sv, D);
      rank_scatter2<<<B, 256, 0, stream>>>(sure_ix, sure_val, sure_cnt,
                                           amb_ix, amb_sv, amb_cnt, kptr,
                                           hidden, tk_idx, tk_val);
    } else {
      enc_gemm_bf16<<<gg, 256, 0, stream>>>(Xb, Wb, b_enc, hidden, D, H, 1);  // u16 keys
      topk_select<<<B, 256, 0, stream>>>(x, b_pre, W_enc, b_enc, hidden,
                                         tk_idx, tk_val, kptr, D, 0.04f);
    }
  } else {
    dim3 gg(H / BN, B / BM);
    enc_gemm_f32<<<gg, 256, 0, stream>>>(x, W_enc, b_enc, b_pre, hidden, D, H);
    const size_t sh = CAND_MAX * sizeof(double) + (size_t)D * sizeof(float)
                    + CAND_MAX * sizeof(int) + (NBITER + 8) * sizeof(int);
    topk_refine<<<B, 256, sh, stream>>>(x, b_pre, W_enc, b_enc, hidden,
                                        tk_idx, tk_val, kptr, D, H, 1e-3f);
  }

  if (useWT)
    transpose_wdec_bf16<<<dim3((H + 31) / 32, (D + 31) / 32), 256, 0, stream>>>(W_dec, WTb, D, H);

  decode_loss<<<B, 256, 0, stream>>>(x, b_pre, b_dec, W_dec, WTb,
                                     tk_idx, tk_val, kptr, recon, row_ssq, D, H, useWT);

  const int rpb = (B + 63) / 64;
  finalize_part<<<64, 256, 0, stream>>>(row_ssq, tk_val, kptr, part_s, part_c, B, rpb);
  finalize_k2<<<1, 64, 0, stream>>>(part_s, part_c, scalars, 64, B, D);
}

// Round 8
// 1250.288 us; speedup vs baseline: 4.9063x; 1.0638x over previous
//
#include <hip/hip_runtime.h>
#include <hip/hip_bf16.h>

constexpr int K_MAX    = 128;   // max supported k (actual k=64 read from device)
constexpr int S_MAX    = 128;   // sure-member cap per row
constexpr int A_MAX    = 256;   // ambiguous cap per row
constexpr int P_MAX    = 384;   // loose candidate pool cap (LDS)
constexpr int CAND_MAX = 512;   // fused-fallback candidate cap
constexpr int BM = 128, BN = 128, BKF = 16;
constexpr int NBITER = 42;      // fallback bisection iterations
constexpr int D_MAX   = 2048;   // fast path requires D <= D_MAX
constexpr int H_FIX   = 16384;  // fast path requires H == H_FIX

typedef __attribute__((ext_vector_type(8))) short bf16x8;
typedef __attribute__((ext_vector_type(8))) unsigned short u16x8;
typedef __attribute__((ext_vector_type(4))) float f32x4;

__device__ inline unsigned short f2bf(float f) {   // round-to-nearest-even
  unsigned u = __float_as_uint(f);
  return (unsigned short)((u + 0x7fff + ((u >> 16) & 1)) >> 16);
}
// monotone 16-bit key: key order == value order (handles negatives)
__device__ inline unsigned short key_of(float f) {
  unsigned short b = f2bf(f);
  return b ^ ((b & 0x8000) ? 0xFFFF : 0x8000);
}
__device__ inline float val_of_key(unsigned short kk) {
  unsigned short b = (kk & 0x8000) ? (unsigned short)(kk ^ 0x8000)
                                   : (unsigned short)(kk ^ 0xFFFF);
  return __uint_as_float(((unsigned)b) << 16);
}
__device__ inline float bf2f(unsigned short b) {
  return __uint_as_float(((unsigned)b) << 16);
}

// conflict-free superrow swizzle: 16B-chunk slot of (row r, chunk c) in a
// [128 rows x 8 chunks] tile. Within each 256B super-row (2 rows, 16 slots),
// slot = (r&1)*8 + (c ^ ((r>>1)&7)). Fragment reads (16 lanes, rows r..r+15,
// fixed c) then hit 16 DISTINCT slots spanning all 32 banks.
__device__ inline int lds_slot(int r, int c) {
  return ((r >> 1) << 4) | ((r & 1) << 3) | (c ^ ((r >> 1) & 7));
}

// ---------------- prep: Xb = bf16(x - b_pre), Wb = bf16(W_enc) ----------------
__global__ __launch_bounds__(256) void prep_xb(
    const float* __restrict__ x, const float* __restrict__ b_pre,
    unsigned short* __restrict__ Xb, int D, size_t total4)
{
  for (size_t i = blockIdx.x * 256 + threadIdx.x; i < total4; i += (size_t)gridDim.x * 256) {
    const size_t e = i * 4;
    const int d = (int)(e % D);
    float4 xv = *reinterpret_cast<const float4*>(x + e);
    float4 bp = *reinterpret_cast<const float4*>(b_pre + d);
    ushort4 o;
    o.x = f2bf(xv.x - bp.x); o.y = f2bf(xv.y - bp.y);
    o.z = f2bf(xv.z - bp.z); o.w = f2bf(xv.w - bp.w);
    *reinterpret_cast<ushort4*>(Xb + e) = o;
  }
}

__global__ __launch_bounds__(256) void prep_wb(
    const float* __restrict__ W, unsigned short* __restrict__ Wb, size_t total4)
{
  for (size_t i = blockIdx.x * 256 + threadIdx.x; i < total4; i += (size_t)gridDim.x * 256) {
    const size_t e = i * 4;
    float4 wv = *reinterpret_cast<const float4*>(W + e);
    ushort4 o;
    o.x = f2bf(wv.x); o.y = f2bf(wv.y); o.z = f2bf(wv.z); o.w = f2bf(wv.w);
    *reinterpret_cast<ushort4*>(Wb + e) = o;
  }
}

// ---------------- kernel 1: encoder GEMM, bf16 MFMA ----------------
// BK=64, double-buffered LDS, stage-first, ONE barrier per K-tile.
// LDS layout: superrow-swizzled 16B chunks (conflict-free ds_read_b128).
// Staging keeps the LDS dest linear (global_load_lds constraint) and fetches
// the inverse-permuted GLOBAL chunk per lane (both-sides-or-neither).
__global__ __launch_bounds__(256) void enc_gemm_bf16(
    const unsigned short* __restrict__ Xb, const unsigned short* __restrict__ Wb,
    const float* __restrict__ b_enc, float* __restrict__ pre, int D, int H, int writeKeys)
{
  __shared__ unsigned short As[2][128 * 64];   // 128 rows x 64 ushort, swizzled chunks
  __shared__ unsigned short Bs[2][128 * 64];
  const int tid  = threadIdx.x;
  const int wave = tid >> 6, lane = tid & 63;
  const int m0 = blockIdx.y * 128, n0 = blockIdx.x * 128;
  const int wm = (wave >> 1) * 64, wn = (wave & 1) * 64;
  const int l16 = lane & 15, lhi = lane >> 4;

  // per-lane staging decode: LDS slot idx -> (row, global chunk)
  // idx = base + lane; sr = idx>>4; u = idx&15; row = sr*2 + (u>>3); ch = (u&7)^(sr&7)
  f32x4 acc[4][4];
#pragma unroll
  for (int i = 0; i < 4; ++i)
#pragma unroll
    for (int j = 0; j < 4; ++j) acc[i][j] = (f32x4){0.f, 0.f, 0.f, 0.f};

  const int NT = D / 64;

  // prologue: stage tile 0 into buffer 0
#pragma unroll
  for (int i = 0; i < 4; ++i) {
    const int base = wave * 64 + i * 256;     // wave-uniform slot base (1024B aligned)
    const int idx  = base + lane;
    const int sr = idx >> 4, u = idx & 15;
    const int row = (sr << 1) | (u >> 3);
    const int ch  = (u & 7) ^ (sr & 7);
    __builtin_amdgcn_global_load_lds(
        (const __attribute__((address_space(1))) unsigned int*)(Xb + (size_t)(m0 + row) * D + ch * 8),
        (__attribute__((address_space(3))) unsigned int*)(As[0] + (size_t)base * 8), 16, 0, 0);
    __builtin_amdgcn_global_load_lds(
        (const __attribute__((address_space(1))) unsigned int*)(Wb + (size_t)(n0 + row) * D + ch * 8),
        (__attribute__((address_space(3))) unsigned int*)(Bs[0] + (size_t)base * 8), 16, 0, 0);
  }
  __syncthreads();   // compiler emits vmcnt(0) drain before s_barrier

  int cur = 0;
  for (int t = 0; t < NT; ++t) {
    // issue next tile's staging BEFORE compute (overlaps with MFMA below)
    if (t + 1 < NT) {
      const int kb = (t + 1) * 64;
      const int nxt = cur ^ 1;
#pragma unroll
      for (int i = 0; i < 4; ++i) {
        const int base = wave * 64 + i * 256;
        const int idx  = base + lane;
        const int sr = idx >> 4, u = idx & 15;
        const int row = (sr << 1) | (u >> 3);
        const int ch  = (u & 7) ^ (sr & 7);
        __builtin_amdgcn_global_load_lds(
            (const __attribute__((address_space(1))) unsigned int*)(Xb + (size_t)(m0 + row) * D + kb + ch * 8),
            (__attribute__((address_space(3))) unsigned int*)(As[nxt] + (size_t)base * 8), 16, 0, 0);
        __builtin_amdgcn_global_load_lds(
            (const __attribute__((address_space(1))) unsigned int*)(Wb + (size_t)(n0 + row) * D + kb + ch * 8),
            (__attribute__((address_space(3))) unsigned int*)(Bs[nxt] + (size_t)base * 8), 16, 0, 0);
      }
    }
    // compute current tile (K=64 = two K=32 slices); swizzled fragment reads
#pragma unroll
    for (int kk = 0; kk < 2; ++kk) {
      bf16x8 af[4], bfr[4];
#pragma unroll
      for (int mi = 0; mi < 4; ++mi)
        af[mi] = *reinterpret_cast<const bf16x8*>(
            As[cur] + (size_t)lds_slot(wm + mi * 16 + l16, kk * 4 + lhi) * 8);
#pragma unroll
      for (int ni = 0; ni < 4; ++ni)
        bfr[ni] = *reinterpret_cast<const bf16x8*>(
            Bs[cur] + (size_t)lds_slot(wn + ni * 16 + l16, kk * 4 + lhi) * 8);
#pragma unroll
      for (int mi = 0; mi < 4; ++mi)
#pragma unroll
        for (int ni = 0; ni < 4; ++ni)
          acc[mi][ni] = __builtin_amdgcn_mfma_f32_16x16x32_bf16(af[mi], bfr[ni], acc[mi][ni], 0, 0, 0);
    }
    __syncthreads();   // drains next-tile stores + protects buffer reuse
    cur ^= 1;
  }

  if (writeKeys) {
#pragma unroll
    for (int ni = 0; ni < 4; ++ni) {
      const int n = n0 + wn + ni * 16 + l16;
      const float be = b_enc[n];
#pragma unroll
      for (int mi = 0; mi < 4; ++mi) {
        const int mbase = m0 + wm + mi * 16 + lhi * 4;
#pragma unroll
        for (int r = 0; r < 4; ++r) {
          unsigned short* prow = (unsigned short*)(pre + (size_t)(mbase + r) * H);
          prow[n] = key_of(acc[mi][ni][r] + be);
        }
      }
    }
  } else {
#pragma unroll
    for (int ni = 0; ni < 4; ++ni) {
      const int n = n0 + wn + ni * 16 + l16;
      const float be = b_enc[n];
#pragma unroll
      for (int mi = 0; mi < 4; ++mi) {
        const int mbase = m0 + wm + mi * 16 + lhi * 4;
#pragma unroll
        for (int r = 0; r < 4; ++r)
          pre[(size_t)(mbase + r) * H + n] = acc[mi][ni][r] + be;
      }
    }
  }
}

// ---------------- kernel 2: classify rows into sure members + ambiguous band ----------------
__global__ __launch_bounds__(256) void topk_classify(
    const float* __restrict__ pre,
    int* __restrict__ sure_ix, float* __restrict__ sure_val, int* __restrict__ sure_cnt,
    int* __restrict__ amb_ix, int* __restrict__ amb_cnt,
    const int* __restrict__ kptr, float delta)
{
  constexpr int H = H_FIX;
  __shared__ int   hist[4096];
  __shared__ int   chunk[256];
  __shared__ int   misc[8];
  __shared__ float fth[2];
  __shared__ float pot_v[P_MAX];
  __shared__ int   pot_i[P_MAX];

  const int tid = threadIdx.x, b = blockIdx.x;
  const int k = min(*kptr, K_MAX);
  const float* prow = pre + (size_t)b * H;

  if (tid < 8) misc[tid] = 0;
  for (int i = tid; i < 4096; i += 256) hist[i] = 0;
  __syncthreads();

  // ---- pass 1: histogram of bf16 keys (bins = key>>4) ----
  for (int i = tid; i < H / 4; i += 256) {
    float4 v = reinterpret_cast<const float4*>(prow)[i];
    atomicAdd(&hist[key_of(v.x) >> 4], 1);
    atomicAdd(&hist[key_of(v.y) >> 4], 1);
    atomicAdd(&hist[key_of(v.z) >> 4], 1);
    atomicAdd(&hist[key_of(v.w) >> 4], 1);
  }
  __syncthreads();

  // ---- find bin b1 containing the k-th largest key ----
  int csum = 0;
#pragma unroll
  for (int j = 0; j < 16; ++j) csum += hist[tid * 16 + j];
  chunk[tid] = csum;
  __syncthreads();
  int gt = 0;
  for (int j = tid + 1; j < 256; ++j) gt += chunk[j];
  {
    int run = gt;
#pragma unroll
    for (int j = 15; j >= 0; --j) {
      const int hc = hist[tid * 16 + j];
      if (run < k && k <= run + hc) { misc[0] = tid * 16 + j; misc[1] = run; }
      run += hc;
    }
  }
  __syncthreads();
  const int b1 = misc[0];
  if (tid < 16) chunk[tid] = 0;
  __syncthreads();

  // loose lower bound: guaranteed <= final ambiguous threshold, and < bin b1 bottom
  const float binlo = val_of_key((unsigned short)(b1 << 4));
  const float binhi = val_of_key((unsigned short)min((b1 << 4) + 16, 65535));
  const float v_loose = binlo - delta - (binhi - binlo) * 0.25f;

  // ---- pass 2 (L2-hot): collect loose pool only ----
  for (int i = tid; i < H / 4; i += 256) {
    float4 v = reinterpret_cast<const float4*>(prow)[i];
    const float f[4] = {v.x, v.y, v.z, v.w};
#pragma unroll
    for (int c = 0; c < 4; ++c) {
      if (f[c] >= v_loose) {
        const int p = atomicAdd(&misc[6], 1);
        if (p < P_MAX) { pot_v[p] = f[c]; pot_i[p] = 4 * i + c; }
      }
    }
  }
  __syncthreads();
  const int P = min(misc[6], P_MAX);

  // ---- sub-bin counts of bin b1 from the pool ----
  for (int i = tid; i < P; i += 256) {
    const unsigned short kk = key_of(pot_v[i]);
    if ((int)(kk >> 4) == b1) atomicAdd(&chunk[kk & 15], 1);
  }
  __syncthreads();

  // ---- exact k-th key -> f32 thresholds ----
  if (tid == 0) {
    int run = misc[1];
    int K16 = b1 << 4;
    for (int j = 15; j >= 0; --j) {
      const int c = chunk[j];
      if (run < k && k <= run + c) K16 = (b1 << 4) | j;
      run += c;
    }
    const float v_lo = val_of_key((unsigned short)K16);
    const float v_hi = val_of_key((unsigned short)min(K16 + 1, 65535));
    const float ulp = v_hi - v_lo;
    fth[0] = v_hi + delta;          // sure: f >  fth[0]
    fth[1] = v_lo - ulp - delta;    // amb : f >= fth[1]
  }
  __syncthreads();
  const float vs = fth[0], va = fth[1];

  // ---- classify pool ----
  for (int i = tid; i < P; i += 256) {
    const float f = pot_v[i];
    const int h = pot_i[i];
    if (f > vs) {
      const int p = atomicAdd(&misc[4], 1);
      if (p < S_MAX) { sure_ix[(size_t)b * S_MAX + p] = h; sure_val[(size_t)b * S_MAX + p] = f; }
    } else if (f >= va) {
      const int p = atomicAdd(&misc[5], 1);
      if (p < A_MAX) amb_ix[(size_t)b * A_MAX + p] = h;
    }
  }
  __syncthreads();
  if (tid == 0) {
    sure_cnt[b] = min(misc[4], S_MAX);
    amb_cnt[b]  = min(misc[5], A_MAX);
  }
}

// ---------------- kernel 3: exact f64 dot products for ambiguous only ----------------
__global__ __launch_bounds__(256) void refine_f64(
    const float* __restrict__ X, const float* __restrict__ b_pre,
    const float* __restrict__ W, const float* __restrict__ b_enc,
    const int* __restrict__ amb_ix, const int* __restrict__ amb_cnt,
    double* __restrict__ amb_sv, int D)
{
  __shared__ float xr[D_MAX];
  const int tid = threadIdx.x, b = blockIdx.x;
  const int C = min(amb_cnt[b], A_MAX);
  for (int d = tid; d < D; d += 256) xr[d] = X[(size_t)b * D + d] - b_pre[d];
  __syncthreads();
  const int wid = tid >> 6, lane = tid & 63;
  for (int c = wid; c < C; c += 4) {
    const int h = amb_ix[(size_t)b * A_MAX + c];
    const float* wr = W + (size_t)h * D;
    double s0 = 0.0, s1 = 0.0;
    int i = lane;
    for (; i + 64 < D; i += 128) {
      s0 += (double)xr[i] * (double)wr[i];
      s1 += (double)xr[i + 64] * (double)wr[i + 64];
    }
    if (i < D) s0 += (double)xr[i] * (double)wr[i];
    double s = s0 + s1;
    for (int off = 32; off; off >>= 1) s += __shfl_xor(s, off);
    if (lane == 0) amb_sv[(size_t)b * A_MAX + c] = s + (double)b_enc[h];
  }
}

// ---------------- kernel 4: zero row, write sure, rank ambiguous, scatter ----------------
__global__ __launch_bounds__(256) void rank_scatter2(
    const int* __restrict__ sure_ix, const float* __restrict__ sure_val,
    const int* __restrict__ sure_cnt,
    const int* __restrict__ amb_ix, const double* __restrict__ amb_sv,
    const int* __restrict__ amb_cnt, const int* __restrict__ kptr,
    float* __restrict__ hidden, int* __restrict__ tk_idx, float* __restrict__ tk_val)
{
  constexpr int H = H_FIX;
  __shared__ double asv[A_MAX];
  __shared__ int    aix[A_MAX];
  const int tid = threadIdx.x, b = blockIdx.x;
  const int k = min(*kptr, K_MAX);
  const int S = min(min(sure_cnt[b], S_MAX), k);
  const int A = min(amb_cnt[b], A_MAX);
  float* hrow = hidden + (size_t)b * H;

  for (int c = tid; c < A; c += 256) {
    asv[c] = amb_sv[(size_t)b * A_MAX + c];
    aix[c] = amb_ix[(size_t)b * A_MAX + c];
  }
  const float4 z4 = {0.f, 0.f, 0.f, 0.f};
  for (int i = tid; i < (H >> 2); i += 256)
    reinterpret_cast<float4*>(hrow)[i] = z4;
  __syncthreads();

  // sure members: value = f32 GEMM approx (err << 1.28 threshold)
  for (int i = tid; i < S; i += 256) {
    const int h = sure_ix[(size_t)b * S_MAX + i];
    const float v = sure_val[(size_t)b * S_MAX + i];
    const float rv = (v > 0.f) ? v : 0.f;
    hrow[h] = rv;
    tk_idx[(size_t)b * K_MAX + i] = h;
    tk_val[(size_t)b * K_MAX + i] = rv;
  }
  // ambiguous: top (k-S) by exact f64 value, index tie-break
  const int m = k - S;
  for (int c = tid; c < A; c += 256) {
    const double v = asv[c];
    const int h = aix[c];
    int r = 0;
    for (int j = 0; j < A; ++j) {
      const double vj = asv[j];
      r += ((vj > v) || (vj == v && aix[j] < h)) ? 1 : 0;
    }
    if (r < m) {
      const float rv = (v > 0.0) ? (float)v : 0.f;
      hrow[h] = rv;
      tk_idx[(size_t)b * K_MAX + S + r] = h;
      tk_val[(size_t)b * K_MAX + S + r] = rv;
    }
  }
}

// ---------------- fused fallback: single-pass select on u16 keys ----------------
__global__ __launch_bounds__(256, 2) void topk_select(
    const float* __restrict__ X, const float* __restrict__ b_pre,
    const float* __restrict__ W, const float* __restrict__ b_enc,
    float* __restrict__ hidden, int* __restrict__ tk_idx, float* __restrict__ tk_val,
    const int* __restrict__ kptr, int D, float margin)
{
  constexpr int H = H_FIX, NC = H_FIX / (256 * 8);
  __shared__ double cand_sv[CAND_MAX];
  __shared__ float  xr[D_MAX];
  __shared__ int    cand_ix[CAND_MAX];
  __shared__ int    hist[4096];
  __shared__ int    chunk[256];
  __shared__ int    misc[8];

  const int tid = threadIdx.x, b = blockIdx.x;
  const int k = min(*kptr, K_MAX);
  float* hrow = hidden + (size_t)b * H;
  const unsigned short* krow = (const unsigned short*)hrow;

  if (tid < 8) misc[tid] = 0;
  for (int i = tid; i < 4096; i += 256) hist[i] = 0;
  for (int d = tid; d < D; d += 256) xr[d] = X[(size_t)b * D + d] - b_pre[d];

  u16x8 kv[NC];
#pragma unroll
  for (int i = 0; i < NC; ++i)
    kv[i] = *reinterpret_cast<const u16x8*>(krow + ((size_t)i * 256 + tid) * 8);
  __syncthreads();

#pragma unroll
  for (int i = 0; i < NC; ++i)
#pragma unroll
    for (int j = 0; j < 8; ++j)
      atomicAdd(&hist[((unsigned)(unsigned short)kv[i][j]) >> 4], 1);
  __syncthreads();

  int csum = 0;
#pragma unroll
  for (int j = 0; j < 16; ++j) csum += hist[tid * 16 + j];
  chunk[tid] = csum;
  __syncthreads();
  int gt = 0;
  for (int j = tid + 1; j < 256; ++j) gt += chunk[j];
  {
    int run = gt;
#pragma unroll
    for (int j = 15; j >= 0; --j) {
      const int hc = hist[tid * 16 + j];
      if (run < k && k <= run + hc) { misc[0] = tid * 16 + j; misc[1] = run; }
      run += hc;
    }
  }
  __syncthreads();
  const int b1 = misc[0];
  if (tid < 16) chunk[tid] = 0;
  __syncthreads();
#pragma unroll
  for (int i = 0; i < NC; ++i)
#pragma unroll
    for (int j = 0; j < 8; ++j) {
      const unsigned kk = (unsigned)(unsigned short)kv[i][j];
      if ((int)(kk >> 4) == b1) atomicAdd(&chunk[kk & 15], 1);
    }
  __syncthreads();
  if (tid == 0) {
    int run = misc[1];
    int K16 = b1 << 4;
    for (int j = 15; j >= 0; --j) {
      const int c = chunk[j];
      if (run < k && k <= run + c) K16 = (b1 << 4) | j;
      run += c;
    }
    const float vthr = val_of_key((unsigned short)K16) - margin;
    int kt = (int)key_of(vthr);
    if (kt > K16) kt = K16;
    misc[2] = kt;
  }
  __syncthreads();
  const unsigned kthr = (unsigned)misc[2];

#pragma unroll
  for (int i = 0; i < NC; ++i)
#pragma unroll
    for (int j = 0; j < 8; ++j) {
      if ((unsigned)(unsigned short)kv[i][j] >= kthr) {
        const int pos = atomicAdd(&misc[3], 1);
        if (pos < CAND_MAX) cand_ix[pos] = (i * 256 + tid) * 8 + j;
      }
    }
  __syncthreads();
  const int C = min(misc[3], CAND_MAX);

  const float4 z4 = {0.f, 0.f, 0.f, 0.f};
  for (int i = tid; i < (H >> 2); i += 256)
    reinterpret_cast<float4*>(hrow)[i] = z4;

  const int wid = tid >> 6, lane = tid & 63;
  for (int c = wid; c < C; c += 4) {
    const int h = cand_ix[c];
    const float* wr = W + (size_t)h * D;
    double s = 0.0;
    for (int i = lane; i < D; i += 64) s += (double)xr[i] * (double)wr[i];
    for (int off = 32; off; off >>= 1) s += __shfl_xor(s, off);
    if (lane == 0) cand_sv[c] = s + (double)b_enc[h];
  }
  __syncthreads();

  for (int c = tid; c < C; c += 256) {
    const double v = cand_sv[c];
    const int h = cand_ix[c];
    int r = 0;
    for (int j = 0; j < C; ++j) {
      const double vj = cand_sv[j];
      r += ((vj > v) || (vj == v && cand_ix[j] < h)) ? 1 : 0;
    }
    if (r < k) {
      const float rv = (v > 0.0) ? (float)v : 0.f;
      hrow[h] = rv;
      tk_idx[(size_t)b * K_MAX + r] = h;
      tk_val[(size_t)b * K_MAX + r] = rv;
    }
  }
}

// ---------------- fallback: fp32 GEMM ----------------
__global__ __launch_bounds__(256) void enc_gemm_f32(
    const float* __restrict__ X, const float* __restrict__ W,
    const float* __restrict__ b_enc, const float* __restrict__ b_pre,
    float* __restrict__ pre, int D, int H)
{
  __shared__ float As[BKF][BM + 4];
  __shared__ float Bs[BKF][BN + 4];
  const int tid = threadIdx.x;
  const int m0 = blockIdx.y * BM;
  const int n0 = blockIdx.x * BN;
  const int tx = tid & 15, ty = tid >> 4;
  float acc[8][8];
#pragma unroll
  for (int i = 0; i < 8; ++i)
#pragma unroll
    for (int j = 0; j < 8; ++j) acc[i][j] = 0.f;

  for (int kb = 0; kb < D; kb += BKF) {
#pragma unroll
    for (int t = 0; t < 2; ++t) {
      const int f4i = tid + t * 256;
      const int row = f4i >> 2;
      const int kq  = (f4i & 3) << 2;
      float4 xv = *reinterpret_cast<const float4*>(X + (size_t)(m0 + row) * D + kb + kq);
      float4 bp = *reinterpret_cast<const float4*>(b_pre + kb + kq);
      As[kq + 0][row] = xv.x - bp.x; As[kq + 1][row] = xv.y - bp.y;
      As[kq + 2][row] = xv.z - bp.z; As[kq + 3][row] = xv.w - bp.w;
      float4 wv = *reinterpret_cast<const float4*>(W + (size_t)(n0 + row) * D + kb + kq);
      Bs[kq + 0][row] = wv.x; Bs[kq + 1][row] = wv.y;
      Bs[kq + 2][row] = wv.z; Bs[kq + 3][row] = wv.w;
    }
    __syncthreads();
#pragma unroll
    for (int kk = 0; kk < BKF; ++kk) {
      float4 a0 = *reinterpret_cast<const float4*>(&As[kk][ty * 8]);
      float4 a1 = *reinterpret_cast<const float4*>(&As[kk][ty * 8 + 4]);
      float4 b0 = *reinterpret_cast<const float4*>(&Bs[kk][tx * 8]);
      float4 b1 = *reinterpret_cast<const float4*>(&Bs[kk][tx * 8 + 4]);
      float av[8] = {a0.x, a0.y, a0.z, a0.w, a1.x, a1.y, a1.z, a1.w};
      float bv[8] = {b0.x, b0.y, b0.z, b0.w, b1.x, b1.y, b1.z, b1.w};
#pragma unroll
      for (int i = 0; i < 8; ++i)
#pragma unroll
        for (int j = 0; j < 8; ++j) acc[i][j] += av[i] * bv[j];
    }
    __syncthreads();
  }
#pragma unroll
  for (int i = 0; i < 8; ++i) {
    const size_t m = (size_t)(m0 + ty * 8 + i);
#pragma unroll
    for (int j = 0; j < 8; j += 4) {
      const int n = n0 + tx * 8 + j;
      float4 o;
      o.x = acc[i][j + 0] + b_enc[n + 0];
      o.y = acc[i][j + 1] + b_enc[n + 1];
      o.z = acc[i][j + 2] + b_enc[n + 2];
      o.w = acc[i][j + 3] + b_enc[n + 3];
      *reinterpret_cast<float4*>(pre + m * H + n) = o;
    }
  }
}

// ---------------- fallback: bisection top-k (reads f32 pre) ----------------
__global__ __launch_bounds__(256) void topk_refine(
    const float* __restrict__ X, const float* __restrict__ b_pre,
    const float* __restrict__ W, const float* __restrict__ b_enc,
    float* __restrict__ hidden, int* __restrict__ tk_idx, float* __restrict__ tk_val,
    const int* __restrict__ kptr, int D, int H, float margin)
{
  extern __shared__ char smem_raw[];
  double* cand_val = reinterpret_cast<double*>(smem_raw);
  float*  xr       = reinterpret_cast<float*>(cand_val + CAND_MAX);
  int*    cand_idx = reinterpret_cast<int*>(xr + D);
  int*    misc     = cand_idx + CAND_MAX;

  const int tid = threadIdx.x;
  const int b = blockIdx.x;
  const int k = min(*kptr, K_MAX);
  float* hrow = hidden + (size_t)b * H;

  for (int i = tid; i < NBITER + 2; i += 256) misc[i] = 0;
  for (int d = tid; d < D; d += 256) xr[d] = X[(size_t)b * D + d] - b_pre[d];

  float f[64];
#pragma unroll
  for (int i = 0; i < 16; ++i) {
    const int base = i * 1024 + tid * 4;
    float4 v = {-3e38f, -3e38f, -3e38f, -3e38f};
    if (base + 3 < H) v = *reinterpret_cast<const float4*>(hrow + base);
    f[4 * i + 0] = v.x; f[4 * i + 1] = v.y; f[4 * i + 2] = v.z; f[4 * i + 3] = v.w;
  }
  __syncthreads();

  float lo = -1e4f, hi = 1e4f;
  for (int it = 0; it < NBITER; ++it) {
    const float mid = 0.5f * (lo + hi);
    int cnt = 0;
#pragma unroll
    for (int j = 0; j < 64; ++j) cnt += (f[j] >= mid) ? 1 : 0;
    for (int off = 32; off; off >>= 1) cnt += __shfl_xor(cnt, off);
    if ((tid & 63) == 0) atomicAdd(&misc[it], cnt);
    __syncthreads();
    if (misc[it] >= k) lo = mid; else hi = mid;
  }

  const float thresh = lo - margin;
#pragma unroll
  for (int j = 0; j < 64; ++j) {
    if (f[j] >= thresh) {
      const int h = (j >> 2) * 1024 + tid * 4 + (j & 3);
      if (h < H) {
        int pos = atomicAdd(&misc[NBITER], 1);
        if (pos < CAND_MAX) cand_idx[pos] = h;
      }
    }
  }
  __syncthreads();
  const int C = min(misc[NBITER], CAND_MAX);

  const int wid = tid >> 6, lane = tid & 63;
  for (int c = wid; c < C; c += 4) {
    const int h = cand_idx[c];
    const float* wr = W + (size_t)h * D;
    double s = 0.0;
    for (int i = lane; i < D; i += 64) s += (double)xr[i] * (double)wr[i];
    for (int off = 32; off; off >>= 1) s += __shfl_xor(s, off);
    if (lane == 0) cand_val[c] = s + (double)b_enc[h];
  }
  __syncthreads();

  const float4 z4 = {0.f, 0.f, 0.f, 0.f};
  for (int i = tid; i < (H >> 2); i += 256)
    reinterpret_cast<float4*>(hrow)[i] = z4;
  __syncthreads();

  for (int c = tid; c < C; c += 256) {
    const double v = cand_val[c];
    const int h = cand_idx[c];
    int r = 0;
    for (int j = 0; j < C; ++j) {
      const double vj = cand_val[j];
      r += ((vj > v) || (vj == v && cand_idx[j] < h)) ? 1 : 0;
    }
    if (r < k) {
      const float rv = (v > 0.0) ? (float)v : 0.f;
      hrow[h] = rv;
      tk_idx[(size_t)b * K_MAX + r] = h;
      tk_val[(size_t)b * K_MAX + r] = rv;
    }
  }
}

// ---------------- kernel 5: W_dec [D,H] -> bf16 W_decT [H,D] ----------------
__global__ __launch_bounds__(256) void transpose_wdec_bf16(
    const float* __restrict__ Wsrc, unsigned short* __restrict__ WT, int D, int H)
{
  __shared__ float tile[32][33];
  const int c  = threadIdx.x & 31;
  const int r0 = threadIdx.x >> 5;
  const int h0 = blockIdx.x * 32;
  const int d0 = blockIdx.y * 32;
#pragma unroll
  for (int r = r0; r < 32; r += 8) {
    const int d = d0 + r, h = h0 + c;
    if (d < D && h < H) tile[r][c] = Wsrc[(size_t)d * H + h];
  }
  __syncthreads();
#pragma unroll
  for (int r = r0; r < 32; r += 8) {
    const int h = h0 + r, d = d0 + c;
    if (h < H && d < D) WT[(size_t)h * D + d] = f2bf(tile[c][r]);
  }
}

// ---------------- kernel 6: sparse decode + per-row squared error (vectorized) ----------------
__global__ __launch_bounds__(256) void decode_loss(
    const float* __restrict__ X, const float* __restrict__ b_pre,
    const float* __restrict__ b_dec, const float* __restrict__ Wfull,
    const unsigned short* __restrict__ WTb,
    const int* __restrict__ tk_idx, const float* __restrict__ tk_val,
    const int* __restrict__ kptr,
    float* __restrict__ recon, double* __restrict__ row_ssq,
    int D, int H, int useWT)
{
  __shared__ int   sidx[K_MAX];
  __shared__ float sval[K_MAX];
  __shared__ double sd[4];
  const int tid = threadIdx.x, b = blockIdx.x;
  const int k = min(*kptr, K_MAX);
  if (tid < k) {
    sidx[tid] = tk_idx[(size_t)b * K_MAX + tid];
    sval[tid] = tk_val[(size_t)b * K_MAX + tid];
  }
  __syncthreads();
  double ssq = 0.0;
  const int D4 = D >> 2;
  for (int dc = tid; dc < D4; dc += 256) {
    const int d = dc * 4;
    float4 bd = *reinterpret_cast<const float4*>(b_dec + d);
    float4 bp = *reinterpret_cast<const float4*>(b_pre + d);
    float4 a = {bd.x + bp.x, bd.y + bp.y, bd.z + bp.z, bd.w + bp.w};
    if (useWT) {
#pragma unroll 4
      for (int j = 0; j < k; ++j) {
        const ushort4 w = *reinterpret_cast<const ushort4*>(WTb + (size_t)sidx[j] * D + d);
        const float s = sval[j];
        a.x += s * bf2f(w.x); a.y += s * bf2f(w.y);
        a.z += s * bf2f(w.z); a.w += s * bf2f(w.w);
      }
    } else {
#pragma unroll 4
      for (int j = 0; j < k; ++j) {
        const float s = sval[j];
        const int h = sidx[j];
        a.x += s * Wfull[(size_t)(d + 0) * H + h];
        a.y += s * Wfull[(size_t)(d + 1) * H + h];
        a.z += s * Wfull[(size_t)(d + 2) * H + h];
        a.w += s * Wfull[(size_t)(d + 3) * H + h];
      }
    }
    *reinterpret_cast<float4*>(recon + (size_t)b * D + d) = a;
    float4 xv = *reinterpret_cast<const float4*>(X + (size_t)b * D + d);
    const double d0 = (double)a.x - (double)xv.x;
    const double d1 = (double)a.y - (double)xv.y;
    const double d2 = (double)a.z - (double)xv.z;
    const double d3 = (double)a.w - (double)xv.w;
    ssq += d0 * d0 + d1 * d1 + d2 * d2 + d3 * d3;
  }
  for (int off = 32; off; off >>= 1) ssq += __shfl_xor(ssq, off);
  if ((tid & 63) == 0) sd[tid >> 6] = ssq;
  __syncthreads();
  if (tid == 0) row_ssq[b] = sd[0] + sd[1] + sd[2] + sd[3];
}

// ---------------- kernel 7a: per-chunk partial losses (64 blocks) ----------------
__global__ __launch_bounds__(256) void finalize_part(
    const double* __restrict__ row_ssq, const float* __restrict__ tk_val,
    const int* __restrict__ kptr, double* __restrict__ part_s, int* __restrict__ part_c,
    int Bdim, int rows_per_blk)
{
  __shared__ double sd[4];
  __shared__ int si[4];
  const int tid = threadIdx.x;
  const int k = min(*kptr, K_MAX);
  const int b0 = blockIdx.x * rows_per_blk;
  const int b1 = min(b0 + rows_per_blk, Bdim);
  double s = 0.0;
  for (int i = b0 + tid; i < b1; i += 256) s += row_ssq[i];
  int cnt = 0;
  const int total = (b1 - b0) * k;
  for (int i = tid; i < total; i += 256) {
    const int bb = b0 + i / k, j = i - (i / k) * k;
    cnt += (tk_val[(size_t)bb * K_MAX + j] > 0.f) ? 1 : 0;
  }
  for (int off = 32; off; off >>= 1) { s += __shfl_xor(s, off); cnt += __shfl_xor(cnt, off); }
  if ((tid & 63) == 0) { sd[tid >> 6] = s; si[tid >> 6] = cnt; }
  __syncthreads();
  if (tid == 0) {
    part_s[blockIdx.x] = sd[0] + sd[1] + sd[2] + sd[3];
    part_c[blockIdx.x] = si[0] + si[1] + si[2] + si[3];
  }
}

// ---------------- kernel 7b: final scalar losses ----------------
__global__ __launch_bounds__(64) void finalize_k2(
    const double* __restrict__ part_s, const int* __restrict__ part_c,
    float* __restrict__ scalars, int nparts, int Bdim, int D)
{
  const int tid = threadIdx.x;
  double s = (tid < nparts) ? part_s[tid] : 0.0;
  int cnt = (tid < nparts) ? part_c[tid] : 0;
  for (int off = 32; off; off >>= 1) { s += __shfl_xor(s, off); cnt += __shfl_xor(cnt, off); }
  if (tid == 0) {
    const double rl = s / ((double)Bdim * (double)D);
    scalars[0] = (float)rl;                     // loss
    scalars[1] = (float)rl;                     // reconstruction_loss
    scalars[2] = 0.f;                           // sparsity_loss
    scalars[3] = (float)((double)cnt / Bdim);   // l0
  }
}

extern "C" void kernel_launch(void* const* d_in, const int* in_sizes, int n_in,
                              void* d_out, int out_size, void* d_ws, size_t ws_size,
                              hipStream_t stream)
{
  const float* x     = (const float*)d_in[0];
  const float* W_enc = (const float*)d_in[1];
  const float* b_enc = (const float*)d_in[2];
  const float* W_dec = (const float*)d_in[3];
  const float* b_dec = (const float*)d_in[4];
  const float* b_pre = (const float*)d_in[5];
  const int*   kptr  = (const int*)d_in[6];

  const int D = in_sizes[4];          // 1280
  const int H = in_sizes[2];          // 16384
  const int B = in_sizes[0] / D;      // 8192

  float* recon   = (float*)d_out;
  float* hidden  = recon + (size_t)B * D;       // temporarily holds pre (f32 or keys)
  float* scalars = hidden + (size_t)B * H;

  // ---- workspace layout (single running cursor) ----
  size_t off = 0;
  int* tk_idx = (int*)((char*)d_ws + off);        off += (size_t)B * K_MAX * sizeof(int);
  float* tk_val = (float*)((char*)d_ws + off);    off += (size_t)B * K_MAX * sizeof(float);
  off = (off + 7) & ~(size_t)7;
  double* row_ssq = (double*)((char*)d_ws + off); off += (size_t)B * sizeof(double);
  double* part_s = (double*)((char*)d_ws + off);  off += 64 * sizeof(double);
  int* part_c = (int*)((char*)d_ws + off);        off += 64 * sizeof(int);
  off = (off + 7) & ~(size_t)7;

  unsigned short* Xb = (unsigned short*)((char*)d_ws + off);
  off += (size_t)B * D * sizeof(unsigned short);
  unsigned short* Wb = (unsigned short*)((char*)d_ws + off);
  off += (size_t)H * D * sizeof(unsigned short);
  const int useBF16 = (off <= ws_size) ? 1 : 0;

  unsigned short* WTb = (unsigned short*)((char*)d_ws + off);
  off += (size_t)D * H * sizeof(unsigned short);
  const int useWT = (off <= ws_size) ? 1 : 0;

  int* sure_ix = (int*)((char*)d_ws + off);       off += (size_t)B * S_MAX * sizeof(int);
  float* sure_val = (float*)((char*)d_ws + off);  off += (size_t)B * S_MAX * sizeof(float);
  int* sure_cnt = (int*)((char*)d_ws + off);      off += (size_t)B * sizeof(int);
  int* amb_ix = (int*)((char*)d_ws + off);        off += (size_t)B * A_MAX * sizeof(int);
  int* amb_cnt = (int*)((char*)d_ws + off);       off += (size_t)B * sizeof(int);
  off = (off + 7) & ~(size_t)7;
  double* amb_sv = (double*)((char*)d_ws + off);  off += (size_t)B * A_MAX * sizeof(double);
  const int useSPLIT = (useBF16 && off <= ws_size) ? 1 : 0;

  const bool fast_ok = (D % 64 == 0) && (D <= D_MAX) &&
                       (H == H_FIX) && (B % 128 == 0);

  if (useBF16 && fast_ok) {
    const size_t tx4 = (size_t)B * D / 4, tw4 = (size_t)H * D / 4;
    prep_xb<<<2048, 256, 0, stream>>>(x, b_pre, Xb, D, tx4);
    prep_wb<<<2048, 256, 0, stream>>>(W_enc, Wb, tw4);
    dim3 gg(H / 128, B / 128);
    if (useSPLIT) {
      enc_gemm_bf16<<<gg, 256, 0, stream>>>(Xb, Wb, b_enc, hidden, D, H, 0);  // f32 pre
      // delta >= 2*eps: eps (max |f32approx - f64|) <= ~0.015 -> delta 0.04
      topk_classify<<<B, 256, 0, stream>>>(hidden, sure_ix, sure_val, sure_cnt,
                                           amb_ix, amb_cnt, kptr, 0.04f);
      refine_f64<<<B, 256, 0, stream>>>(x, b_pre, W_enc, b_enc, amb_ix, amb_cnt, amb_sv, D);
      rank_scatter2<<<B, 256, 0, stream>>>(sure_ix, sure_val, sure_cnt,
                                           amb_ix, amb_sv, amb_cnt, kptr,
                                           hidden, tk_idx, tk_val);
    } else {
      enc_gemm_bf16<<<gg, 256, 0, stream>>>(Xb, Wb, b_enc, hidden, D, H, 1);  // u16 keys
      topk_select<<<B, 256, 0, stream>>>(x, b_pre, W_enc, b_enc, hidden,
                                         tk_idx, tk_val, kptr, D, 0.04f);
    }
  } else {
    dim3 gg(H / BN, B / BM);
    enc_gemm_f32<<<gg, 256, 0, stream>>>(x, W_enc, b_enc, b_pre, hidden, D, H);
    const size_t sh = CAND_MAX * sizeof(double) + (size_t)D * sizeof(float)
                    + CAND_MAX * sizeof(int) + (NBITER + 8) * sizeof(int);
    topk_refine<<<B, 256, sh, stream>>>(x, b_pre, W_enc, b_enc, hidden,
                                        tk_idx, tk_val, kptr, D, H, 1e-3f);
  }

  if (useWT)
    transpose_wdec_bf16<<<dim3((H + 31) / 32, (D + 31) / 32), 256, 0, stream>>>(W_dec, WTb, D, H);

  decode_loss<<<B, 256, 0, stream>>>(x, b_pre, b_dec, W_dec, WTb,
                                     tk_idx, tk_val, kptr, recon, row_ssq, D, H, useWT);

  const int rpb = (B + 63) / 64;
  finalize_part<<<64, 256, 0, stream>>>(row_ssq, tk_val, kptr, part_s, part_c, B, rpb);
  finalize_k2<<<1, 64, 0, stream>>>(part_s, part_c, scalars, 64, B, D);
}

// Round 9
// 1182.372 us; speedup vs baseline: 5.1881x; 1.0574x over previous
//
#include <hip/hip_runtime.h>
#include <hip/hip_bf16.h>

constexpr int K_MAX    = 128;   // max supported k (actual k=64 read from device)
constexpr int S_MAX    = 128;   // sure-member cap per row
constexpr int A_MAX    = 256;   // ambiguous cap per row
constexpr int CAND_MAX = 512;   // fused-fallback candidate cap
constexpr int BM = 128, BN = 128, BKF = 16;
constexpr int NBITER = 42;      // fallback bisection iterations
constexpr int D_MAX   = 2048;   // fast path requires D <= D_MAX
constexpr int H_FIX   = 16384;  // fast path requires H == H_FIX

typedef __attribute__((ext_vector_type(8))) short bf16x8;
typedef __attribute__((ext_vector_type(8))) unsigned short u16x8;
typedef __attribute__((ext_vector_type(4))) float f32x4;

__device__ inline unsigned short f2bf(float f) {   // round-to-nearest-even
  unsigned u = __float_as_uint(f);
  return (unsigned short)((u + 0x7fff + ((u >> 16) & 1)) >> 16);
}
// monotone 16-bit key: key order == value order (handles negatives)
__device__ inline unsigned short key_of(float f) {
  unsigned short b = f2bf(f);
  return b ^ ((b & 0x8000) ? 0xFFFF : 0x8000);
}
__device__ inline float val_of_key(unsigned short kk) {
  unsigned short b = (kk & 0x8000) ? (unsigned short)(kk ^ 0x8000)
                                   : (unsigned short)(kk ^ 0xFFFF);
  return __uint_as_float(((unsigned)b) << 16);
}
__device__ inline float bf2f(unsigned short b) {
  return __uint_as_float(((unsigned)b) << 16);
}

// conflict-free superrow swizzle (R8-verified: bank conflicts 1.26e8 -> 0)
__device__ inline int lds_slot(int r, int c) {
  return ((r >> 1) << 4) | ((r & 1) << 3) | (c ^ ((r >> 1) & 7));
}

// ---------------- prep: Xb = bf16(x - b_pre), Wb = bf16(W_enc) ----------------
__global__ __launch_bounds__(256) void prep_xb(
    const float* __restrict__ x, const float* __restrict__ b_pre,
    unsigned short* __restrict__ Xb, int D, size_t total4)
{
  for (size_t i = blockIdx.x * 256 + threadIdx.x; i < total4; i += (size_t)gridDim.x * 256) {
    const size_t e = i * 4;
    const int d = (int)(e % D);
    float4 xv = *reinterpret_cast<const float4*>(x + e);
    float4 bp = *reinterpret_cast<const float4*>(b_pre + d);
    ushort4 o;
    o.x = f2bf(xv.x - bp.x); o.y = f2bf(xv.y - bp.y);
    o.z = f2bf(xv.z - bp.z); o.w = f2bf(xv.w - bp.w);
    *reinterpret_cast<ushort4*>(Xb + e) = o;
  }
}

__global__ __launch_bounds__(256) void prep_wb(
    const float* __restrict__ W, unsigned short* __restrict__ Wb, size_t total4)
{
  for (size_t i = blockIdx.x * 256 + threadIdx.x; i < total4; i += (size_t)gridDim.x * 256) {
    const size_t e = i * 4;
    float4 wv = *reinterpret_cast<const float4*>(W + e);
    ushort4 o;
    o.x = f2bf(wv.x); o.y = f2bf(wv.y); o.z = f2bf(wv.z); o.w = f2bf(wv.w);
    *reinterpret_cast<ushort4*>(Wb + e) = o;
  }
}

// ---------------- kernel 1: encoder GEMM, bf16 MFMA, writes monotone u16 keys ----------------
// BK=64, double-buffered LDS, stage-first, one barrier per K-tile, superrow
// swizzle (conflict-free), XCD-aware block swizzle (L2 locality).
__global__ __launch_bounds__(256) void enc_gemm_bf16(
    const unsigned short* __restrict__ Xb, const unsigned short* __restrict__ Wb,
    const float* __restrict__ b_enc, float* __restrict__ pre, int D, int H)
{
  __shared__ unsigned short As[2][128 * 64];
  __shared__ unsigned short Bs[2][128 * 64];
  const int tid  = threadIdx.x;
  const int wave = tid >> 6, lane = tid & 63;

  // XCD-aware swizzle: give each XCD a contiguous tile range (nwg % 8 == 0)
  int lin = blockIdx.y * gridDim.x + blockIdx.x;
  const int nwg = gridDim.x * gridDim.y;
  if ((nwg & 7) == 0) {
    const int cpx = nwg >> 3;
    lin = (lin & 7) * cpx + (lin >> 3);
  }
  const int m0 = (lin / gridDim.x) * 128, n0 = (lin % gridDim.x) * 128;

  const int wm = (wave >> 1) * 64, wn = (wave & 1) * 64;
  const int l16 = lane & 15, lhi = lane >> 4;

  f32x4 acc[4][4];
#pragma unroll
  for (int i = 0; i < 4; ++i)
#pragma unroll
    for (int j = 0; j < 4; ++j) acc[i][j] = (f32x4){0.f, 0.f, 0.f, 0.f};

  const int NT = D / 64;

  // prologue: stage tile 0 into buffer 0 (LDS dest linear, global src inverse-permuted)
#pragma unroll
  for (int i = 0; i < 4; ++i) {
    const int base = wave * 64 + i * 256;
    const int idx  = base + lane;
    const int sr = idx >> 4, u = idx & 15;
    const int row = (sr << 1) | (u >> 3);
    const int ch  = (u & 7) ^ (sr & 7);
    __builtin_amdgcn_global_load_lds(
        (const __attribute__((address_space(1))) unsigned int*)(Xb + (size_t)(m0 + row) * D + ch * 8),
        (__attribute__((address_space(3))) unsigned int*)(As[0] + (size_t)base * 8), 16, 0, 0);
    __builtin_amdgcn_global_load_lds(
        (const __attribute__((address_space(1))) unsigned int*)(Wb + (size_t)(n0 + row) * D + ch * 8),
        (__attribute__((address_space(3))) unsigned int*)(Bs[0] + (size_t)base * 8), 16, 0, 0);
  }
  __syncthreads();

  int cur = 0;
  for (int t = 0; t < NT; ++t) {
    if (t + 1 < NT) {
      const int kb = (t + 1) * 64;
      const int nxt = cur ^ 1;
#pragma unroll
      for (int i = 0; i < 4; ++i) {
        const int base = wave * 64 + i * 256;
        const int idx  = base + lane;
        const int sr = idx >> 4, u = idx & 15;
        const int row = (sr << 1) | (u >> 3);
        const int ch  = (u & 7) ^ (sr & 7);
        __builtin_amdgcn_global_load_lds(
            (const __attribute__((address_space(1))) unsigned int*)(Xb + (size_t)(m0 + row) * D + kb + ch * 8),
            (__attribute__((address_space(3))) unsigned int*)(As[nxt] + (size_t)base * 8), 16, 0, 0);
        __builtin_amdgcn_global_load_lds(
            (const __attribute__((address_space(1))) unsigned int*)(Wb + (size_t)(n0 + row) * D + kb + ch * 8),
            (__attribute__((address_space(3))) unsigned int*)(Bs[nxt] + (size_t)base * 8), 16, 0, 0);
      }
    }
#pragma unroll
    for (int kk = 0; kk < 2; ++kk) {
      bf16x8 af[4], bfr[4];
#pragma unroll
      for (int mi = 0; mi < 4; ++mi)
        af[mi] = *reinterpret_cast<const bf16x8*>(
            As[cur] + (size_t)lds_slot(wm + mi * 16 + l16, kk * 4 + lhi) * 8);
#pragma unroll
      for (int ni = 0; ni < 4; ++ni)
        bfr[ni] = *reinterpret_cast<const bf16x8*>(
            Bs[cur] + (size_t)lds_slot(wn + ni * 16 + l16, kk * 4 + lhi) * 8);
#pragma unroll
      for (int mi = 0; mi < 4; ++mi)
#pragma unroll
        for (int ni = 0; ni < 4; ++ni)
          acc[mi][ni] = __builtin_amdgcn_mfma_f32_16x16x32_bf16(af[mi], bfr[ni], acc[mi][ni], 0, 0, 0);
    }
    __syncthreads();
    cur ^= 1;
  }

  // epilogue: write monotone u16 keys (half the bytes of f32 pre)
#pragma unroll
  for (int ni = 0; ni < 4; ++ni) {
    const int n = n0 + wn + ni * 16 + l16;
    const float be = b_enc[n];
#pragma unroll
    for (int mi = 0; mi < 4; ++mi) {
      const int mbase = m0 + wm + mi * 16 + lhi * 4;
#pragma unroll
      for (int r = 0; r < 4; ++r) {
        unsigned short* prow = (unsigned short*)(pre + (size_t)(mbase + r) * H);
        prow[n] = key_of(acc[mi][ni][r] + be);
      }
    }
  }
}

// ---------------- kernel 2: single-pass key classify (registers only) ----------------
// 64 keys/thread in 16 VGPRs; hist -> exact k-th key -> sure/amb thresholds in
// key space -> classify from registers. ONE 256MB read, no re-pass.
__global__ __launch_bounds__(256) void topk_classify_keys(
    const float* __restrict__ hidden,
    int* __restrict__ sure_ix, float* __restrict__ sure_val, int* __restrict__ sure_cnt,
    int* __restrict__ amb_ix, int* __restrict__ amb_cnt,
    const int* __restrict__ kptr, float delta)
{
  constexpr int H = H_FIX, NC = H_FIX / (256 * 8);
  __shared__ int hist[4096];
  __shared__ int chunk[256];
  __shared__ int misc[8];   // 0:b1 1:run 2:ks 3:ka 4:sure_n 5:amb_n

  const int tid = threadIdx.x, b = blockIdx.x;
  const int k = min(*kptr, K_MAX);
  const unsigned short* krow = (const unsigned short*)(hidden + (size_t)b * H);

  if (tid < 8) misc[tid] = 0;
  for (int i = tid; i < 4096; i += 256) hist[i] = 0;

  u16x8 kv[NC];
#pragma unroll
  for (int i = 0; i < NC; ++i)
    kv[i] = *reinterpret_cast<const u16x8*>(krow + ((size_t)i * 256 + tid) * 8);
  __syncthreads();

#pragma unroll
  for (int i = 0; i < NC; ++i)
#pragma unroll
    for (int j = 0; j < 8; ++j)
      atomicAdd(&hist[((unsigned)(unsigned short)kv[i][j]) >> 4], 1);
  __syncthreads();

  int csum = 0;
#pragma unroll
  for (int j = 0; j < 16; ++j) csum += hist[tid * 16 + j];
  chunk[tid] = csum;
  __syncthreads();
  int gt = 0;
  for (int j = tid + 1; j < 256; ++j) gt += chunk[j];
  {
    int run = gt;
#pragma unroll
    for (int j = 15; j >= 0; --j) {
      const int hc = hist[tid * 16 + j];
      if (run < k && k <= run + hc) { misc[0] = tid * 16 + j; misc[1] = run; }
      run += hc;
    }
  }
  __syncthreads();
  const int b1 = misc[0];
  if (tid < 16) chunk[tid] = 0;
  __syncthreads();
  // 16-bin sub-histogram of bin b1 (from registers)
#pragma unroll
  for (int i = 0; i < NC; ++i)
#pragma unroll
    for (int j = 0; j < 8; ++j) {
      const unsigned kk = (unsigned)(unsigned short)kv[i][j];
      if ((int)(kk >> 4) == b1) atomicAdd(&chunk[kk & 15], 1);
    }
  __syncthreads();
  if (tid == 0) {
    int run = misc[1];
    int K16 = b1 << 4;
    for (int j = 15; j >= 0; --j) {
      const int c = chunk[j];
      if (run < k && k <= run + c) K16 = (b1 << 4) | j;
      run += c;
    }
    const float v_lo = val_of_key((unsigned short)K16);
    const float v_hi = val_of_key((unsigned short)min(K16 + 1, 65535));
    const float ulp = v_hi - v_lo;
    const float vs = v_hi + delta;          // sure: value >  vs
    const float va = v_lo - ulp - delta;    // amb : value >= va
    int ks = key_of(vs); if (val_of_key((unsigned short)ks) > vs) --ks;   // floor key
    int ka = key_of(va); if (val_of_key((unsigned short)ka) < va) ++ka;   // ceil key
    misc[2] = ks; misc[3] = ka;
  }
  __syncthreads();
  const unsigned ks = (unsigned)misc[2], ka = (unsigned)misc[3];

#pragma unroll
  for (int i = 0; i < NC; ++i)
#pragma unroll
    for (int j = 0; j < 8; ++j) {
      const unsigned kk = (unsigned)(unsigned short)kv[i][j];
      if (kk > ks) {
        const int p = atomicAdd(&misc[4], 1);
        if (p < S_MAX) {
          const int h = (i * 256 + tid) * 8 + j;
          sure_ix[(size_t)b * S_MAX + p] = h;
          sure_val[(size_t)b * S_MAX + p] = val_of_key((unsigned short)kk);
        }
      } else if (kk >= ka) {
        const int p = atomicAdd(&misc[5], 1);
        if (p < A_MAX) amb_ix[(size_t)b * A_MAX + p] = (i * 256 + tid) * 8 + j;
      }
    }
  __syncthreads();
  if (tid == 0) {
    sure_cnt[b] = min(misc[4], S_MAX);
    amb_cnt[b]  = min(misc[5], A_MAX);
  }
}

// ---------------- kernel 3: exact f64 dot products for ambiguous only ----------------
__global__ __launch_bounds__(256) void refine_f64(
    const float* __restrict__ X, const float* __restrict__ b_pre,
    const float* __restrict__ W, const float* __restrict__ b_enc,
    const int* __restrict__ amb_ix, const int* __restrict__ amb_cnt,
    double* __restrict__ amb_sv, int D)
{
  __shared__ float xr[D_MAX];
  const int tid = threadIdx.x, b = blockIdx.x;
  const int C = min(amb_cnt[b], A_MAX);
  for (int d = tid; d < D; d += 256) xr[d] = X[(size_t)b * D + d] - b_pre[d];
  __syncthreads();
  const int wid = tid >> 6, lane = tid & 63;
  for (int c = wid; c < C; c += 4) {
    const int h = amb_ix[(size_t)b * A_MAX + c];
    const float* wr = W + (size_t)h * D;
    double s0 = 0.0, s1 = 0.0;
    int i = lane;
    for (; i + 64 < D; i += 128) {
      s0 += (double)xr[i] * (double)wr[i];
      s1 += (double)xr[i + 64] * (double)wr[i + 64];
    }
    if (i < D) s0 += (double)xr[i] * (double)wr[i];
    double s = s0 + s1;
    for (int off = 32; off; off >>= 1) s += __shfl_xor(s, off);
    if (lane == 0) amb_sv[(size_t)b * A_MAX + c] = s + (double)b_enc[h];
  }
}

// ---------------- kernel 4: zero row, write sure, rank ambiguous, scatter ----------------
__global__ __launch_bounds__(256) void rank_scatter2(
    const int* __restrict__ sure_ix, const float* __restrict__ sure_val,
    const int* __restrict__ sure_cnt,
    const int* __restrict__ amb_ix, const double* __restrict__ amb_sv,
    const int* __restrict__ amb_cnt, const int* __restrict__ kptr,
    float* __restrict__ hidden, int* __restrict__ tk_idx, float* __restrict__ tk_val)
{
  constexpr int H = H_FIX;
  __shared__ double asv[A_MAX];
  __shared__ int    aix[A_MAX];
  const int tid = threadIdx.x, b = blockIdx.x;
  const int k = min(*kptr, K_MAX);
  const int S = min(min(sure_cnt[b], S_MAX), k);
  const int A = min(amb_cnt[b], A_MAX);
  float* hrow = hidden + (size_t)b * H;

  for (int c = tid; c < A; c += 256) {
    asv[c] = amb_sv[(size_t)b * A_MAX + c];
    aix[c] = amb_ix[(size_t)b * A_MAX + c];
  }
  const float4 z4 = {0.f, 0.f, 0.f, 0.f};
  for (int i = tid; i < (H >> 2); i += 256)
    reinterpret_cast<float4*>(hrow)[i] = z4;
  __syncthreads();

  // sure members: value = bf16-granular GEMM approx (err << 1.28 threshold)
  for (int i = tid; i < S; i += 256) {
    const int h = sure_ix[(size_t)b * S_MAX + i];
    const float v = sure_val[(size_t)b * S_MAX + i];
    const float rv = (v > 0.f) ? v : 0.f;
    hrow[h] = rv;
    tk_idx[(size_t)b * K_MAX + i] = h;
    tk_val[(size_t)b * K_MAX + i] = rv;
  }
  // ambiguous: top (k-S) by exact f64 value, index tie-break
  const int m = k - S;
  for (int c = tid; c < A; c += 256) {
    const double v = asv[c];
    const int h = aix[c];
    int r = 0;
    for (int j = 0; j < A; ++j) {
      const double vj = asv[j];
      r += ((vj > v) || (vj == v && aix[j] < h)) ? 1 : 0;
    }
    if (r < m) {
      const float rv = (v > 0.0) ? (float)v : 0.f;
      hrow[h] = rv;
      tk_idx[(size_t)b * K_MAX + S + r] = h;
      tk_val[(size_t)b * K_MAX + S + r] = rv;
    }
  }
}

// ---------------- fused fallback: single-pass select on u16 keys ----------------
__global__ __launch_bounds__(256, 2) void topk_select(
    const float* __restrict__ X, const float* __restrict__ b_pre,
    const float* __restrict__ W, const float* __restrict__ b_enc,
    float* __restrict__ hidden, int* __restrict__ tk_idx, float* __restrict__ tk_val,
    const int* __restrict__ kptr, int D, float margin)
{
  constexpr int H = H_FIX, NC = H_FIX / (256 * 8);
  __shared__ double cand_sv[CAND_MAX];
  __shared__ float  xr[D_MAX];
  __shared__ int    cand_ix[CAND_MAX];
  __shared__ int    hist[4096];
  __shared__ int    chunk[256];
  __shared__ int    misc[8];

  const int tid = threadIdx.x, b = blockIdx.x;
  const int k = min(*kptr, K_MAX);
  float* hrow = hidden + (size_t)b * H;
  const unsigned short* krow = (const unsigned short*)hrow;

  if (tid < 8) misc[tid] = 0;
  for (int i = tid; i < 4096; i += 256) hist[i] = 0;
  for (int d = tid; d < D; d += 256) xr[d] = X[(size_t)b * D + d] - b_pre[d];

  u16x8 kv[NC];
#pragma unroll
  for (int i = 0; i < NC; ++i)
    kv[i] = *reinterpret_cast<const u16x8*>(krow + ((size_t)i * 256 + tid) * 8);
  __syncthreads();

#pragma unroll
  for (int i = 0; i < NC; ++i)
#pragma unroll
    for (int j = 0; j < 8; ++j)
      atomicAdd(&hist[((unsigned)(unsigned short)kv[i][j]) >> 4], 1);
  __syncthreads();

  int csum = 0;
#pragma unroll
  for (int j = 0; j < 16; ++j) csum += hist[tid * 16 + j];
  chunk[tid] = csum;
  __syncthreads();
  int gt = 0;
  for (int j = tid + 1; j < 256; ++j) gt += chunk[j];
  {
    int run = gt;
#pragma unroll
    for (int j = 15; j >= 0; --j) {
      const int hc = hist[tid * 16 + j];
      if (run < k && k <= run + hc) { misc[0] = tid * 16 + j; misc[1] = run; }
      run += hc;
    }
  }
  __syncthreads();
  const int b1 = misc[0];
  if (tid < 16) chunk[tid] = 0;
  __syncthreads();
#pragma unroll
  for (int i = 0; i < NC; ++i)
#pragma unroll
    for (int j = 0; j < 8; ++j) {
      const unsigned kk = (unsigned)(unsigned short)kv[i][j];
      if ((int)(kk >> 4) == b1) atomicAdd(&chunk[kk & 15], 1);
    }
  __syncthreads();
  if (tid == 0) {
    int run = misc[1];
    int K16 = b1 << 4;
    for (int j = 15; j >= 0; --j) {
      const int c = chunk[j];
      if (run < k && k <= run + c) K16 = (b1 << 4) | j;
      run += c;
    }
    const float vthr = val_of_key((unsigned short)K16) - margin;
    int kt = (int)key_of(vthr);
    if (kt > K16) kt = K16;
    misc[2] = kt;
  }
  __syncthreads();
  const unsigned kthr = (unsigned)misc[2];

#pragma unroll
  for (int i = 0; i < NC; ++i)
#pragma unroll
    for (int j = 0; j < 8; ++j) {
      if ((unsigned)(unsigned short)kv[i][j] >= kthr) {
        const int pos = atomicAdd(&misc[3], 1);
        if (pos < CAND_MAX) cand_ix[pos] = (i * 256 + tid) * 8 + j;
      }
    }
  __syncthreads();
  const int C = min(misc[3], CAND_MAX);

  const float4 z4 = {0.f, 0.f, 0.f, 0.f};
  for (int i = tid; i < (H >> 2); i += 256)
    reinterpret_cast<float4*>(hrow)[i] = z4;

  const int wid = tid >> 6, lane = tid & 63;
  for (int c = wid; c < C; c += 4) {
    const int h = cand_ix[c];
    const float* wr = W + (size_t)h * D;
    double s = 0.0;
    for (int i = lane; i < D; i += 64) s += (double)xr[i] * (double)wr[i];
    for (int off = 32; off; off >>= 1) s += __shfl_xor(s, off);
    if (lane == 0) cand_sv[c] = s + (double)b_enc[h];
  }
  __syncthreads();

  for (int c = tid; c < C; c += 256) {
    const double v = cand_sv[c];
    const int h = cand_ix[c];
    int r = 0;
    for (int j = 0; j < C; ++j) {
      const double vj = cand_sv[j];
      r += ((vj > v) || (vj == v && cand_ix[j] < h)) ? 1 : 0;
    }
    if (r < k) {
      const float rv = (v > 0.0) ? (float)v : 0.f;
      hrow[h] = rv;
      tk_idx[(size_t)b * K_MAX + r] = h;
      tk_val[(size_t)b * K_MAX + r] = rv;
    }
  }
}

// ---------------- fallback: fp32 GEMM ----------------
__global__ __launch_bounds__(256) void enc_gemm_f32(
    const float* __restrict__ X, const float* __restrict__ W,
    const float* __restrict__ b_enc, const float* __restrict__ b_pre,
    float* __restrict__ pre, int D, int H)
{
  __shared__ float As[BKF][BM + 4];
  __shared__ float Bs[BKF][BN + 4];
  const int tid = threadIdx.x;
  const int m0 = blockIdx.y * BM;
  const int n0 = blockIdx.x * BN;
  const int tx = tid & 15, ty = tid >> 4;
  float acc[8][8];
#pragma unroll
  for (int i = 0; i < 8; ++i)
#pragma unroll
    for (int j = 0; j < 8; ++j) acc[i][j] = 0.f;

  for (int kb = 0; kb < D; kb += BKF) {
#pragma unroll
    for (int t = 0; t < 2; ++t) {
      const int f4i = tid + t * 256;
      const int row = f4i >> 2;
      const int kq  = (f4i & 3) << 2;
      float4 xv = *reinterpret_cast<const float4*>(X + (size_t)(m0 + row) * D + kb + kq);
      float4 bp = *reinterpret_cast<const float4*>(b_pre + kb + kq);
      As[kq + 0][row] = xv.x - bp.x; As[kq + 1][row] = xv.y - bp.y;
      As[kq + 2][row] = xv.z - bp.z; As[kq + 3][row] = xv.w - bp.w;
      float4 wv = *reinterpret_cast<const float4*>(W + (size_t)(n0 + row) * D + kb + kq);
      Bs[kq + 0][row] = wv.x; Bs[kq + 1][row] = wv.y;
      Bs[kq + 2][row] = wv.z; Bs[kq + 3][row] = wv.w;
    }
    __syncthreads();
#pragma unroll
    for (int kk = 0; kk < BKF; ++kk) {
      float4 a0 = *reinterpret_cast<const float4*>(&As[kk][ty * 8]);
      float4 a1 = *reinterpret_cast<const float4*>(&As[kk][ty * 8 + 4]);
      float4 b0 = *reinterpret_cast<const float4*>(&Bs[kk][tx * 8]);
      float4 b1 = *reinterpret_cast<const float4*>(&Bs[kk][tx * 8 + 4]);
      float av[8] = {a0.x, a0.y, a0.z, a0.w, a1.x, a1.y, a1.z, a1.w};
      float bv[8] = {b0.x, b0.y, b0.z, b0.w, b1.x, b1.y, b1.z, b1.w};
#pragma unroll
      for (int i = 0; i < 8; ++i)
#pragma unroll
        for (int j = 0; j < 8; ++j) acc[i][j] += av[i] * bv[j];
    }
    __syncthreads();
  }
#pragma unroll
  for (int i = 0; i < 8; ++i) {
    const size_t m = (size_t)(m0 + ty * 8 + i);
#pragma unroll
    for (int j = 0; j < 8; j += 4) {
      const int n = n0 + tx * 8 + j;
      float4 o;
      o.x = acc[i][j + 0] + b_enc[n + 0];
      o.y = acc[i][j + 1] + b_enc[n + 1];
      o.z = acc[i][j + 2] + b_enc[n + 2];
      o.w = acc[i][j + 3] + b_enc[n + 3];
      *reinterpret_cast<float4*>(pre + m * H + n) = o;
    }
  }
}

// ---------------- fallback: bisection top-k (reads f32 pre) ----------------
__global__ __launch_bounds__(256) void topk_refine(
    const float* __restrict__ X, const float* __restrict__ b_pre,
    const float* __restrict__ W, const float* __restrict__ b_enc,
    float* __restrict__ hidden, int* __restrict__ tk_idx, float* __restrict__ tk_val,
    const int* __restrict__ kptr, int D, int H, float margin)
{
  extern __shared__ char smem_raw[];
  double* cand_val = reinterpret_cast<double*>(smem_raw);
  float*  xr       = reinterpret_cast<float*>(cand_val + CAND_MAX);
  int*    cand_idx = reinterpret_cast<int*>(xr + D);
  int*    misc     = cand_idx + CAND_MAX;

  const int tid = threadIdx.x;
  const int b = blockIdx.x;
  const int k = min(*kptr, K_MAX);
  float* hrow = hidden + (size_t)b * H;

  for (int i = tid; i < NBITER + 2; i += 256) misc[i] = 0;
  for (int d = tid; d < D; d += 256) xr[d] = X[(size_t)b * D + d] - b_pre[d];

  float f[64];
#pragma unroll
  for (int i = 0; i < 16; ++i) {
    const int base = i * 1024 + tid * 4;
    float4 v = {-3e38f, -3e38f, -3e38f, -3e38f};
    if (base + 3 < H) v = *reinterpret_cast<const float4*>(hrow + base);
    f[4 * i + 0] = v.x; f[4 * i + 1] = v.y; f[4 * i + 2] = v.z; f[4 * i + 3] = v.w;
  }
  __syncthreads();

  float lo = -1e4f, hi = 1e4f;
  for (int it = 0; it < NBITER; ++it) {
    const float mid = 0.5f * (lo + hi);
    int cnt = 0;
#pragma unroll
    for (int j = 0; j < 64; ++j) cnt += (f[j] >= mid) ? 1 : 0;
    for (int off = 32; off; off >>= 1) cnt += __shfl_xor(cnt, off);
    if ((tid & 63) == 0) atomicAdd(&misc[it], cnt);
    __syncthreads();
    if (misc[it] >= k) lo = mid; else hi = mid;
  }

  const float thresh = lo - margin;
#pragma unroll
  for (int j = 0; j < 64; ++j) {
    if (f[j] >= thresh) {
      const int h = (j >> 2) * 1024 + tid * 4 + (j & 3);
      if (h < H) {
        int pos = atomicAdd(&misc[NBITER], 1);
        if (pos < CAND_MAX) cand_idx[pos] = h;
      }
    }
  }
  __syncthreads();
  const int C = min(misc[NBITER], CAND_MAX);

  const int wid = tid >> 6, lane = tid & 63;
  for (int c = wid; c < C; c += 4) {
    const int h = cand_idx[c];
    const float* wr = W + (size_t)h * D;
    double s = 0.0;
    for (int i = lane; i < D; i += 64) s += (double)xr[i] * (double)wr[i];
    for (int off = 32; off; off >>= 1) s += __shfl_xor(s, off);
    if (lane == 0) cand_val[c] = s + (double)b_enc[h];
  }
  __syncthreads();

  const float4 z4 = {0.f, 0.f, 0.f, 0.f};
  for (int i = tid; i < (H >> 2); i += 256)
    reinterpret_cast<float4*>(hrow)[i] = z4;
  __syncthreads();

  for (int c = tid; c < C; c += 256) {
    const double v = cand_val[c];
    const int h = cand_idx[c];
    int r = 0;
    for (int j = 0; j < C; ++j) {
      const double vj = cand_val[j];
      r += ((vj > v) || (vj == v && cand_idx[j] < h)) ? 1 : 0;
    }
    if (r < k) {
      const float rv = (v > 0.0) ? (float)v : 0.f;
      hrow[h] = rv;
      tk_idx[(size_t)b * K_MAX + r] = h;
      tk_val[(size_t)b * K_MAX + r] = rv;
    }
  }
}

// ---------------- kernel 5: W_dec [D,H] -> bf16 W_decT [H,D] ----------------
__global__ __launch_bounds__(256) void transpose_wdec_bf16(
    const float* __restrict__ Wsrc, unsigned short* __restrict__ WT, int D, int H)
{
  __shared__ float tile[32][33];
  const int c  = threadIdx.x & 31;
  const int r0 = threadIdx.x >> 5;
  const int h0 = blockIdx.x * 32;
  const int d0 = blockIdx.y * 32;
#pragma unroll
  for (int r = r0; r < 32; r += 8) {
    const int d = d0 + r, h = h0 + c;
    if (d < D && h < H) tile[r][c] = Wsrc[(size_t)d * H + h];
  }
  __syncthreads();
#pragma unroll
  for (int r = r0; r < 32; r += 8) {
    const int h = h0 + r, d = d0 + c;
    if (h < H && d < D) WT[(size_t)h * D + d] = f2bf(tile[c][r]);
  }
}

// ---------------- kernel 6: sparse decode + per-row squared error (vectorized) ----------------
__global__ __launch_bounds__(256) void decode_loss(
    const float* __restrict__ X, const float* __restrict__ b_pre,
    const float* __restrict__ b_dec, const float* __restrict__ Wfull,
    const unsigned short* __restrict__ WTb,
    const int* __restrict__ tk_idx, const float* __restrict__ tk_val,
    const int* __restrict__ kptr,
    float* __restrict__ recon, double* __restrict__ row_ssq,
    int D, int H, int useWT)
{
  __shared__ int   sidx[K_MAX];
  __shared__ float sval[K_MAX];
  __shared__ double sd[4];
  const int tid = threadIdx.x, b = blockIdx.x;
  const int k = min(*kptr, K_MAX);
  if (tid < k) {
    sidx[tid] = tk_idx[(size_t)b * K_MAX + tid];
    sval[tid] = tk_val[(size_t)b * K_MAX + tid];
  }
  __syncthreads();
  double ssq = 0.0;
  const int D4 = D >> 2;
  for (int dc = tid; dc < D4; dc += 256) {
    const int d = dc * 4;
    float4 bd = *reinterpret_cast<const float4*>(b_dec + d);
    float4 bp = *reinterpret_cast<const float4*>(b_pre + d);
    float4 a = {bd.x + bp.x, bd.y + bp.y, bd.z + bp.z, bd.w + bp.w};
    if (useWT) {
#pragma unroll 4
      for (int j = 0; j < k; ++j) {
        const ushort4 w = *reinterpret_cast<const ushort4*>(WTb + (size_t)sidx[j] * D + d);
        const float s = sval[j];
        a.x += s * bf2f(w.x); a.y += s * bf2f(w.y);
        a.z += s * bf2f(w.z); a.w += s * bf2f(w.w);
      }
    } else {
#pragma unroll 4
      for (int j = 0; j < k; ++j) {
        const float s = sval[j];
        const int h = sidx[j];
        a.x += s * Wfull[(size_t)(d + 0) * H + h];
        a.y += s * Wfull[(size_t)(d + 1) * H + h];
        a.z += s * Wfull[(size_t)(d + 2) * H + h];
        a.w += s * Wfull[(size_t)(d + 3) * H + h];
      }
    }
    *reinterpret_cast<float4*>(recon + (size_t)b * D + d) = a;
    float4 xv = *reinterpret_cast<const float4*>(X + (size_t)b * D + d);
    const double d0 = (double)a.x - (double)xv.x;
    const double d1 = (double)a.y - (double)xv.y;
    const double d2 = (double)a.z - (double)xv.z;
    const double d3 = (double)a.w - (double)xv.w;
    ssq += d0 * d0 + d1 * d1 + d2 * d2 + d3 * d3;
  }
  for (int off = 32; off; off >>= 1) ssq += __shfl_xor(ssq, off);
  if ((tid & 63) == 0) sd[tid >> 6] = ssq;
  __syncthreads();
  if (tid == 0) row_ssq[b] = sd[0] + sd[1] + sd[2] + sd[3];
}

// ---------------- kernel 7a: per-chunk partial losses (64 blocks) ----------------
__global__ __launch_bounds__(256) void finalize_part(
    const double* __restrict__ row_ssq, const float* __restrict__ tk_val,
    const int* __restrict__ kptr, double* __restrict__ part_s, int* __restrict__ part_c,
    int Bdim, int rows_per_blk)
{
  __shared__ double sd[4];
  __shared__ int si[4];
  const int tid = threadIdx.x;
  const int k = min(*kptr, K_MAX);
  const int b0 = blockIdx.x * rows_per_blk;
  const int b1 = min(b0 + rows_per_blk, Bdim);
  double s = 0.0;
  for (int i = b0 + tid; i < b1; i += 256) s += row_ssq[i];
  int cnt = 0;
  const int total = (b1 - b0) * k;
  for (int i = tid; i < total; i += 256) {
    const int bb = b0 + i / k, j = i - (i / k) * k;
    cnt += (tk_val[(size_t)bb * K_MAX + j] > 0.f) ? 1 : 0;
  }
  for (int off = 32; off; off >>= 1) { s += __shfl_xor(s, off); cnt += __shfl_xor(cnt, off); }
  if ((tid & 63) == 0) { sd[tid >> 6] = s; si[tid >> 6] = cnt; }
  __syncthreads();
  if (tid == 0) {
    part_s[blockIdx.x] = sd[0] + sd[1] + sd[2] + sd[3];
    part_c[blockIdx.x] = si[0] + si[1] + si[2] + si[3];
  }
}

// ---------------- kernel 7b: final scalar losses ----------------
__global__ __launch_bounds__(64) void finalize_k2(
    const double* __restrict__ part_s, const int* __restrict__ part_c,
    float* __restrict__ scalars, int nparts, int Bdim, int D)
{
  const int tid = threadIdx.x;
  double s = (tid < nparts) ? part_s[tid] : 0.0;
  int cnt = (tid < nparts) ? part_c[tid] : 0;
  for (int off = 32; off; off >>= 1) { s += __shfl_xor(s, off); cnt += __shfl_xor(cnt, off); }
  if (tid == 0) {
    const double rl = s / ((double)Bdim * (double)D);
    scalars[0] = (float)rl;                     // loss
    scalars[1] = (float)rl;                     // reconstruction_loss
    scalars[2] = 0.f;                           // sparsity_loss
    scalars[3] = (float)((double)cnt / Bdim);   // l0
  }
}

extern "C" void kernel_launch(void* const* d_in, const int* in_sizes, int n_in,
                              void* d_out, int out_size, void* d_ws, size_t ws_size,
                              hipStream_t stream)
{
  const float* x     = (const float*)d_in[0];
  const float* W_enc = (const float*)d_in[1];
  const float* b_enc = (const float*)d_in[2];
  const float* W_dec = (const float*)d_in[3];
  const float* b_dec = (const float*)d_in[4];
  const float* b_pre = (const float*)d_in[5];
  const int*   kptr  = (const int*)d_in[6];

  const int D = in_sizes[4];          // 1280
  const int H = in_sizes[2];          // 16384
  const int B = in_sizes[0] / D;      // 8192

  float* recon   = (float*)d_out;
  float* hidden  = recon + (size_t)B * D;       // temporarily holds keys / f32 pre
  float* scalars = hidden + (size_t)B * H;

  // ---- workspace layout (single running cursor) ----
  size_t off = 0;
  int* tk_idx = (int*)((char*)d_ws + off);        off += (size_t)B * K_MAX * sizeof(int);
  float* tk_val = (float*)((char*)d_ws + off);    off += (size_t)B * K_MAX * sizeof(float);
  off = (off + 7) & ~(size_t)7;
  double* row_ssq = (double*)((char*)d_ws + off); off += (size_t)B * sizeof(double);
  double* part_s = (double*)((char*)d_ws + off);  off += 64 * sizeof(double);
  int* part_c = (int*)((char*)d_ws + off);        off += 64 * sizeof(int);
  off = (off + 7) & ~(size_t)7;

  unsigned short* Xb = (unsigned short*)((char*)d_ws + off);
  off += (size_t)B * D * sizeof(unsigned short);
  unsigned short* Wb = (unsigned short*)((char*)d_ws + off);
  off += (size_t)H * D * sizeof(unsigned short);
  const int useBF16 = (off <= ws_size) ? 1 : 0;

  unsigned short* WTb = (unsigned short*)((char*)d_ws + off);
  off += (size_t)D * H * sizeof(unsigned short);
  const int useWT = (off <= ws_size) ? 1 : 0;

  int* sure_ix = (int*)((char*)d_ws + off);       off += (size_t)B * S_MAX * sizeof(int);
  float* sure_val = (float*)((char*)d_ws + off);  off += (size_t)B * S_MAX * sizeof(float);
  int* sure_cnt = (int*)((char*)d_ws + off);      off += (size_t)B * sizeof(int);
  int* amb_ix = (int*)((char*)d_ws + off);        off += (size_t)B * A_MAX * sizeof(int);
  int* amb_cnt = (int*)((char*)d_ws + off);       off += (size_t)B * sizeof(int);
  off = (off + 7) & ~(size_t)7;
  double* amb_sv = (double*)((char*)d_ws + off);  off += (size_t)B * A_MAX * sizeof(double);
  const int useSPLIT = (useBF16 && off <= ws_size) ? 1 : 0;

  const bool fast_ok = (D % 64 == 0) && (D <= D_MAX) &&
                       (H == H_FIX) && (B % 128 == 0);

  if (useBF16 && fast_ok) {
    const size_t tx4 = (size_t)B * D / 4, tw4 = (size_t)H * D / 4;
    prep_xb<<<2048, 256, 0, stream>>>(x, b_pre, Xb, D, tx4);
    prep_wb<<<2048, 256, 0, stream>>>(W_enc, Wb, tw4);
    dim3 gg(H / 128, B / 128);
    enc_gemm_bf16<<<gg, 256, 0, stream>>>(Xb, Wb, b_enc, hidden, D, H);  // u16 keys
    if (useSPLIT) {
      // delta >= 2*(GEMM err ~0.01 + bf16 ulp/2 ~0.008) with slack
      topk_classify_keys<<<B, 256, 0, stream>>>(hidden, sure_ix, sure_val, sure_cnt,
                                                amb_ix, amb_cnt, kptr, 0.05f);
      refine_f64<<<B, 256, 0, stream>>>(x, b_pre, W_enc, b_enc, amb_ix, amb_cnt, amb_sv, D);
      rank_scatter2<<<B, 256, 0, stream>>>(sure_ix, sure_val, sure_cnt,
                                           amb_ix, amb_sv, amb_cnt, kptr,
                                           hidden, tk_idx, tk_val);
    } else {
      topk_select<<<B, 256, 0, stream>>>(x, b_pre, W_enc, b_enc, hidden,
                                         tk_idx, tk_val, kptr, D, 0.04f);
    }
  } else {
    dim3 gg(H / BN, B / BM);
    enc_gemm_f32<<<gg, 256, 0, stream>>>(x, W_enc, b_enc, b_pre, hidden, D, H);
    const size_t sh = CAND_MAX * sizeof(double) + (size_t)D * sizeof(float)
                    + CAND_MAX * sizeof(int) + (NBITER + 8) * sizeof(int);
    topk_refine<<<B, 256, sh, stream>>>(x, b_pre, W_enc, b_enc, hidden,
                                        tk_idx, tk_val, kptr, D, H, 1e-3f);
  }

  if (useWT)
    transpose_wdec_bf16<<<dim3((H + 31) / 32, (D + 31) / 32), 256, 0, stream>>>(W_dec, WTb, D, H);

  decode_loss<<<B, 256, 0, stream>>>(x, b_pre, b_dec, W_dec, WTb,
                                     tk_idx, tk_val, kptr, recon, row_ssq, D, H, useWT);

  const int rpb = (B + 63) / 64;
  finalize_part<<<64, 256, 0, stream>>>(row_ssq, tk_val, kptr, part_s, part_c, B, rpb);
  finalize_k2<<<1, 64, 0, stream>>>(part_s, part_c, scalars, 64, B, D);
}

// Round 10
// 1136.405 us; speedup vs baseline: 5.3979x; 1.0405x over previous
//
#include <hip/hip_runtime.h>
#include <hip/hip_bf16.h>

constexpr int K_MAX    = 128;   // max supported k (actual k=64 read from device)
constexpr int S_MAX    = 128;   // sure-member cap per row (provably S <= k-1 < 128)
constexpr int A_MAX    = 256;   // ambiguous cap per row
constexpr int CAND_MAX = 512;   // fused-fallback candidate cap
constexpr int BM = 128, BN = 128, BKF = 16;
constexpr int NBITER = 42;      // fallback bisection iterations
constexpr int D_MAX   = 2048;   // fast path requires D <= D_MAX
constexpr int H_FIX   = 16384;  // fast path requires H == H_FIX

typedef __attribute__((ext_vector_type(8))) short bf16x8;
typedef __attribute__((ext_vector_type(8))) unsigned short u16x8;
typedef __attribute__((ext_vector_type(4))) float f32x4;

__device__ inline unsigned short f2bf(float f) {   // round-to-nearest-even
  unsigned u = __float_as_uint(f);
  return (unsigned short)((u + 0x7fff + ((u >> 16) & 1)) >> 16);
}
// monotone 16-bit key: key order == value order (handles negatives)
__device__ inline unsigned short key_of(float f) {
  unsigned short b = f2bf(f);
  return b ^ ((b & 0x8000) ? 0xFFFF : 0x8000);
}
__device__ inline float val_of_key(unsigned short kk) {
  unsigned short b = (kk & 0x8000) ? (unsigned short)(kk ^ 0x8000)
                                   : (unsigned short)(kk ^ 0xFFFF);
  return __uint_as_float(((unsigned)b) << 16);
}
__device__ inline float bf2f(unsigned short b) {
  return __uint_as_float(((unsigned)b) << 16);
}

// conflict-free superrow swizzle (R8-verified: bank conflicts 1.26e8 -> 0)
__device__ inline int lds_slot(int r, int c) {
  return ((r >> 1) << 4) | ((r & 1) << 3) | (c ^ ((r >> 1) & 7));
}

// ---------------- prep: Xb = bf16(x - b_pre), Wb = bf16(W_enc) ----------------
__global__ __launch_bounds__(256) void prep_xb(
    const float* __restrict__ x, const float* __restrict__ b_pre,
    unsigned short* __restrict__ Xb, int D, size_t total4)
{
  for (size_t i = blockIdx.x * 256 + threadIdx.x; i < total4; i += (size_t)gridDim.x * 256) {
    const size_t e = i * 4;
    const int d = (int)(e % D);
    float4 xv = *reinterpret_cast<const float4*>(x + e);
    float4 bp = *reinterpret_cast<const float4*>(b_pre + d);
    ushort4 o;
    o.x = f2bf(xv.x - bp.x); o.y = f2bf(xv.y - bp.y);
    o.z = f2bf(xv.z - bp.z); o.w = f2bf(xv.w - bp.w);
    *reinterpret_cast<ushort4*>(Xb + e) = o;
  }
}

__global__ __launch_bounds__(256) void prep_wb(
    const float* __restrict__ W, unsigned short* __restrict__ Wb, size_t total4)
{
  for (size_t i = blockIdx.x * 256 + threadIdx.x; i < total4; i += (size_t)gridDim.x * 256) {
    const size_t e = i * 4;
    float4 wv = *reinterpret_cast<const float4*>(W + e);
    ushort4 o;
    o.x = f2bf(wv.x); o.y = f2bf(wv.y); o.z = f2bf(wv.z); o.w = f2bf(wv.w);
    *reinterpret_cast<ushort4*>(Wb + e) = o;
  }
}

// ---------------- kernel 1: encoder GEMM, bf16 MFMA, writes monotone u16 keys ----------------
// BK=64, double-buffered LDS, stage-first, one barrier per K-tile, superrow
// swizzle (conflict-free). NO XCD block swizzle (R9: tripled FETCH; L3-fit regime).
__global__ __launch_bounds__(256) void enc_gemm_bf16(
    const unsigned short* __restrict__ Xb, const unsigned short* __restrict__ Wb,
    const float* __restrict__ b_enc, float* __restrict__ pre, int D, int H)
{
  __shared__ unsigned short As[2][128 * 64];
  __shared__ unsigned short Bs[2][128 * 64];
  const int tid  = threadIdx.x;
  const int wave = tid >> 6, lane = tid & 63;
  const int m0 = blockIdx.y * 128, n0 = blockIdx.x * 128;
  const int wm = (wave >> 1) * 64, wn = (wave & 1) * 64;
  const int l16 = lane & 15, lhi = lane >> 4;

  f32x4 acc[4][4];
#pragma unroll
  for (int i = 0; i < 4; ++i)
#pragma unroll
    for (int j = 0; j < 4; ++j) acc[i][j] = (f32x4){0.f, 0.f, 0.f, 0.f};

  const int NT = D / 64;

  // prologue: stage tile 0 into buffer 0 (LDS dest linear, global src inverse-permuted)
#pragma unroll
  for (int i = 0; i < 4; ++i) {
    const int base = wave * 64 + i * 256;
    const int idx  = base + lane;
    const int sr = idx >> 4, u = idx & 15;
    const int row = (sr << 1) | (u >> 3);
    const int ch  = (u & 7) ^ (sr & 7);
    __builtin_amdgcn_global_load_lds(
        (const __attribute__((address_space(1))) unsigned int*)(Xb + (size_t)(m0 + row) * D + ch * 8),
        (__attribute__((address_space(3))) unsigned int*)(As[0] + (size_t)base * 8), 16, 0, 0);
    __builtin_amdgcn_global_load_lds(
        (const __attribute__((address_space(1))) unsigned int*)(Wb + (size_t)(n0 + row) * D + ch * 8),
        (__attribute__((address_space(3))) unsigned int*)(Bs[0] + (size_t)base * 8), 16, 0, 0);
  }
  __syncthreads();

  int cur = 0;
  for (int t = 0; t < NT; ++t) {
    if (t + 1 < NT) {
      const int kb = (t + 1) * 64;
      const int nxt = cur ^ 1;
#pragma unroll
      for (int i = 0; i < 4; ++i) {
        const int base = wave * 64 + i * 256;
        const int idx  = base + lane;
        const int sr = idx >> 4, u = idx & 15;
        const int row = (sr << 1) | (u >> 3);
        const int ch  = (u & 7) ^ (sr & 7);
        __builtin_amdgcn_global_load_lds(
            (const __attribute__((address_space(1))) unsigned int*)(Xb + (size_t)(m0 + row) * D + kb + ch * 8),
            (__attribute__((address_space(3))) unsigned int*)(As[nxt] + (size_t)base * 8), 16, 0, 0);
        __builtin_amdgcn_global_load_lds(
            (const __attribute__((address_space(1))) unsigned int*)(Wb + (size_t)(n0 + row) * D + kb + ch * 8),
            (__attribute__((address_space(3))) unsigned int*)(Bs[nxt] + (size_t)base * 8), 16, 0, 0);
      }
    }
#pragma unroll
    for (int kk = 0; kk < 2; ++kk) {
      bf16x8 af[4], bfr[4];
#pragma unroll
      for (int mi = 0; mi < 4; ++mi)
        af[mi] = *reinterpret_cast<const bf16x8*>(
            As[cur] + (size_t)lds_slot(wm + mi * 16 + l16, kk * 4 + lhi) * 8);
#pragma unroll
      for (int ni = 0; ni < 4; ++ni)
        bfr[ni] = *reinterpret_cast<const bf16x8*>(
            Bs[cur] + (size_t)lds_slot(wn + ni * 16 + l16, kk * 4 + lhi) * 8);
#pragma unroll
      for (int mi = 0; mi < 4; ++mi)
#pragma unroll
        for (int ni = 0; ni < 4; ++ni)
          acc[mi][ni] = __builtin_amdgcn_mfma_f32_16x16x32_bf16(af[mi], bfr[ni], acc[mi][ni], 0, 0, 0);
    }
    __syncthreads();
    cur ^= 1;
  }

  // epilogue: write monotone u16 keys (half the bytes of f32 pre)
#pragma unroll
  for (int ni = 0; ni < 4; ++ni) {
    const int n = n0 + wn + ni * 16 + l16;
    const float be = b_enc[n];
#pragma unroll
    for (int mi = 0; mi < 4; ++mi) {
      const int mbase = m0 + wm + mi * 16 + lhi * 4;
#pragma unroll
      for (int r = 0; r < 4; ++r) {
        unsigned short* prow = (unsigned short*)(pre + (size_t)(mbase + r) * H);
        prow[n] = key_of(acc[mi][ni][r] + be);
      }
    }
  }
}

// ---------------- kernel 2: single-pass key classify + hidden-row zero ----------------
// 64 keys/thread in 16 VGPRs; hist -> exact k-th key -> sure/amb thresholds in
// key space -> classify from registers. Also zeroes the hidden row (keys are
// consumed into registers first) so the scatter kernel needs no zero pass.
__global__ __launch_bounds__(256) void topk_classify_keys(
    float* __restrict__ hidden,
    int* __restrict__ sure_ix, float* __restrict__ sure_val, int* __restrict__ sure_cnt,
    int* __restrict__ amb_ix, int* __restrict__ amb_cnt,
    const int* __restrict__ kptr, float delta)
{
  constexpr int H = H_FIX, NC = H_FIX / (256 * 8);
  __shared__ int hist[4096];
  __shared__ int chunk[256];
  __shared__ int misc[8];   // 0:b1 1:run 2:ks 3:ka 4:sure_n 5:amb_n

  const int tid = threadIdx.x, b = blockIdx.x;
  const int k = min(*kptr, K_MAX);
  float* hrow = hidden + (size_t)b * H;
  const unsigned short* krow = (const unsigned short*)hrow;

  if (tid < 8) misc[tid] = 0;
  for (int i = tid; i < 4096; i += 256) hist[i] = 0;

  u16x8 kv[NC];
#pragma unroll
  for (int i = 0; i < NC; ++i)
    kv[i] = *reinterpret_cast<const u16x8*>(krow + ((size_t)i * 256 + tid) * 8);
  __syncthreads();   // all keys in registers before the row is overwritten

  // zero the hidden row now; stores drain while we do LDS histogram work
  const float4 z4 = {0.f, 0.f, 0.f, 0.f};
  for (int i = tid; i < (H >> 2); i += 256)
    reinterpret_cast<float4*>(hrow)[i] = z4;

#pragma unroll
  for (int i = 0; i < NC; ++i)
#pragma unroll
    for (int j = 0; j < 8; ++j)
      atomicAdd(&hist[((unsigned)(unsigned short)kv[i][j]) >> 4], 1);
  __syncthreads();

  int csum = 0;
#pragma unroll
  for (int j = 0; j < 16; ++j) csum += hist[tid * 16 + j];
  chunk[tid] = csum;
  __syncthreads();
  int gt = 0;
  for (int j = tid + 1; j < 256; ++j) gt += chunk[j];
  {
    int run = gt;
#pragma unroll
    for (int j = 15; j >= 0; --j) {
      const int hc = hist[tid * 16 + j];
      if (run < k && k <= run + hc) { misc[0] = tid * 16 + j; misc[1] = run; }
      run += hc;
    }
  }
  __syncthreads();
  const int b1 = misc[0];
  if (tid < 16) chunk[tid] = 0;
  __syncthreads();
  // 16-bin sub-histogram of bin b1 (from registers)
#pragma unroll
  for (int i = 0; i < NC; ++i)
#pragma unroll
    for (int j = 0; j < 8; ++j) {
      const unsigned kk = (unsigned)(unsigned short)kv[i][j];
      if ((int)(kk >> 4) == b1) atomicAdd(&chunk[kk & 15], 1);
    }
  __syncthreads();
  if (tid == 0) {
    int run = misc[1];
    int K16 = b1 << 4;
    for (int j = 15; j >= 0; --j) {
      const int c = chunk[j];
      if (run < k && k <= run + c) K16 = (b1 << 4) | j;
      run += c;
    }
    const float v_lo = val_of_key((unsigned short)K16);
    const float v_hi = val_of_key((unsigned short)min(K16 + 1, 65535));
    const float ulp = v_hi - v_lo;
    const float vs = v_hi + delta;          // sure: value >  vs
    const float va = v_lo - ulp - delta;    // amb : value >= va
    int ks = key_of(vs); if (val_of_key((unsigned short)ks) > vs) --ks;   // floor key
    int ka = key_of(va); if (val_of_key((unsigned short)ka) < va) ++ka;   // ceil key
    misc[2] = ks; misc[3] = ka;
  }
  __syncthreads();
  const unsigned ks = (unsigned)misc[2], ka = (unsigned)misc[3];

#pragma unroll
  for (int i = 0; i < NC; ++i)
#pragma unroll
    for (int j = 0; j < 8; ++j) {
      const unsigned kk = (unsigned)(unsigned short)kv[i][j];
      if (kk > ks) {
        const int p = atomicAdd(&misc[4], 1);
        if (p < S_MAX) {
          const int h = (i * 256 + tid) * 8 + j;
          sure_ix[(size_t)b * S_MAX + p] = h;
          sure_val[(size_t)b * S_MAX + p] = val_of_key((unsigned short)kk);
        }
      } else if (kk >= ka) {
        const int p = atomicAdd(&misc[5], 1);
        if (p < A_MAX) amb_ix[(size_t)b * A_MAX + p] = (i * 256 + tid) * 8 + j;
      }
    }
  __syncthreads();
  if (tid == 0) {
    sure_cnt[b] = min(misc[4], S_MAX);
    amb_cnt[b]  = min(misc[5], A_MAX);
  }
}

// ---------------- kernel 3: f64 refine + rank + scatter (merged; row pre-zeroed) ----------------
__global__ __launch_bounds__(256) void refine_scatter(
    const float* __restrict__ X, const float* __restrict__ b_pre,
    const float* __restrict__ W, const float* __restrict__ b_enc,
    const int* __restrict__ sure_ix, const float* __restrict__ sure_val,
    const int* __restrict__ sure_cnt,
    const int* __restrict__ amb_ix, const int* __restrict__ amb_cnt,
    const int* __restrict__ kptr,
    float* __restrict__ hidden, int* __restrict__ tk_idx, float* __restrict__ tk_val, int D)
{
  constexpr int H = H_FIX;
  __shared__ float  xr[D_MAX];
  __shared__ double asv[A_MAX];
  __shared__ int    aix[A_MAX];
  const int tid = threadIdx.x, b = blockIdx.x;
  const int k = min(*kptr, K_MAX);
  const int S = min(min(sure_cnt[b], S_MAX), k);
  const int A = min(amb_cnt[b], A_MAX);
  float* hrow = hidden + (size_t)b * H;

  for (int d = tid; d < D; d += 256) xr[d] = X[(size_t)b * D + d] - b_pre[d];
  for (int c = tid; c < A; c += 256) aix[c] = amb_ix[(size_t)b * A_MAX + c];

  // sure members: value = bf16-granular GEMM approx (err << 1.28 threshold)
  for (int i = tid; i < S; i += 256) {
    const int h = sure_ix[(size_t)b * S_MAX + i];
    const float v = sure_val[(size_t)b * S_MAX + i];
    const float rv = (v > 0.f) ? v : 0.f;
    hrow[h] = rv;
    tk_idx[(size_t)b * K_MAX + i] = h;
    tk_val[(size_t)b * K_MAX + i] = rv;
  }
  __syncthreads();

  // exact f64 dots for the ambiguous band (deterministic reduction order)
  const int wid = tid >> 6, lane = tid & 63;
  for (int c = wid; c < A; c += 4) {
    const int h = aix[c];
    const float* wr = W + (size_t)h * D;
    double s0 = 0.0, s1 = 0.0;
    int i = lane;
    for (; i + 64 < D; i += 128) {
      s0 += (double)xr[i] * (double)wr[i];
      s1 += (double)xr[i + 64] * (double)wr[i + 64];
    }
    if (i < D) s0 += (double)xr[i] * (double)wr[i];
    double s = s0 + s1;
    for (int off = 32; off; off >>= 1) s += __shfl_xor(s, off);
    if (lane == 0) asv[c] = s + (double)b_enc[h];
  }
  __syncthreads();

  // ambiguous: top (k-S) by exact f64 value, index tie-break
  const int m = k - S;
  for (int c = tid; c < A; c += 256) {
    const double v = asv[c];
    const int h = aix[c];
    int r = 0;
    for (int j = 0; j < A; ++j) {
      const double vj = asv[j];
      r += ((vj > v) || (vj == v && aix[j] < h)) ? 1 : 0;
    }
    if (r < m) {
      const float rv = (v > 0.0) ? (float)v : 0.f;
      hrow[h] = rv;
      tk_idx[(size_t)b * K_MAX + S + r] = h;
      tk_val[(size_t)b * K_MAX + S + r] = rv;
    }
  }
}

// ---------------- fused fallback: single-pass select on u16 keys ----------------
__global__ __launch_bounds__(256, 2) void topk_select(
    const float* __restrict__ X, const float* __restrict__ b_pre,
    const float* __restrict__ W, const float* __restrict__ b_enc,
    float* __restrict__ hidden, int* __restrict__ tk_idx, float* __restrict__ tk_val,
    const int* __restrict__ kptr, int D, float margin)
{
  constexpr int H = H_FIX, NC = H_FIX / (256 * 8);
  __shared__ double cand_sv[CAND_MAX];
  __shared__ float  xr[D_MAX];
  __shared__ int    cand_ix[CAND_MAX];
  __shared__ int    hist[4096];
  __shared__ int    chunk[256];
  __shared__ int    misc[8];

  const int tid = threadIdx.x, b = blockIdx.x;
  const int k = min(*kptr, K_MAX);
  float* hrow = hidden + (size_t)b * H;
  const unsigned short* krow = (const unsigned short*)hrow;

  if (tid < 8) misc[tid] = 0;
  for (int i = tid; i < 4096; i += 256) hist[i] = 0;
  for (int d = tid; d < D; d += 256) xr[d] = X[(size_t)b * D + d] - b_pre[d];

  u16x8 kv[NC];
#pragma unroll
  for (int i = 0; i < NC; ++i)
    kv[i] = *reinterpret_cast<const u16x8*>(krow + ((size_t)i * 256 + tid) * 8);
  __syncthreads();

#pragma unroll
  for (int i = 0; i < NC; ++i)
#pragma unroll
    for (int j = 0; j < 8; ++j)
      atomicAdd(&hist[((unsigned)(unsigned short)kv[i][j]) >> 4], 1);
  __syncthreads();

  int csum = 0;
#pragma unroll
  for (int j = 0; j < 16; ++j) csum += hist[tid * 16 + j];
  chunk[tid] = csum;
  __syncthreads();
  int gt = 0;
  for (int j = tid + 1; j < 256; ++j) gt += chunk[j];
  {
    int run = gt;
#pragma unroll
    for (int j = 15; j >= 0; --j) {
      const int hc = hist[tid * 16 + j];
      if (run < k && k <= run + hc) { misc[0] = tid * 16 + j; misc[1] = run; }
      run += hc;
    }
  }
  __syncthreads();
  const int b1 = misc[0];
  if (tid < 16) chunk[tid] = 0;
  __syncthreads();
#pragma unroll
  for (int i = 0; i < NC; ++i)
#pragma unroll
    for (int j = 0; j < 8; ++j) {
      const unsigned kk = (unsigned)(unsigned short)kv[i][j];
      if ((int)(kk >> 4) == b1) atomicAdd(&chunk[kk & 15], 1);
    }
  __syncthreads();
  if (tid == 0) {
    int run = misc[1];
    int K16 = b1 << 4;
    for (int j = 15; j >= 0; --j) {
      const int c = chunk[j];
      if (run < k && k <= run + c) K16 = (b1 << 4) | j;
      run += c;
    }
    const float vthr = val_of_key((unsigned short)K16) - margin;
    int kt = (int)key_of(vthr);
    if (kt > K16) kt = K16;
    misc[2] = kt;
  }
  __syncthreads();
  const unsigned kthr = (unsigned)misc[2];

#pragma unroll
  for (int i = 0; i < NC; ++i)
#pragma unroll
    for (int j = 0; j < 8; ++j) {
      if ((unsigned)(unsigned short)kv[i][j] >= kthr) {
        const int pos = atomicAdd(&misc[3], 1);
        if (pos < CAND_MAX) cand_ix[pos] = (i * 256 + tid) * 8 + j;
      }
    }
  __syncthreads();
  const int C = min(misc[3], CAND_MAX);

  const float4 z4 = {0.f, 0.f, 0.f, 0.f};
  for (int i = tid; i < (H >> 2); i += 256)
    reinterpret_cast<float4*>(hrow)[i] = z4;

  const int wid = tid >> 6, lane = tid & 63;
  for (int c = wid; c < C; c += 4) {
    const int h = cand_ix[c];
    const float* wr = W + (size_t)h * D;
    double s = 0.0;
    for (int i = lane; i < D; i += 64) s += (double)xr[i] * (double)wr[i];
    for (int off = 32; off; off >>= 1) s += __shfl_xor(s, off);
    if (lane == 0) cand_sv[c] = s + (double)b_enc[h];
  }
  __syncthreads();

  for (int c = tid; c < C; c += 256) {
    const double v = cand_sv[c];
    const int h = cand_ix[c];
    int r = 0;
    for (int j = 0; j < C; ++j) {
      const double vj = cand_sv[j];
      r += ((vj > v) || (vj == v && cand_ix[j] < h)) ? 1 : 0;
    }
    if (r < k) {
      const float rv = (v > 0.0) ? (float)v : 0.f;
      hrow[h] = rv;
      tk_idx[(size_t)b * K_MAX + r] = h;
      tk_val[(size_t)b * K_MAX + r] = rv;
    }
  }
}

// ---------------- fallback: fp32 GEMM ----------------
__global__ __launch_bounds__(256) void enc_gemm_f32(
    const float* __restrict__ X, const float* __restrict__ W,
    const float* __restrict__ b_enc, const float* __restrict__ b_pre,
    float* __restrict__ pre, int D, int H)
{
  __shared__ float As[BKF][BM + 4];
  __shared__ float Bs[BKF][BN + 4];
  const int tid = threadIdx.x;
  const int m0 = blockIdx.y * BM;
  const int n0 = blockIdx.x * BN;
  const int tx = tid & 15, ty = tid >> 4;
  float acc[8][8];
#pragma unroll
  for (int i = 0; i < 8; ++i)
#pragma unroll
    for (int j = 0; j < 8; ++j) acc[i][j] = 0.f;

  for (int kb = 0; kb < D; kb += BKF) {
#pragma unroll
    for (int t = 0; t < 2; ++t) {
      const int f4i = tid + t * 256;
      const int row = f4i >> 2;
      const int kq  = (f4i & 3) << 2;
      float4 xv = *reinterpret_cast<const float4*>(X + (size_t)(m0 + row) * D + kb + kq);
      float4 bp = *reinterpret_cast<const float4*>(b_pre + kb + kq);
      As[kq + 0][row] = xv.x - bp.x; As[kq + 1][row] = xv.y - bp.y;
      As[kq + 2][row] = xv.z - bp.z; As[kq + 3][row] = xv.w - bp.w;
      float4 wv = *reinterpret_cast<const float4*>(W + (size_t)(n0 + row) * D + kb + kq);
      Bs[kq + 0][row] = wv.x; Bs[kq + 1][row] = wv.y;
      Bs[kq + 2][row] = wv.z; Bs[kq + 3][row] = wv.w;
    }
    __syncthreads();
#pragma unroll
    for (int kk = 0; kk < BKF; ++kk) {
      float4 a0 = *reinterpret_cast<const float4*>(&As[kk][ty * 8]);
      float4 a1 = *reinterpret_cast<const float4*>(&As[kk][ty * 8 + 4]);
      float4 b0 = *reinterpret_cast<const float4*>(&Bs[kk][tx * 8]);
      float4 b1 = *reinterpret_cast<const float4*>(&Bs[kk][tx * 8 + 4]);
      float av[8] = {a0.x, a0.y, a0.z, a0.w, a1.x, a1.y, a1.z, a1.w};
      float bv[8] = {b0.x, b0.y, b0.z, b0.w, b1.x, b1.y, b1.z, b1.w};
#pragma unroll
      for (int i = 0; i < 8; ++i)
#pragma unroll
        for (int j = 0; j < 8; ++j) acc[i][j] += av[i] * bv[j];
    }
    __syncthreads();
  }
#pragma unroll
  for (int i = 0; i < 8; ++i) {
    const size_t m = (size_t)(m0 + ty * 8 + i);
#pragma unroll
    for (int j = 0; j < 8; j += 4) {
      const int n = n0 + tx * 8 + j;
      float4 o;
      o.x = acc[i][j + 0] + b_enc[n + 0];
      o.y = acc[i][j + 1] + b_enc[n + 1];
      o.z = acc[i][j + 2] + b_enc[n + 2];
      o.w = acc[i][j + 3] + b_enc[n + 3];
      *reinterpret_cast<float4*>(pre + m * H + n) = o;
    }
  }
}

// ---------------- fallback: bisection top-k (reads f32 pre) ----------------
__global__ __launch_bounds__(256) void topk_refine(
    const float* __restrict__ X, const float* __restrict__ b_pre,
    const float* __restrict__ W, const float* __restrict__ b_enc,
    float* __restrict__ hidden, int* __restrict__ tk_idx, float* __restrict__ tk_val,
    const int* __restrict__ kptr, int D, int H, float margin)
{
  extern __shared__ char smem_raw[];
  double* cand_val = reinterpret_cast<double*>(smem_raw);
  float*  xr       = reinterpret_cast<float*>(cand_val + CAND_MAX);
  int*    cand_idx = reinterpret_cast<int*>(xr + D);
  int*    misc     = cand_idx + CAND_MAX;

  const int tid = threadIdx.x;
  const int b = blockIdx.x;
  const int k = min(*kptr, K_MAX);
  float* hrow = hidden + (size_t)b * H;

  for (int i = tid; i < NBITER + 2; i += 256) misc[i] = 0;
  for (int d = tid; d < D; d += 256) xr[d] = X[(size_t)b * D + d] - b_pre[d];

  float f[64];
#pragma unroll
  for (int i = 0; i < 16; ++i) {
    const int base = i * 1024 + tid * 4;
    float4 v = {-3e38f, -3e38f, -3e38f, -3e38f};
    if (base + 3 < H) v = *reinterpret_cast<const float4*>(hrow + base);
    f[4 * i + 0] = v.x; f[4 * i + 1] = v.y; f[4 * i + 2] = v.z; f[4 * i + 3] = v.w;
  }
  __syncthreads();

  float lo = -1e4f, hi = 1e4f;
  for (int it = 0; it < NBITER; ++it) {
    const float mid = 0.5f * (lo + hi);
    int cnt = 0;
#pragma unroll
    for (int j = 0; j < 64; ++j) cnt += (f[j] >= mid) ? 1 : 0;
    for (int off = 32; off; off >>= 1) cnt += __shfl_xor(cnt, off);
    if ((tid & 63) == 0) atomicAdd(&misc[it], cnt);
    __syncthreads();
    if (misc[it] >= k) lo = mid; else hi = mid;
  }

  const float thresh = lo - margin;
#pragma unroll
  for (int j = 0; j < 64; ++j) {
    if (f[j] >= thresh) {
      const int h = (j >> 2) * 1024 + tid * 4 + (j & 3);
      if (h < H) {
        int pos = atomicAdd(&misc[NBITER], 1);
        if (pos < CAND_MAX) cand_idx[pos] = h;
      }
    }
  }
  __syncthreads();
  const int C = min(misc[NBITER], CAND_MAX);

  const int wid = tid >> 6, lane = tid & 63;
  for (int c = wid; c < C; c += 4) {
    const int h = cand_idx[c];
    const float* wr = W + (size_t)h * D;
    double s = 0.0;
    for (int i = lane; i < D; i += 64) s += (double)xr[i] * (double)wr[i];
    for (int off = 32; off; off >>= 1) s += __shfl_xor(s, off);
    if (lane == 0) cand_val[c] = s + (double)b_enc[h];
  }
  __syncthreads();

  const float4 z4 = {0.f, 0.f, 0.f, 0.f};
  for (int i = tid; i < (H >> 2); i += 256)
    reinterpret_cast<float4*>(hrow)[i] = z4;
  __syncthreads();

  for (int c = tid; c < C; c += 256) {
    const double v = cand_val[c];
    const int h = cand_idx[c];
    int r = 0;
    for (int j = 0; j < C; ++j) {
      const double vj = cand_val[j];
      r += ((vj > v) || (vj == v && cand_idx[j] < h)) ? 1 : 0;
    }
    if (r < k) {
      const float rv = (v > 0.0) ? (float)v : 0.f;
      hrow[h] = rv;
      tk_idx[(size_t)b * K_MAX + r] = h;
      tk_val[(size_t)b * K_MAX + r] = rv;
    }
  }
}

// ---------------- kernel 5: W_dec [D,H] -> bf16 W_decT [H,D] ----------------
__global__ __launch_bounds__(256) void transpose_wdec_bf16(
    const float* __restrict__ Wsrc, unsigned short* __restrict__ WT, int D, int H)
{
  __shared__ float tile[32][33];
  const int c  = threadIdx.x & 31;
  const int r0 = threadIdx.x >> 5;
  const int h0 = blockIdx.x * 32;
  const int d0 = blockIdx.y * 32;
#pragma unroll
  for (int r = r0; r < 32; r += 8) {
    const int d = d0 + r, h = h0 + c;
    if (d < D && h < H) tile[r][c] = Wsrc[(size_t)d * H + h];
  }
  __syncthreads();
#pragma unroll
  for (int r = r0; r < 32; r += 8) {
    const int h = h0 + r, d = d0 + c;
    if (h < H && d < D) WT[(size_t)h * D + d] = f2bf(tile[c][r]);
  }
}

// ---------------- kernel 6: sparse decode + per-row squared error (vectorized) ----------------
__global__ __launch_bounds__(256) void decode_loss(
    const float* __restrict__ X, const float* __restrict__ b_pre,
    const float* __restrict__ b_dec, const float* __restrict__ Wfull,
    const unsigned short* __restrict__ WTb,
    const int* __restrict__ tk_idx, const float* __restrict__ tk_val,
    const int* __restrict__ kptr,
    float* __restrict__ recon, double* __restrict__ row_ssq,
    int D, int H, int useWT)
{
  __shared__ int   sidx[K_MAX];
  __shared__ float sval[K_MAX];
  __shared__ double sd[4];
  const int tid = threadIdx.x, b = blockIdx.x;
  const int k = min(*kptr, K_MAX);
  if (tid < k) {
    sidx[tid] = tk_idx[(size_t)b * K_MAX + tid];
    sval[tid] = tk_val[(size_t)b * K_MAX + tid];
  }
  __syncthreads();
  double ssq = 0.0;
  const int D4 = D >> 2;
  for (int dc = tid; dc < D4; dc += 256) {
    const int d = dc * 4;
    float4 bd = *reinterpret_cast<const float4*>(b_dec + d);
    float4 bp = *reinterpret_cast<const float4*>(b_pre + d);
    float4 a = {bd.x + bp.x, bd.y + bp.y, bd.z + bp.z, bd.w + bp.w};
    if (useWT) {
#pragma unroll 4
      for (int j = 0; j < k; ++j) {
        const ushort4 w = *reinterpret_cast<const ushort4*>(WTb + (size_t)sidx[j] * D + d);
        const float s = sval[j];
        a.x += s * bf2f(w.x); a.y += s * bf2f(w.y);
        a.z += s * bf2f(w.z); a.w += s * bf2f(w.w);
      }
    } else {
#pragma unroll 4
      for (int j = 0; j < k; ++j) {
        const float s = sval[j];
        const int h = sidx[j];
        a.x += s * Wfull[(size_t)(d + 0) * H + h];
        a.y += s * Wfull[(size_t)(d + 1) * H + h];
        a.z += s * Wfull[(size_t)(d + 2) * H + h];
        a.w += s * Wfull[(size_t)(d + 3) * H + h];
      }
    }
    *reinterpret_cast<float4*>(recon + (size_t)b * D + d) = a;
    float4 xv = *reinterpret_cast<const float4*>(X + (size_t)b * D + d);
    const double d0 = (double)a.x - (double)xv.x;
    const double d1 = (double)a.y - (double)xv.y;
    const double d2 = (double)a.z - (double)xv.z;
    const double d3 = (double)a.w - (double)xv.w;
    ssq += d0 * d0 + d1 * d1 + d2 * d2 + d3 * d3;
  }
  for (int off = 32; off; off >>= 1) ssq += __shfl_xor(ssq, off);
  if ((tid & 63) == 0) sd[tid >> 6] = ssq;
  __syncthreads();
  if (tid == 0) row_ssq[b] = sd[0] + sd[1] + sd[2] + sd[3];
}

// ---------------- kernel 7a: per-chunk partial losses (64 blocks) ----------------
__global__ __launch_bounds__(256) void finalize_part(
    const double* __restrict__ row_ssq, const float* __restrict__ tk_val,
    const int* __restrict__ kptr, double* __restrict__ part_s, int* __restrict__ part_c,
    int Bdim, int rows_per_blk)
{
  __shared__ double sd[4];
  __shared__ int si[4];
  const int tid = threadIdx.x;
  const int k = min(*kptr, K_MAX);
  const int b0 = blockIdx.x * rows_per_blk;
  const int b1 = min(b0 + rows_per_blk, Bdim);
  double s = 0.0;
  for (int i = b0 + tid; i < b1; i += 256) s += row_ssq[i];
  int cnt = 0;
  const int total = (b1 - b0) * k;
  for (int i = tid; i < total; i += 256) {
    const int bb = b0 + i / k, j = i - (i / k) * k;
    cnt += (tk_val[(size_t)bb * K_MAX + j] > 0.f) ? 1 : 0;
  }
  for (int off = 32; off; off >>= 1) { s += __shfl_xor(s, off); cnt += __shfl_xor(cnt, off); }
  if ((tid & 63) == 0) { sd[tid >> 6] = s; si[tid >> 6] = cnt; }
  __syncthreads();
  if (tid == 0) {
    part_s[blockIdx.x] = sd[0] + sd[1] + sd[2] + sd[3];
    part_c[blockIdx.x] = si[0] + si[1] + si[2] + si[3];
  }
}

// ---------------- kernel 7b: final scalar losses ----------------
__global__ __launch_bounds__(64) void finalize_k2(
    const double* __restrict__ part_s, const int* __restrict__ part_c,
    float* __restrict__ scalars, int nparts, int Bdim, int D)
{
  const int tid = threadIdx.x;
  double s = (tid < nparts) ? part_s[tid] : 0.0;
  int cnt = (tid < nparts) ? part_c[tid] : 0;
  for (int off = 32; off; off >>= 1) { s += __shfl_xor(s, off); cnt += __shfl_xor(cnt, off); }
  if (tid == 0) {
    const double rl = s / ((double)Bdim * (double)D);
    scalars[0] = (float)rl;                     // loss
    scalars[1] = (float)rl;                     // reconstruction_loss
    scalars[2] = 0.f;                           // sparsity_loss
    scalars[3] = (float)((double)cnt / Bdim);   // l0
  }
}

extern "C" void kernel_launch(void* const* d_in, const int* in_sizes, int n_in,
                              void* d_out, int out_size, void* d_ws, size_t ws_size,
                              hipStream_t stream)
{
  const float* x     = (const float*)d_in[0];
  const float* W_enc = (const float*)d_in[1];
  const float* b_enc = (const float*)d_in[2];
  const float* W_dec = (const float*)d_in[3];
  const float* b_dec = (const float*)d_in[4];
  const float* b_pre = (const float*)d_in[5];
  const int*   kptr  = (const int*)d_in[6];

  const int D = in_sizes[4];          // 1280
  const int H = in_sizes[2];          // 16384
  const int B = in_sizes[0] / D;      // 8192

  float* recon   = (float*)d_out;
  float* hidden  = recon + (size_t)B * D;       // temporarily holds keys / f32 pre
  float* scalars = hidden + (size_t)B * H;

  // ---- workspace layout (single running cursor) ----
  size_t off = 0;
  int* tk_idx = (int*)((char*)d_ws + off);        off += (size_t)B * K_MAX * sizeof(int);
  float* tk_val = (float*)((char*)d_ws + off);    off += (size_t)B * K_MAX * sizeof(float);
  off = (off + 7) & ~(size_t)7;
  double* row_ssq = (double*)((char*)d_ws + off); off += (size_t)B * sizeof(double);
  double* part_s = (double*)((char*)d_ws + off);  off += 64 * sizeof(double);
  int* part_c = (int*)((char*)d_ws + off);        off += 64 * sizeof(int);
  off = (off + 7) & ~(size_t)7;

  unsigned short* Xb = (unsigned short*)((char*)d_ws + off);
  off += (size_t)B * D * sizeof(unsigned short);
  unsigned short* Wb = (unsigned short*)((char*)d_ws + off);
  off += (size_t)H * D * sizeof(unsigned short);
  const int useBF16 = (off <= ws_size) ? 1 : 0;

  unsigned short* WTb = (unsigned short*)((char*)d_ws + off);
  off += (size_t)D * H * sizeof(unsigned short);
  const int useWT = (off <= ws_size) ? 1 : 0;

  int* sure_ix = (int*)((char*)d_ws + off);       off += (size_t)B * S_MAX * sizeof(int);
  float* sure_val = (float*)((char*)d_ws + off);  off += (size_t)B * S_MAX * sizeof(float);
  int* sure_cnt = (int*)((char*)d_ws + off);      off += (size_t)B * sizeof(int);
  int* amb_ix = (int*)((char*)d_ws + off);        off += (size_t)B * A_MAX * sizeof(int);
  int* amb_cnt = (int*)((char*)d_ws + off);       off += (size_t)B * sizeof(int);
  off = (off + 7) & ~(size_t)7;
  const int useSPLIT = (useBF16 && off <= ws_size) ? 1 : 0;

  const bool fast_ok = (D % 64 == 0) && (D <= D_MAX) &&
                       (H == H_FIX) && (B % 128 == 0);

  if (useBF16 && fast_ok) {
    const size_t tx4 = (size_t)B * D / 4, tw4 = (size_t)H * D / 4;
    prep_xb<<<2048, 256, 0, stream>>>(x, b_pre, Xb, D, tx4);
    prep_wb<<<2048, 256, 0, stream>>>(W_enc, Wb, tw4);
    dim3 gg(H / 128, B / 128);
    enc_gemm_bf16<<<gg, 256, 0, stream>>>(Xb, Wb, b_enc, hidden, D, H);  // u16 keys
    if (useSPLIT) {
      // delta >= 2*(GEMM err ~0.01 + bf16 ulp/2 ~0.008) with slack
      topk_classify_keys<<<B, 256, 0, stream>>>(hidden, sure_ix, sure_val, sure_cnt,
                                                amb_ix, amb_cnt, kptr, 0.05f);
      refine_scatter<<<B, 256, 0, stream>>>(x, b_pre, W_enc, b_enc,
                                            sure_ix, sure_val, sure_cnt,
                                            amb_ix, amb_cnt, kptr,
                                            hidden, tk_idx, tk_val, D);
    } else {
      topk_select<<<B, 256, 0, stream>>>(x, b_pre, W_enc, b_enc, hidden,
                                         tk_idx, tk_val, kptr, D, 0.04f);
    }
  } else {
    dim3 gg(H / BN, B / BM);
    enc_gemm_f32<<<gg, 256, 0, stream>>>(x, W_enc, b_enc, b_pre, hidden, D, H);
    const size_t sh = CAND_MAX * sizeof(double) + (size_t)D * sizeof(float)
                    + CAND_MAX * sizeof(int) + (NBITER + 8) * sizeof(int);
    topk_refine<<<B, 256, sh, stream>>>(x, b_pre, W_enc, b_enc, hidden,
                                        tk_idx, tk_val, kptr, D, H, 1e-3f);
  }

  if (useWT)
    transpose_wdec_bf16<<<dim3((H + 31) / 32, (D + 31) / 32), 256, 0, stream>>>(W_dec, WTb, D, H);

  decode_loss<<<B, 256, 0, stream>>>(x, b_pre, b_dec, W_dec, WTb,
                                     tk_idx, tk_val, kptr, recon, row_ssq, D, H, useWT);

  const int rpb = (B + 63) / 64;
  finalize_part<<<64, 256, 0, stream>>>(row_ssq, tk_val, kptr, part_s, part_c, B, rpb);
  finalize_k2<<<1, 64, 0, stream>>>(part_s, part_c, scalars, 64, B, D);
}

// Round 11
// 994.467 us; speedup vs baseline: 6.1684x; 1.1427x over previous
//
#include <hip/hip_runtime.h>
#include <hip/hip_bf16.h>

constexpr int K_MAX    = 128;   // max supported k (actual k=64 read from device)
constexpr int S_MAX    = 128;   // sure-member cap per row (provably S <= k-1 < 128)
constexpr int A_MAX    = 256;   // ambiguous cap per row
constexpr int CAND_MAX = 512;   // fused-fallback candidate cap
constexpr int BM = 128, BN = 128, BKF = 16;
constexpr int NBITER = 42;      // fallback bisection iterations
constexpr int D_MAX   = 2048;   // fast path requires D <= D_MAX
constexpr int H_FIX   = 16384;  // fast path requires H == H_FIX

typedef __attribute__((ext_vector_type(8))) short bf16x8;
typedef __attribute__((ext_vector_type(8))) unsigned short u16x8;
typedef __attribute__((ext_vector_type(4))) float f32x4;

__device__ inline unsigned short f2bf(float f) {   // round-to-nearest-even
  unsigned u = __float_as_uint(f);
  return (unsigned short)((u + 0x7fff + ((u >> 16) & 1)) >> 16);
}
// monotone 16-bit key: key order == value order (handles negatives)
__device__ inline unsigned short key_of(float f) {
  unsigned short b = f2bf(f);
  return b ^ ((b & 0x8000) ? 0xFFFF : 0x8000);
}
__device__ inline float val_of_key(unsigned short kk) {
  unsigned short b = (kk & 0x8000) ? (unsigned short)(kk ^ 0x8000)
                                   : (unsigned short)(kk ^ 0xFFFF);
  return __uint_as_float(((unsigned)b) << 16);
}
__device__ inline float bf2f(unsigned short b) {
  return __uint_as_float(((unsigned)b) << 16);
}

// conflict-free superrow swizzle (R8-verified: bank conflicts 1.26e8 -> 0)
// domain: r in [0,128), c in [0,8); slot units of 16B within a 128-row half-tile
__device__ inline int lds_slot(int r, int c) {
  return ((r >> 1) << 4) | ((r & 1) << 3) | (c ^ ((r >> 1) & 7));
}

// ---------------- prep: Xb = bf16(x - b_pre), Wb = bf16(W_enc) ----------------
__global__ __launch_bounds__(256) void prep_xb(
    const float* __restrict__ x, const float* __restrict__ b_pre,
    unsigned short* __restrict__ Xb, int D, size_t total4)
{
  for (size_t i = blockIdx.x * 256 + threadIdx.x; i < total4; i += (size_t)gridDim.x * 256) {
    const size_t e = i * 4;
    const int d = (int)(e % D);
    float4 xv = *reinterpret_cast<const float4*>(x + e);
    float4 bp = *reinterpret_cast<const float4*>(b_pre + d);
    ushort4 o;
    o.x = f2bf(xv.x - bp.x); o.y = f2bf(xv.y - bp.y);
    o.z = f2bf(xv.z - bp.z); o.w = f2bf(xv.w - bp.w);
    *reinterpret_cast<ushort4*>(Xb + e) = o;
  }
}

__global__ __launch_bounds__(256) void prep_wb(
    const float* __restrict__ W, unsigned short* __restrict__ Wb, size_t total4)
{
  for (size_t i = blockIdx.x * 256 + threadIdx.x; i < total4; i += (size_t)gridDim.x * 256) {
    const size_t e = i * 4;
    float4 wv = *reinterpret_cast<const float4*>(W + e);
    ushort4 o;
    o.x = f2bf(wv.x); o.y = f2bf(wv.y); o.z = f2bf(wv.z); o.w = f2bf(wv.w);
    *reinterpret_cast<ushort4*>(Wb + e) = o;
  }
}

// ---------------- kernel 1: encoder GEMM 256x256, 8 waves, 4-phase counted-vmcnt ----------------
// Per-wave 64(M)x128(N). K-tile=64. LDS: 2 dbuf x (A 256x64 + B 256x64) bf16 = 128KB.
// Stage units per tile: ph0:A-half0, ph1:A-half1, ph2:{Bq0,Bq2}, ph3:{Bq1,Bq3}
// (2 loads/thread/phase). vmcnt(2) @ph0, vmcnt(4) @ph2 (counted, never 0 mid-loop);
// 2 barriers/tile. Superrow swizzle per 128-row half (conflict-free reads).
__global__ __launch_bounds__(512, 2) void enc_gemm_bf16(
    const unsigned short* __restrict__ Xb, const unsigned short* __restrict__ Wb,
    const float* __restrict__ b_enc, float* __restrict__ pre, int D, int H)
{
  __shared__ unsigned short As[2][2048 * 8];   // [buf][slot*8], 2048 slots x 16B
  __shared__ unsigned short Bs[2][2048 * 8];
  const int tid  = threadIdx.x;
  const int wave = tid >> 6, lane = tid & 63;
  const int m0 = blockIdx.y * 256, n0 = blockIdx.x * 256;
  const int wm = (wave >> 1) * 64;   // 4 M-classes x 64 rows
  const int wn = (wave & 1) * 128;   // 2 N-classes x 128 cols
  const int l16 = lane & 15, lhi = lane >> 4;

  f32x4 acc[4][8];
#pragma unroll
  for (int i = 0; i < 4; ++i)
#pragma unroll
    for (int j = 0; j < 8; ++j) acc[i][j] = (f32x4){0.f, 0.f, 0.f, 0.f};

  const int NT = D / 64;

  // stage A half h (rows h*128..h*128+127) of K-tile at kb into buf (2 instr/thread)
  auto stageA = [&](int buf, int h, int kb) {
#pragma unroll
    for (int i = 0; i < 2; ++i) {
      const int idx = i * 512 + wave * 64 + lane;      // within-half slot 0..1023
      const int sr = idx >> 4, u = idx & 15;
      const int r  = (sr << 1) | (u >> 3);
      const int ch = (u & 7) ^ (sr & 7);
      __builtin_amdgcn_global_load_lds(
          (const __attribute__((address_space(1))) unsigned int*)
              (Xb + (size_t)(m0 + h * 128 + r) * D + kb + ch * 8),
          (__attribute__((address_space(3))) unsigned int*)
              (&As[buf][(size_t)(h * 1024 + idx) * 8]), 16, 0, 0);
    }
  };
  // stage B quarter q (cols q*64..q*64+63) of K-tile at kb into buf (1 instr/thread)
  auto stageBq = [&](int buf, int q, int kb) {
    const int s  = (q & 1) * 512 + wave * 64 + lane;   // within-half slot
    const int sr = s >> 4, u = s & 15;
    const int r  = (sr << 1) | (u >> 3);
    const int ch = (u & 7) ^ (sr & 7);
    __builtin_amdgcn_global_load_lds(
        (const __attribute__((address_space(1))) unsigned int*)
            (Wb + (size_t)(n0 + (q >> 1) * 128 + r) * D + kb + ch * 8),
        (__attribute__((address_space(3))) unsigned int*)
            (&Bs[buf][(size_t)((q >> 1) * 1024 + s) * 8]), 16, 0, 0);
  };
  auto readA = [&](int buf, int mi, int kk) -> bf16x8 {
    const int gr = wm + mi * 16 + l16;
    return *reinterpret_cast<const bf16x8*>(
        &As[buf][(size_t)((gr >> 7) * 1024 + lds_slot(gr & 127, kk * 4 + lhi)) * 8]);
  };
  auto readB = [&](int buf, int ni, int kk) -> bf16x8 {
    const int gr = wn + ni * 16 + l16;
    return *reinterpret_cast<const bf16x8*>(
        &Bs[buf][(size_t)((gr >> 7) * 1024 + lds_slot(gr & 127, kk * 4 + lhi)) * 8]);
  };

  // prologue: stage tile 0 in steady-state queue order: A0,A1,Bq0,Bq2,Bq1,Bq3
  stageA(0, 0, 0); stageA(0, 1, 0);
  stageBq(0, 0, 0); stageBq(0, 2, 0);
  stageBq(0, 1, 0); stageBq(0, 3, 0);

  int cur = 0;
  for (int t = 0; t < NT; ++t) {
    const int nxt = cur ^ 1;
    const int kb1 = (t + 1) * 64;
    const bool more = (t + 1 < NT);

    bf16x8 af[4][2], bf[2][2];

    // ---- phase 0: drain A0,A1,first-B-quarters (leave last 2 loads in flight) ----
    asm volatile("s_waitcnt vmcnt(2)" ::: "memory");
    __builtin_amdgcn_s_barrier();
#pragma unroll
    for (int mi = 0; mi < 4; ++mi)
#pragma unroll
      for (int kk = 0; kk < 2; ++kk) af[mi][kk] = readA(cur, mi, kk);
#pragma unroll
    for (int j = 0; j < 2; ++j)
#pragma unroll
      for (int kk = 0; kk < 2; ++kk) bf[j][kk] = readB(cur, j, kk);
    if (more) stageA(nxt, 0, kb1);
    __builtin_amdgcn_s_setprio(1);
#pragma unroll
    for (int mi = 0; mi < 4; ++mi)
#pragma unroll
      for (int j = 0; j < 2; ++j)
#pragma unroll
        for (int kk = 0; kk < 2; ++kk)
          acc[mi][j] = __builtin_amdgcn_mfma_f32_16x16x32_bf16(af[mi][kk], bf[j][kk], acc[mi][j], 0, 0, 0);
    __builtin_amdgcn_s_setprio(0);

    // ---- phase 1 (same B quarter, no sync needed) ----
#pragma unroll
    for (int j = 0; j < 2; ++j)
#pragma unroll
      for (int kk = 0; kk < 2; ++kk) bf[j][kk] = readB(cur, 2 + j, kk);
    if (more) stageA(nxt, 1, kb1);
    __builtin_amdgcn_s_setprio(1);
#pragma unroll
    for (int mi = 0; mi < 4; ++mi)
#pragma unroll
      for (int j = 0; j < 2; ++j)
#pragma unroll
        for (int kk = 0; kk < 2; ++kk)
          acc[mi][2 + j] = __builtin_amdgcn_mfma_f32_16x16x32_bf16(af[mi][kk], bf[j][kk], acc[mi][2 + j], 0, 0, 0);
    __builtin_amdgcn_s_setprio(0);

    // ---- phase 2: drain second-B-quarters (Bq1,Bq3 of tile t) ----
    if (more) { asm volatile("s_waitcnt vmcnt(4)" ::: "memory"); }
    else      { asm volatile("s_waitcnt vmcnt(0)" ::: "memory"); }
    __builtin_amdgcn_s_barrier();
#pragma unroll
    for (int j = 0; j < 2; ++j)
#pragma unroll
      for (int kk = 0; kk < 2; ++kk) bf[j][kk] = readB(cur, 4 + j, kk);
    if (more) { stageBq(nxt, 0, kb1); stageBq(nxt, 2, kb1); }
    __builtin_amdgcn_s_setprio(1);
#pragma unroll
    for (int mi = 0; mi < 4; ++mi)
#pragma unroll
      for (int j = 0; j < 2; ++j)
#pragma unroll
        for (int kk = 0; kk < 2; ++kk)
          acc[mi][4 + j] = __builtin_amdgcn_mfma_f32_16x16x32_bf16(af[mi][kk], bf[j][kk], acc[mi][4 + j], 0, 0, 0);
    __builtin_amdgcn_s_setprio(0);

    // ---- phase 3 ----
#pragma unroll
    for (int j = 0; j < 2; ++j)
#pragma unroll
      for (int kk = 0; kk < 2; ++kk) bf[j][kk] = readB(cur, 6 + j, kk);
    if (more) { stageBq(nxt, 1, kb1); stageBq(nxt, 3, kb1); }
    __builtin_amdgcn_s_setprio(1);
#pragma unroll
    for (int mi = 0; mi < 4; ++mi)
#pragma unroll
      for (int j = 0; j < 2; ++j)
#pragma unroll
        for (int kk = 0; kk < 2; ++kk)
          acc[mi][6 + j] = __builtin_amdgcn_mfma_f32_16x16x32_bf16(af[mi][kk], bf[j][kk], acc[mi][6 + j], 0, 0, 0);
    __builtin_amdgcn_s_setprio(0);

    cur = nxt;
  }

  // epilogue: write monotone u16 keys
#pragma unroll
  for (int ni = 0; ni < 8; ++ni) {
    const int n = n0 + wn + ni * 16 + l16;
    const float be = b_enc[n];
#pragma unroll
    for (int mi = 0; mi < 4; ++mi) {
      const int mbase = m0 + wm + mi * 16 + lhi * 4;
#pragma unroll
      for (int r = 0; r < 4; ++r) {
        unsigned short* prow = (unsigned short*)(pre + (size_t)(mbase + r) * H);
        prow[n] = key_of(acc[mi][ni][r] + be);
      }
    }
  }
}

// ---------------- kernel 2: single-pass key classify + hidden-row zero ----------------
__global__ __launch_bounds__(256) void topk_classify_keys(
    float* __restrict__ hidden,
    int* __restrict__ sure_ix, float* __restrict__ sure_val, int* __restrict__ sure_cnt,
    int* __restrict__ amb_ix, int* __restrict__ amb_cnt,
    const int* __restrict__ kptr, float delta)
{
  constexpr int H = H_FIX, NC = H_FIX / (256 * 8);
  __shared__ int hist[4096];
  __shared__ int chunk[256];
  __shared__ int misc[8];

  const int tid = threadIdx.x, b = blockIdx.x;
  const int k = min(*kptr, K_MAX);
  float* hrow = hidden + (size_t)b * H;
  const unsigned short* krow = (const unsigned short*)hrow;

  if (tid < 8) misc[tid] = 0;
  for (int i = tid; i < 4096; i += 256) hist[i] = 0;

  u16x8 kv[NC];
#pragma unroll
  for (int i = 0; i < NC; ++i)
    kv[i] = *reinterpret_cast<const u16x8*>(krow + ((size_t)i * 256 + tid) * 8);
  __syncthreads();   // all keys in registers before the row is overwritten

  const float4 z4 = {0.f, 0.f, 0.f, 0.f};
  for (int i = tid; i < (H >> 2); i += 256)
    reinterpret_cast<float4*>(hrow)[i] = z4;

#pragma unroll
  for (int i = 0; i < NC; ++i)
#pragma unroll
    for (int j = 0; j < 8; ++j)
      atomicAdd(&hist[((unsigned)(unsigned short)kv[i][j]) >> 4], 1);
  __syncthreads();

  int csum = 0;
#pragma unroll
  for (int j = 0; j < 16; ++j) csum += hist[tid * 16 + j];
  chunk[tid] = csum;
  __syncthreads();
  int gt = 0;
  for (int j = tid + 1; j < 256; ++j) gt += chunk[j];
  {
    int run = gt;
#pragma unroll
    for (int j = 15; j >= 0; --j) {
      const int hc = hist[tid * 16 + j];
      if (run < k && k <= run + hc) { misc[0] = tid * 16 + j; misc[1] = run; }
      run += hc;
    }
  }
  __syncthreads();
  const int b1 = misc[0];
  if (tid < 16) chunk[tid] = 0;
  __syncthreads();
#pragma unroll
  for (int i = 0; i < NC; ++i)
#pragma unroll
    for (int j = 0; j < 8; ++j) {
      const unsigned kk = (unsigned)(unsigned short)kv[i][j];
      if ((int)(kk >> 4) == b1) atomicAdd(&chunk[kk & 15], 1);
    }
  __syncthreads();
  if (tid == 0) {
    int run = misc[1];
    int K16 = b1 << 4;
    for (int j = 15; j >= 0; --j) {
      const int c = chunk[j];
      if (run < k && k <= run + c) K16 = (b1 << 4) | j;
      run += c;
    }
    const float v_lo = val_of_key((unsigned short)K16);
    const float v_hi = val_of_key((unsigned short)min(K16 + 1, 65535));
    const float ulp = v_hi - v_lo;
    const float vs = v_hi + delta;          // sure: value >  vs
    const float va = v_lo - ulp - delta;    // amb : value >= va
    int ks = key_of(vs); if (val_of_key((unsigned short)ks) > vs) --ks;   // floor key
    int ka = key_of(va); if (val_of_key((unsigned short)ka) < va) ++ka;   // ceil key
    misc[2] = ks; misc[3] = ka;
  }
  __syncthreads();
  const unsigned ks = (unsigned)misc[2], ka = (unsigned)misc[3];

#pragma unroll
  for (int i = 0; i < NC; ++i)
#pragma unroll
    for (int j = 0; j < 8; ++j) {
      const unsigned kk = (unsigned)(unsigned short)kv[i][j];
      if (kk > ks) {
        const int p = atomicAdd(&misc[4], 1);
        if (p < S_MAX) {
          const int h = (i * 256 + tid) * 8 + j;
          sure_ix[(size_t)b * S_MAX + p] = h;
          sure_val[(size_t)b * S_MAX + p] = val_of_key((unsigned short)kk);
        }
      } else if (kk >= ka) {
        const int p = atomicAdd(&misc[5], 1);
        if (p < A_MAX) amb_ix[(size_t)b * A_MAX + p] = (i * 256 + tid) * 8 + j;
      }
    }
  __syncthreads();
  if (tid == 0) {
    sure_cnt[b] = min(misc[4], S_MAX);
    amb_cnt[b]  = min(misc[5], A_MAX);
  }
}

// ---------------- kernel 3: f64 refine + rank + scatter (merged; row pre-zeroed) ----------------
__global__ __launch_bounds__(256) void refine_scatter(
    const float* __restrict__ X, const float* __restrict__ b_pre,
    const float* __restrict__ W, const float* __restrict__ b_enc,
    const int* __restrict__ sure_ix, const float* __restrict__ sure_val,
    const int* __restrict__ sure_cnt,
    const int* __restrict__ amb_ix, const int* __restrict__ amb_cnt,
    const int* __restrict__ kptr,
    float* __restrict__ hidden, int* __restrict__ tk_idx, float* __restrict__ tk_val, int D)
{
  constexpr int H = H_FIX;
  __shared__ float  xr[D_MAX];
  __shared__ double asv[A_MAX];
  __shared__ int    aix[A_MAX];
  const int tid = threadIdx.x, b = blockIdx.x;
  const int k = min(*kptr, K_MAX);
  const int S = min(min(sure_cnt[b], S_MAX), k);
  const int A = min(amb_cnt[b], A_MAX);
  float* hrow = hidden + (size_t)b * H;

  for (int d = tid; d < D; d += 256) xr[d] = X[(size_t)b * D + d] - b_pre[d];
  for (int c = tid; c < A; c += 256) aix[c] = amb_ix[(size_t)b * A_MAX + c];

  for (int i = tid; i < S; i += 256) {
    const int h = sure_ix[(size_t)b * S_MAX + i];
    const float v = sure_val[(size_t)b * S_MAX + i];
    const float rv = (v > 0.f) ? v : 0.f;
    hrow[h] = rv;
    tk_idx[(size_t)b * K_MAX + i] = h;
    tk_val[(size_t)b * K_MAX + i] = rv;
  }
  __syncthreads();

  const int wid = tid >> 6, lane = tid & 63;
  for (int c = wid; c < A; c += 4) {
    const int h = aix[c];
    const float* wr = W + (size_t)h * D;
    double s0 = 0.0, s1 = 0.0;
    int i = lane;
    for (; i + 64 < D; i += 128) {
      s0 += (double)xr[i] * (double)wr[i];
      s1 += (double)xr[i + 64] * (double)wr[i + 64];
    }
    if (i < D) s0 += (double)xr[i] * (double)wr[i];
    double s = s0 + s1;
    for (int off = 32; off; off >>= 1) s += __shfl_xor(s, off);
    if (lane == 0) asv[c] = s + (double)b_enc[h];
  }
  __syncthreads();

  const int m = k - S;
  for (int c = tid; c < A; c += 256) {
    const double v = asv[c];
    const int h = aix[c];
    int r = 0;
    for (int j = 0; j < A; ++j) {
      const double vj = asv[j];
      r += ((vj > v) || (vj == v && aix[j] < h)) ? 1 : 0;
    }
    if (r < m) {
      const float rv = (v > 0.0) ? (float)v : 0.f;
      hrow[h] = rv;
      tk_idx[(size_t)b * K_MAX + S + r] = h;
      tk_val[(size_t)b * K_MAX + S + r] = rv;
    }
  }
}

// ---------------- fallback: fp32 GEMM ----------------
__global__ __launch_bounds__(256) void enc_gemm_f32(
    const float* __restrict__ X, const float* __restrict__ W,
    const float* __restrict__ b_enc, const float* __restrict__ b_pre,
    float* __restrict__ pre, int D, int H)
{
  __shared__ float As[BKF][BM + 4];
  __shared__ float Bs[BKF][BN + 4];
  const int tid = threadIdx.x;
  const int m0 = blockIdx.y * BM;
  const int n0 = blockIdx.x * BN;
  const int tx = tid & 15, ty = tid >> 4;
  float acc[8][8];
#pragma unroll
  for (int i = 0; i < 8; ++i)
#pragma unroll
    for (int j = 0; j < 8; ++j) acc[i][j] = 0.f;

  for (int kb = 0; kb < D; kb += BKF) {
#pragma unroll
    for (int t = 0; t < 2; ++t) {
      const int f4i = tid + t * 256;
      const int row = f4i >> 2;
      const int kq  = (f4i & 3) << 2;
      float4 xv = *reinterpret_cast<const float4*>(X + (size_t)(m0 + row) * D + kb + kq);
      float4 bp = *reinterpret_cast<const float4*>(b_pre + kb + kq);
      As[kq + 0][row] = xv.x - bp.x; As[kq + 1][row] = xv.y - bp.y;
      As[kq + 2][row] = xv.z - bp.z; As[kq + 3][row] = xv.w - bp.w;
      float4 wv = *reinterpret_cast<const float4*>(W + (size_t)(n0 + row) * D + kb + kq);
      Bs[kq + 0][row] = wv.x; Bs[kq + 1][row] = wv.y;
      Bs[kq + 2][row] = wv.z; Bs[kq + 3][row] = wv.w;
    }
    __syncthreads();
#pragma unroll
    for (int kk = 0; kk < BKF; ++kk) {
      float4 a0 = *reinterpret_cast<const float4*>(&As[kk][ty * 8]);
      float4 a1 = *reinterpret_cast<const float4*>(&As[kk][ty * 8 + 4]);
      float4 b0 = *reinterpret_cast<const float4*>(&Bs[kk][tx * 8]);
      float4 b1 = *reinterpret_cast<const float4*>(&Bs[kk][tx * 8 + 4]);
      float av[8] = {a0.x, a0.y, a0.z, a0.w, a1.x, a1.y, a1.z, a1.w};
      float bv[8] = {b0.x, b0.y, b0.z, b0.w, b1.x, b1.y, b1.z, b1.w};
#pragma unroll
      for (int i = 0; i < 8; ++i)
#pragma unroll
        for (int j = 0; j < 8; ++j) acc[i][j] += av[i] * bv[j];
    }
    __syncthreads();
  }
#pragma unroll
  for (int i = 0; i < 8; ++i) {
    const size_t m = (size_t)(m0 + ty * 8 + i);
#pragma unroll
    for (int j = 0; j < 8; j += 4) {
      const int n = n0 + tx * 8 + j;
      float4 o;
      o.x = acc[i][j + 0] + b_enc[n + 0];
      o.y = acc[i][j + 1] + b_enc[n + 1];
      o.z = acc[i][j + 2] + b_enc[n + 2];
      o.w = acc[i][j + 3] + b_enc[n + 3];
      *reinterpret_cast<float4*>(pre + m * H + n) = o;
    }
  }
}

// ---------------- fallback: bisection top-k (reads f32 pre) ----------------
__global__ __launch_bounds__(256) void topk_refine(
    const float* __restrict__ X, const float* __restrict__ b_pre,
    const float* __restrict__ W, const float* __restrict__ b_enc,
    float* __restrict__ hidden, int* __restrict__ tk_idx, float* __restrict__ tk_val,
    const int* __restrict__ kptr, int D, int H, float margin)
{
  extern __shared__ char smem_raw[];
  double* cand_val = reinterpret_cast<double*>(smem_raw);
  float*  xr       = reinterpret_cast<float*>(cand_val + CAND_MAX);
  int*    cand_idx = reinterpret_cast<int*>(xr + D);
  int*    misc     = cand_idx + CAND_MAX;

  const int tid = threadIdx.x;
  const int b = blockIdx.x;
  const int k = min(*kptr, K_MAX);
  float* hrow = hidden + (size_t)b * H;

  for (int i = tid; i < NBITER + 2; i += 256) misc[i] = 0;
  for (int d = tid; d < D; d += 256) xr[d] = X[(size_t)b * D + d] - b_pre[d];

  float f[64];
#pragma unroll
  for (int i = 0; i < 16; ++i) {
    const int base = i * 1024 + tid * 4;
    float4 v = {-3e38f, -3e38f, -3e38f, -3e38f};
    if (base + 3 < H) v = *reinterpret_cast<const float4*>(hrow + base);
    f[4 * i + 0] = v.x; f[4 * i + 1] = v.y; f[4 * i + 2] = v.z; f[4 * i + 3] = v.w;
  }
  __syncthreads();

  float lo = -1e4f, hi = 1e4f;
  for (int it = 0; it < NBITER; ++it) {
    const float mid = 0.5f * (lo + hi);
    int cnt = 0;
#pragma unroll
    for (int j = 0; j < 64; ++j) cnt += (f[j] >= mid) ? 1 : 0;
    for (int off = 32; off; off >>= 1) cnt += __shfl_xor(cnt, off);
    if ((tid & 63) == 0) atomicAdd(&misc[it], cnt);
    __syncthreads();
    if (misc[it] >= k) lo = mid; else hi = mid;
  }

  const float thresh = lo - margin;
#pragma unroll
  for (int j = 0; j < 64; ++j) {
    if (f[j] >= thresh) {
      const int h = (j >> 2) * 1024 + tid * 4 + (j & 3);
      if (h < H) {
        int pos = atomicAdd(&misc[NBITER], 1);
        if (pos < CAND_MAX) cand_idx[pos] = h;
      }
    }
  }
  __syncthreads();
  const int C = min(misc[NBITER], CAND_MAX);

  const int wid = tid >> 6, lane = tid & 63;
  for (int c = wid; c < C; c += 4) {
    const int h = cand_idx[c];
    const float* wr = W + (size_t)h * D;
    double s = 0.0;
    for (int i = lane; i < D; i += 64) s += (double)xr[i] * (double)wr[i];
    for (int off = 32; off; off >>= 1) s += __shfl_xor(s, off);
    if (lane == 0) cand_val[c] = s + (double)b_enc[h];
  }
  __syncthreads();

  const float4 z4 = {0.f, 0.f, 0.f, 0.f};
  for (int i = tid; i < (H >> 2); i += 256)
    reinterpret_cast<float4*>(hrow)[i] = z4;
  __syncthreads();

  for (int c = tid; c < C; c += 256) {
    const double v = cand_val[c];
    const int h = cand_idx[c];
    int r = 0;
    for (int j = 0; j < C; ++j) {
      const double vj = cand_val[j];
      r += ((vj > v) || (vj == v && cand_idx[j] < h)) ? 1 : 0;
    }
    if (r < k) {
      const float rv = (v > 0.0) ? (float)v : 0.f;
      hrow[h] = rv;
      tk_idx[(size_t)b * K_MAX + r] = h;
      tk_val[(size_t)b * K_MAX + r] = rv;
    }
  }
}

// ---------------- kernel 5: W_dec [D,H] -> bf16 W_decT [H,D] ----------------
__global__ __launch_bounds__(256) void transpose_wdec_bf16(
    const float* __restrict__ Wsrc, unsigned short* __restrict__ WT, int D, int H)
{
  __shared__ float tile[32][33];
  const int c  = threadIdx.x & 31;
  const int r0 = threadIdx.x >> 5;
  const int h0 = blockIdx.x * 32;
  const int d0 = blockIdx.y * 32;
#pragma unroll
  for (int r = r0; r < 32; r += 8) {
    const int d = d0 + r, h = h0 + c;
    if (d < D && h < H) tile[r][c] = Wsrc[(size_t)d * H + h];
  }
  __syncthreads();
#pragma unroll
  for (int r = r0; r < 32; r += 8) {
    const int h = h0 + r, d = d0 + c;
    if (h < H && d < D) WT[(size_t)h * D + d] = f2bf(tile[c][r]);
  }
}

// ---------------- kernel 6: sparse decode + per-row squared error (vectorized) ----------------
__global__ __launch_bounds__(256) void decode_loss(
    const float* __restrict__ X, const float* __restrict__ b_pre,
    const float* __restrict__ b_dec, const float* __restrict__ Wfull,
    const unsigned short* __restrict__ WTb,
    const int* __restrict__ tk_idx, const float* __restrict__ tk_val,
    const int* __restrict__ kptr,
    float* __restrict__ recon, double* __restrict__ row_ssq,
    int D, int H, int useWT)
{
  __shared__ int   sidx[K_MAX];
  __shared__ float sval[K_MAX];
  __shared__ double sd[4];
  const int tid = threadIdx.x, b = blockIdx.x;
  const int k = min(*kptr, K_MAX);
  if (tid < k) {
    sidx[tid] = tk_idx[(size_t)b * K_MAX + tid];
    sval[tid] = tk_val[(size_t)b * K_MAX + tid];
  }
  __syncthreads();
  double ssq = 0.0;
  const int D4 = D >> 2;
  for (int dc = tid; dc < D4; dc += 256) {
    const int d = dc * 4;
    float4 bd = *reinterpret_cast<const float4*>(b_dec + d);
    float4 bp = *reinterpret_cast<const float4*>(b_pre + d);
    float4 a = {bd.x + bp.x, bd.y + bp.y, bd.z + bp.z, bd.w + bp.w};
    if (useWT) {
#pragma unroll 4
      for (int j = 0; j < k; ++j) {
        const ushort4 w = *reinterpret_cast<const ushort4*>(WTb + (size_t)sidx[j] * D + d);
        const float s = sval[j];
        a.x += s * bf2f(w.x); a.y += s * bf2f(w.y);
        a.z += s * bf2f(w.z); a.w += s * bf2f(w.w);
      }
    } else {
#pragma unroll 4
      for (int j = 0; j < k; ++j) {
        const float s = sval[j];
        const int h = sidx[j];
        a.x += s * Wfull[(size_t)(d + 0) * H + h];
        a.y += s * Wfull[(size_t)(d + 1) * H + h];
        a.z += s * Wfull[(size_t)(d + 2) * H + h];
        a.w += s * Wfull[(size_t)(d + 3) * H + h];
      }
    }
    *reinterpret_cast<float4*>(recon + (size_t)b * D + d) = a;
    float4 xv = *reinterpret_cast<const float4*>(X + (size_t)b * D + d);
    const double d0 = (double)a.x - (double)xv.x;
    const double d1 = (double)a.y - (double)xv.y;
    const double d2 = (double)a.z - (double)xv.z;
    const double d3 = (double)a.w - (double)xv.w;
    ssq += d0 * d0 + d1 * d1 + d2 * d2 + d3 * d3;
  }
  for (int off = 32; off; off >>= 1) ssq += __shfl_xor(ssq, off);
  if ((tid & 63) == 0) sd[tid >> 6] = ssq;
  __syncthreads();
  if (tid == 0) row_ssq[b] = sd[0] + sd[1] + sd[2] + sd[3];
}

// ---------------- kernel 7a: per-chunk partial losses (64 blocks) ----------------
__global__ __launch_bounds__(256) void finalize_part(
    const double* __restrict__ row_ssq, const float* __restrict__ tk_val,
    const int* __restrict__ kptr, double* __restrict__ part_s, int* __restrict__ part_c,
    int Bdim, int rows_per_blk)
{
  __shared__ double sd[4];
  __shared__ int si[4];
  const int tid = threadIdx.x;
  const int k = min(*kptr, K_MAX);
  const int b0 = blockIdx.x * rows_per_blk;
  const int b1 = min(b0 + rows_per_blk, Bdim);
  double s = 0.0;
  for (int i = b0 + tid; i < b1; i += 256) s += row_ssq[i];
  int cnt = 0;
  const int total = (b1 - b0) * k;
  for (int i = tid; i < total; i += 256) {
    const int bb = b0 + i / k, j = i - (i / k) * k;
    cnt += (tk_val[(size_t)bb * K_MAX + j] > 0.f) ? 1 : 0;
  }
  for (int off = 32; off; off >>= 1) { s += __shfl_xor(s, off); cnt += __shfl_xor(cnt, off); }
  if ((tid & 63) == 0) { sd[tid >> 6] = s; si[tid >> 6] = cnt; }
  __syncthreads();
  if (tid == 0) {
    part_s[blockIdx.x] = sd[0] + sd[1] + sd[2] + sd[3];
    part_c[blockIdx.x] = si[0] + si[1] + si[2] + si[3];
  }
}

// ---------------- kernel 7b: final scalar losses ----------------
__global__ __launch_bounds__(64) void finalize_k2(
    const double* __restrict__ part_s, const int* __restrict__ part_c,
    float* __restrict__ scalars, int nparts, int Bdim, int D)
{
  const int tid = threadIdx.x;
  double s = (tid < nparts) ? part_s[tid] : 0.0;
  int cnt = (tid < nparts) ? part_c[tid] : 0;
  for (int off = 32; off; off >>= 1) { s += __shfl_xor(s, off); cnt += __shfl_xor(cnt, off); }
  if (tid == 0) {
    const double rl = s / ((double)Bdim * (double)D);
    scalars[0] = (float)rl;                     // loss
    scalars[1] = (float)rl;                     // reconstruction_loss
    scalars[2] = 0.f;                           // sparsity_loss
    scalars[3] = (float)((double)cnt / Bdim);   // l0
  }
}

extern "C" void kernel_launch(void* const* d_in, const int* in_sizes, int n_in,
                              void* d_out, int out_size, void* d_ws, size_t ws_size,
                              hipStream_t stream)
{
  const float* x     = (const float*)d_in[0];
  const float* W_enc = (const float*)d_in[1];
  const float* b_enc = (const float*)d_in[2];
  const float* W_dec = (const float*)d_in[3];
  const float* b_dec = (const float*)d_in[4];
  const float* b_pre = (const float*)d_in[5];
  const int*   kptr  = (const int*)d_in[6];

  const int D = in_sizes[4];          // 1280
  const int H = in_sizes[2];          // 16384
  const int B = in_sizes[0] / D;      // 8192

  float* recon   = (float*)d_out;
  float* hidden  = recon + (size_t)B * D;       // temporarily holds keys / f32 pre
  float* scalars = hidden + (size_t)B * H;

  // ---- workspace layout (single running cursor) ----
  size_t off = 0;
  int* tk_idx = (int*)((char*)d_ws + off);        off += (size_t)B * K_MAX * sizeof(int);
  float* tk_val = (float*)((char*)d_ws + off);    off += (size_t)B * K_MAX * sizeof(float);
  off = (off + 7) & ~(size_t)7;
  double* row_ssq = (double*)((char*)d_ws + off); off += (size_t)B * sizeof(double);
  double* part_s = (double*)((char*)d_ws + off);  off += 64 * sizeof(double);
  int* part_c = (int*)((char*)d_ws + off);        off += 64 * sizeof(int);
  off = (off + 7) & ~(size_t)7;

  unsigned short* Xb = (unsigned short*)((char*)d_ws + off);
  off += (size_t)B * D * sizeof(unsigned short);
  unsigned short* Wb = (unsigned short*)((char*)d_ws + off);
  off += (size_t)H * D * sizeof(unsigned short);
  const int useBF16 = (off <= ws_size) ? 1 : 0;

  unsigned short* WTb = (unsigned short*)((char*)d_ws + off);
  off += (size_t)D * H * sizeof(unsigned short);
  const int useWT = (off <= ws_size) ? 1 : 0;

  int* sure_ix = (int*)((char*)d_ws + off);       off += (size_t)B * S_MAX * sizeof(int);
  float* sure_val = (float*)((char*)d_ws + off);  off += (size_t)B * S_MAX * sizeof(float);
  int* sure_cnt = (int*)((char*)d_ws + off);      off += (size_t)B * sizeof(int);
  int* amb_ix = (int*)((char*)d_ws + off);        off += (size_t)B * A_MAX * sizeof(int);
  int* amb_cnt = (int*)((char*)d_ws + off);       off += (size_t)B * sizeof(int);
  off = (off + 7) & ~(size_t)7;
  const int useSPLIT = (useBF16 && off <= ws_size) ? 1 : 0;

  const bool fast_ok = (D % 64 == 0) && (D <= D_MAX) &&
                       (H == H_FIX) && (B % 256 == 0);

  if (useBF16 && fast_ok && useSPLIT) {
    const size_t tx4 = (size_t)B * D / 4, tw4 = (size_t)H * D / 4;
    prep_xb<<<2048, 256, 0, stream>>>(x, b_pre, Xb, D, tx4);
    prep_wb<<<2048, 256, 0, stream>>>(W_enc, Wb, tw4);
    dim3 gg(H / 256, B / 256);
    enc_gemm_bf16<<<gg, 512, 0, stream>>>(Xb, Wb, b_enc, hidden, D, H);  // u16 keys
    // delta >= 2*(GEMM err ~0.01 + bf16 ulp/2 ~0.008) with slack
    topk_classify_keys<<<B, 256, 0, stream>>>(hidden, sure_ix, sure_val, sure_cnt,
                                              amb_ix, amb_cnt, kptr, 0.05f);
    refine_scatter<<<B, 256, 0, stream>>>(x, b_pre, W_enc, b_enc,
                                          sure_ix, sure_val, sure_cnt,
                                          amb_ix, amb_cnt, kptr,
                                          hidden, tk_idx, tk_val, D);
  } else {
    dim3 gg(H / BN, B / BM);
    enc_gemm_f32<<<gg, 256, 0, stream>>>(x, W_enc, b_enc, b_pre, hidden, D, H);
    const size_t sh = CAND_MAX * sizeof(double) + (size_t)D * sizeof(float)
                    + CAND_MAX * sizeof(int) + (NBITER + 8) * sizeof(int);
    topk_refine<<<B, 256, sh, stream>>>(x, b_pre, W_enc, b_enc, hidden,
                                        tk_idx, tk_val, kptr, D, H, 1e-3f);
  }

  if (useWT)
    transpose_wdec_bf16<<<dim3((H + 31) / 32, (D + 31) / 32), 256, 0, stream>>>(W_dec, WTb, D, H);

  decode_loss<<<B, 256, 0, stream>>>(x, b_pre, b_dec, W_dec, WTb,
                                     tk_idx, tk_val, kptr, recon, row_ssq, D, H, useWT);

  const int rpb = (B + 63) / 64;
  finalize_part<<<64, 256, 0, stream>>>(row_ssq, tk_val, kptr, part_s, part_c, B, rpb);
  finalize_k2<<<1, 64, 0, stream>>>(part_s, part_c, scalars, 64, B, D);
}